// Round 2
// baseline (935.262 us; speedup 1.0000x reference)
//
#include <hip/hip_runtime.h>
#include <hip/hip_bf16.h>
#include <stdint.h>

#define NN 50000
#define NE 800000
#define ET 850000   // NE + NN self loops
#define NG 256

typedef __hip_bfloat16 bf16;

__device__ __forceinline__ float b2f(bf16 v) { return __bfloat162float(v); }
__device__ __forceinline__ float lrelu(float x) { return x > 0.f ? x : 0.2f * x; }

__device__ __forceinline__ float wred_sum(float v) {
    for (int o = 32; o > 0; o >>= 1) v += __shfl_xor(v, o, 64);
    return v;
}
__device__ __forceinline__ float wred_max(float v) {
    for (int o = 32; o > 0; o >>= 1) v = fmaxf(v, __shfl_xor(v, o, 64));
    return v;
}

// ---------------- dtype detection ----------------
// flags[0] = 1 if float inputs are fp32 (else bf16)
// flags[1] = 1 if int inputs are int64 (else int32)
__global__ void detect_kernel(const unsigned int* __restrict__ meta_words,
                              const unsigned int* __restrict__ ei_words,
                              int* __restrict__ flags) {
    __shared__ int insane, odd_nonzero;
    if (threadIdx.x == 0) { insane = 0; odd_nonzero = 0; }
    __syncthreads();
    int cnt = 0;
    for (int k = 0; k < 8; k++) {
        unsigned int w = meta_words[threadIdx.x * 8 + k];
        unsigned int lo = w & 0xFFFFu, hi = w >> 16;
        int elo = (int)((lo >> 7) & 0xFF);
        int ehi = (int)((hi >> 7) & 0xFF);
        if (elo >= 0x8D) cnt++;       // |v| >= 16384 as bf16: impossible for real data
        if (ehi >= 0x8D) cnt++;
    }
    if (cnt) atomicAdd(&insane, cnt);
    unsigned int ow = ei_words[threadIdx.x * 2 + 1];   // odd words 1,3,...,511
    if (ow != 0u) atomicAdd(&odd_nonzero, 1);
    __syncthreads();
    if (threadIdx.x == 0) {
        flags[0] = (insane >= 4) ? 1 : 0;
        flags[1] = (odd_nonzero == 0) ? 1 : 0;
    }
}

// ---------------- canonicalize all float inputs to fp32 ----------------
struct CvtArgs {
    const void* src[32];
    int len[32];
    int dst_off[32];
    int blk_base[33];
};

__global__ void cvt_float_kernel(CvtArgs a, float* __restrict__ dst,
                                 const int* __restrict__ flags) {
    int b = blockIdx.x;
    int ai = 0;
    while (b >= a.blk_base[ai + 1]) ai++;
    int base = (b - a.blk_base[ai]) * 1024 + threadIdx.x;
    bool fp32 = flags[0] != 0;
    const float* sf = (const float*)a.src[ai];
    const bf16* sh = (const bf16*)a.src[ai];
    float* d = dst + a.dst_off[ai];
    int len = a.len[ai];
    #pragma unroll
    for (int u = 0; u < 4; u++) {
        int i = base + u * 256;
        if (i < len) d[i] = fp32 ? sf[i] : b2f(sh[i]);
    }
}

__global__ void cvt_int_kernel(const void* __restrict__ src, int* __restrict__ dst,
                               int n, const int* __restrict__ flags) {
    int i = blockIdx.x * 256 + threadIdx.x;
    if (i >= n) return;
    dst[i] = flags[1] ? (int)((const long long*)src)[i] : ((const int*)src)[i];
}

// ---------------- encoders + combiner: x0[N,64] ----------------
__global__ void encode_kernel(const float* __restrict__ meta, const float* __restrict__ wavef,
                              const float* __restrict__ meta_w, const float* __restrict__ meta_b,
                              const float* __restrict__ wave_w, const float* __restrict__ wave_b,
                              const float* __restrict__ comb_w, const float* __restrict__ comb_b,
                              float* __restrict__ x0, int n) {
    int w = threadIdx.x >> 6;
    int lane = threadIdx.x & 63;
    int node = blockIdx.x * 4 + w;
    __shared__ float xs[4][64];

    if (node < n) {
        float acc;
        if (lane < 32) {
            acc = meta_b[lane];
            #pragma unroll
            for (int k = 0; k < 4; k++)
                acc += meta[node * 4 + k] * meta_w[k * 32 + lane];
        } else {
            int c = lane - 32;
            acc = wave_b[c];
            for (int k = 0; k < 64; k++)
                acc += wavef[node * 64 + k] * wave_w[k * 32 + c];
        }
        xs[w][lane] = fmaxf(acc, 0.f);
    }
    __syncthreads();
    if (node < n) {
        float acc2 = comb_b[lane];
        for (int k = 0; k < 64; k++)
            acc2 += xs[w][k] * comb_w[k * 64 + lane];
        x0[node * 64 + lane] = fmaxf(acc2, 0.f);
    }
}

// ---------------- CSR build ----------------
__global__ void count_kernel(const int* __restrict__ ei, int* __restrict__ cnt) {
    int i = blockIdx.x * blockDim.x + threadIdx.x;
    if (i >= ET) return;
    int dst = (i < NE) ? ei[NE + i] : (i - NE);
    atomicAdd(&cnt[dst], 1);
}

__global__ void scan_kernel(const int* __restrict__ cnt, int* __restrict__ off,
                            int* __restrict__ cur, int n) {
    __shared__ int buf[1024];
    __shared__ int s_carry;
    int tid = threadIdx.x;
    if (tid == 0) s_carry = 0;
    __syncthreads();
    for (int base = 0; base < n; base += 1024) {
        int idx = base + tid;
        int v = (idx < n) ? cnt[idx] : 0;
        buf[tid] = v;
        __syncthreads();
        for (int o = 1; o < 1024; o <<= 1) {
            int t = (tid >= o) ? buf[tid - o] : 0;
            __syncthreads();
            buf[tid] += t;
            __syncthreads();
        }
        int incl = buf[tid];
        int c = s_carry;
        if (idx < n) {
            int e = c + incl - v;
            off[idx] = e;
            cur[idx] = e;
        }
        __syncthreads();
        if (tid == 1023) s_carry = c + buf[1023];
        __syncthreads();
    }
    if (tid == 0) off[n] = s_carry;
}

__global__ void fill_kernel(const int* __restrict__ ei, int* __restrict__ cur,
                            int* __restrict__ csr) {
    int i = blockIdx.x * blockDim.x + threadIdx.x;
    if (i >= ET) return;
    int src, dst;
    if (i < NE) { src = ei[i]; dst = ei[NE + i]; }
    else        { src = i - NE; dst = i - NE; }
    int pos = atomicAdd(&cur[dst], 1);
    csr[pos] = src;
}

// ---------------- per-layer GEMM h = x@W, plus s,d attn logits ----------------
__global__ void gemm_sd_kernel(const float* __restrict__ x, int K,
                               const float* __restrict__ W,
                               const float* __restrict__ a_s, const float* __restrict__ a_d,
                               float* __restrict__ h, float* __restrict__ s_out,
                               float* __restrict__ d_out, int n) {
    __shared__ float xs[8 * 128];
    int node0 = blockIdx.x * 8;
    int t = threadIdx.x;           // 0..127 = output channel
    for (int idx = t; idx < 8 * K; idx += 128) {
        int node = node0 + idx / K;
        xs[idx] = (node < n) ? x[node0 * K + idx] : 0.f;
    }
    __syncthreads();
    float acc[8] = {0, 0, 0, 0, 0, 0, 0, 0};
    #pragma unroll 4
    for (int k = 0; k < K; k++) {
        float w = W[k * 128 + t];
        #pragma unroll
        for (int j = 0; j < 8; j++) acc[j] += xs[j * K + k] * w;
    }
    float as_ = a_s[t];
    float ad_ = a_d[t];
    int head = t >> 6, lane = t & 63;
    #pragma unroll
    for (int j = 0; j < 8; j++) {
        int node = node0 + j;
        if (node >= n) break;
        float v = acc[j];
        h[node * 128 + t] = v;
        float ps = wred_sum(v * as_);
        float pd = wred_sum(v * ad_);
        if (lane == 0) {
            s_out[node * 2 + head] = ps;
            d_out[node * 2 + head] = pd;
        }
    }
}

// ---------------- edge softmax + aggregation + bias + BN + res + relu ----------------
__global__ void gat_aggregate_kernel(const float* __restrict__ h, const float* __restrict__ sv,
                                     const float* __restrict__ dv, const int* __restrict__ off,
                                     const int* __restrict__ csr, const float* __restrict__ bias,
                                     const float* __restrict__ bn_g, const float* __restrict__ bn_b,
                                     const float* __restrict__ bn_m, const float* __restrict__ bn_v,
                                     const float* __restrict__ x_res, float* __restrict__ x_out,
                                     int n) {
    int node = blockIdx.x * 4 + (threadIdx.x >> 6);
    int lane = threadIdx.x & 63;
    if (node >= n) return;
    int begin = off[node], end = off[node + 1];
    float d0 = dv[node * 2 + 0], d1 = dv[node * 2 + 1];

    float m0 = -3.0e38f, m1 = -3.0e38f;
    for (int i = begin + lane; i < end; i += 64) {
        int sc = csr[i];
        m0 = fmaxf(m0, lrelu(sv[sc * 2 + 0] + d0));
        m1 = fmaxf(m1, lrelu(sv[sc * 2 + 1] + d1));
    }
    m0 = wred_max(m0);
    m1 = wred_max(m1);

    float z0 = 0.f, z1 = 0.f;
    for (int i = begin + lane; i < end; i += 64) {
        int sc = csr[i];
        z0 += __expf(lrelu(sv[sc * 2 + 0] + d0) - m0);
        z1 += __expf(lrelu(sv[sc * 2 + 1] + d1) - m1);
    }
    z0 = wred_sum(z0);
    z1 = wred_sum(z1);
    float inv0 = 1.f / (z0 + 1e-16f);
    float inv1 = 1.f / (z1 + 1e-16f);

    float acc0 = 0.f, acc1 = 0.f;
    for (int i = begin; i < end; i++) {
        int sc = csr[i];
        float s0v = sv[sc * 2 + 0], s1v = sv[sc * 2 + 1];
        float a0 = __expf(lrelu(s0v + d0) - m0) * inv0;
        float a1 = __expf(lrelu(s1v + d1) - m1) * inv1;
        acc0 += a0 * h[sc * 128 + lane];
        acc1 += a1 * h[sc * 128 + 64 + lane];
    }

    #pragma unroll
    for (int p = 0; p < 2; p++) {
        int c = p * 64 + lane;
        float v = (p == 0 ? acc0 : acc1) + bias[c];
        float scale = bn_g[c] * rsqrtf(bn_v[c] + 1e-5f);
        v = (v - bn_m[c]) * scale + bn_b[c];
        if (x_res) v += x_res[node * 128 + c];
        x_out[node * 128 + c] = fmaxf(v, 0.f);
    }
}

// ---------------- graph boundaries (batch is sorted) ----------------
__global__ void bounds_kernel(const int* __restrict__ batch, int* __restrict__ starts) {
    int g = threadIdx.x;
    if (g > NG) return;
    int lo = 0, hi = NN;
    while (lo < hi) {
        int mid = (lo + hi) >> 1;
        if (batch[mid] < g) lo = mid + 1; else hi = mid;
    }
    starts[g] = lo;
}

// ---------------- global mean pool ----------------
__global__ void pool_kernel(const float* __restrict__ x, const int* __restrict__ starts,
                            float* __restrict__ xg) {
    int g = blockIdx.x;
    int c = threadIdx.x;
    int s0 = starts[g], e0 = starts[g + 1];
    float acc = 0.f;
    int node = s0;
    for (; node + 3 < e0; node += 4)
        acc += x[node * 128 + c] + x[(node + 1) * 128 + c] +
               x[(node + 2) * 128 + c] + x[(node + 3) * 128 + c];
    for (; node < e0; node++) acc += x[node * 128 + c];
    float cf = (float)(e0 - s0);
    xg[g * 128 + c] = acc / fmaxf(cf, 1.f);
}

// ---------------- lat/lon heads (output dtype follows input float dtype) ----------------
__global__ void head_kernel(const float* __restrict__ xg,
                            const float* __restrict__ w1a, const float* __restrict__ b1a,
                            const float* __restrict__ w2a, const float* __restrict__ b2a,
                            const float* __restrict__ w1o, const float* __restrict__ b1o,
                            const float* __restrict__ w2o, const float* __restrict__ b2o,
                            const int* __restrict__ flags, void* __restrict__ out) {
    int g = blockIdx.x;
    int wave = threadIdx.x >> 6;   // 0 = lat, 1 = lon
    int lane = threadIdx.x & 63;
    const float* w1 = wave ? w1o : w1a;
    const float* b1 = wave ? b1o : b1a;
    const float* w2 = wave ? w2o : w2a;
    const float* b2 = wave ? b2o : b2a;
    float acc = b1[lane];
    for (int c = 0; c < 128; c++)
        acc += xg[g * 128 + c] * w1[c * 64 + lane];
    acc = fmaxf(acc, 0.f);
    float contrib = wred_sum(acc * w2[lane]);
    if (lane == 0) {
        float r = contrib + b2[0];
        if (flags[0]) ((float*)out)[wave * NG + g] = r;
        else          ((bf16*)out)[wave * NG + g] = __float2bfloat16(r);
    }
}

extern "C" void kernel_launch(void* const* d_in, const int* in_sizes, int n_in,
                              void* d_out, int out_size, void* d_ws, size_t ws_size,
                              hipStream_t stream) {
    // float input table: d_in index and flat length, in setup_inputs order
    static const int fidx[32] = {0,1, 4,5,6,7,8,9, 10,11,12,13, 14,15,16,17,
                                 18,19,20,21, 22,23,24,25, 26,27,28,29, 30,31,32,33};
    static const int flen[32] = {200000, 3200000, 128, 32, 2048, 32, 4096, 64,
                                 8192, 128, 128, 128, 16384, 128, 128, 128,
                                 16384, 128, 128, 128, 384, 384, 384, 384,
                                 8192, 64, 64, 1, 8192, 64, 64, 1};
    CvtArgs ca;
    int O[32];
    int tot = 0, blk = 0;
    for (int i = 0; i < 32; i++) {
        ca.src[i] = d_in[fidx[i]];
        ca.len[i] = flen[i];
        O[i] = tot;
        ca.dst_off[i] = tot;
        ca.blk_base[i] = blk;
        tot += (flen[i] + 63) & ~63;
        blk += (flen[i] + 1023) / 1024;
    }
    ca.blk_base[32] = blk;

    char* w = (char*)d_ws;
    auto alloc = [&](size_t bytes) -> char* {
        char* p = w;
        w += (bytes + 255) & ~(size_t)255;
        return p;
    };
    int*   flags  = (int*)alloc(256);
    float* cf     = (float*)alloc((size_t)tot * 4);         // canonical fp32 inputs
    int*   ei32   = (int*)alloc((size_t)2 * NE * 4);
    int*   bat32  = (int*)alloc((size_t)NN * 4);
    float* xA     = (float*)alloc((size_t)NN * 128 * 4);
    float* xB     = (float*)alloc((size_t)NN * 128 * 4);
    float* x0     = xB;                                     // x0 dead before xB first written
    float* h      = (float*)alloc((size_t)NN * 128 * 4);
    float* sA     = (float*)alloc((size_t)NN * 2 * 4);
    float* dA     = (float*)alloc((size_t)NN * 2 * 4);
    int*   off    = (int*)alloc((size_t)(NN + 1) * 4);
    int*   cur    = (int*)alloc((size_t)NN * 4);
    int*   csr    = (int*)alloc((size_t)ET * 4);
    int*   starts = (int*)alloc((size_t)(NG + 1) * 4);
    float* xg     = (float*)alloc((size_t)NG * 128 * 4);

    detect_kernel<<<1, 256, 0, stream>>>((const unsigned int*)d_in[0],
                                         (const unsigned int*)d_in[2], flags);
    cvt_float_kernel<<<blk, 256, 0, stream>>>(ca, cf, flags);
    cvt_int_kernel<<<(2 * NE + 255) / 256, 256, 0, stream>>>(d_in[2], ei32, 2 * NE, flags);
    cvt_int_kernel<<<(NN + 255) / 256, 256, 0, stream>>>(d_in[3], bat32, NN, flags);

    hipMemsetAsync(cur, 0, (size_t)NN * 4, stream);

    encode_kernel<<<NN / 4, 256, 0, stream>>>(cf + O[0], cf + O[1], cf + O[2], cf + O[3],
                                              cf + O[4], cf + O[5], cf + O[6], cf + O[7],
                                              x0, NN);
    count_kernel<<<(ET + 255) / 256, 256, 0, stream>>>(ei32, cur);
    scan_kernel<<<1, 1024, 0, stream>>>(cur, off, cur, NN);
    fill_kernel<<<(ET + 255) / 256, 256, 0, stream>>>(ei32, cur, csr);

    // layer 0: K=64, in x0, out xA, no residual
    gemm_sd_kernel<<<NN / 8, 128, 0, stream>>>(x0, 64, cf + O[8], cf + O[9], cf + O[10],
                                               h, sA, dA, NN);
    gat_aggregate_kernel<<<NN / 4, 256, 0, stream>>>(h, sA, dA, off, csr, cf + O[11],
                                                     cf + O[20], cf + O[21], cf + O[22], cf + O[23],
                                                     nullptr, xA, NN);
    // layer 1: K=128, in xA, out xB, residual xA
    gemm_sd_kernel<<<NN / 8, 128, 0, stream>>>(xA, 128, cf + O[12], cf + O[13], cf + O[14],
                                               h, sA, dA, NN);
    gat_aggregate_kernel<<<NN / 4, 256, 0, stream>>>(h, sA, dA, off, csr, cf + O[15],
                                                     cf + O[20] + 128, cf + O[21] + 128,
                                                     cf + O[22] + 128, cf + O[23] + 128,
                                                     xA, xB, NN);
    // layer 2: K=128, in xB, out xA, residual xB
    gemm_sd_kernel<<<NN / 8, 128, 0, stream>>>(xB, 128, cf + O[16], cf + O[17], cf + O[18],
                                               h, sA, dA, NN);
    gat_aggregate_kernel<<<NN / 4, 256, 0, stream>>>(h, sA, dA, off, csr, cf + O[19],
                                                     cf + O[20] + 256, cf + O[21] + 256,
                                                     cf + O[22] + 256, cf + O[23] + 256,
                                                     xB, xA, NN);

    bounds_kernel<<<1, 512, 0, stream>>>(bat32, starts);
    pool_kernel<<<NG, 128, 0, stream>>>(xA, starts, xg);
    head_kernel<<<NG, 128, 0, stream>>>(xg,
                                        cf + O[24], cf + O[25], cf + O[26], cf + O[27],
                                        cf + O[28], cf + O[29], cf + O[30], cf + O[31],
                                        flags, d_out);
}

// Round 3
// 574.781 us; speedup vs baseline: 1.6272x; 1.6272x over previous
//
#include <hip/hip_runtime.h>
#include <hip/hip_bf16.h>
#include <stdint.h>

#define NN 50000
#define NNP 50048   // padded to 64-node gemm tiles
#define NE 800000
#define ET 850000   // NE + NN self loops
#define NG 256
#define CAP 128     // per-node edge capacity for LDS alpha cache

typedef __hip_bfloat16 bf16;
typedef __attribute__((ext_vector_type(8))) short short8;
typedef __attribute__((ext_vector_type(4))) float floatx4;

__device__ __forceinline__ float b2f(bf16 v) { return __bfloat162float(v); }
__device__ __forceinline__ float lrelu(float x) { return x > 0.f ? x : 0.2f * x; }
__device__ __forceinline__ short f2b(float f) {          // RNE bf16 round
    unsigned u = __float_as_uint(f);
    unsigned r = (u + 0x7FFFu + ((u >> 16) & 1u)) >> 16;
    return (short)r;
}
__device__ __forceinline__ float blo(unsigned u) { return __uint_as_float(u << 16); }
__device__ __forceinline__ float bhi(unsigned u) { return __uint_as_float(u & 0xFFFF0000u); }

__device__ __forceinline__ float wred_sum(float v) {
    for (int o = 32; o > 0; o >>= 1) v += __shfl_xor(v, o, 64);
    return v;
}
__device__ __forceinline__ float wred_max(float v) {
    for (int o = 32; o > 0; o >>= 1) v = fmaxf(v, __shfl_xor(v, o, 64));
    return v;
}

// ---------------- dtype detection ----------------
__global__ void detect_kernel(const unsigned int* __restrict__ meta_words,
                              const unsigned int* __restrict__ ei_words,
                              int* __restrict__ flags) {
    __shared__ int insane, odd_nonzero;
    if (threadIdx.x == 0) { insane = 0; odd_nonzero = 0; }
    __syncthreads();
    int cnt = 0;
    for (int k = 0; k < 8; k++) {
        unsigned int w = meta_words[threadIdx.x * 8 + k];
        int elo = (int)(((w & 0xFFFFu) >> 7) & 0xFF);
        int ehi = (int)(((w >> 16) >> 7) & 0xFF);
        if (elo >= 0x8D) cnt++;
        if (ehi >= 0x8D) cnt++;
    }
    if (cnt) atomicAdd(&insane, cnt);
    if (ei_words[threadIdx.x * 2 + 1] != 0u) atomicAdd(&odd_nonzero, 1);
    __syncthreads();
    if (threadIdx.x == 0) {
        flags[0] = (insane >= 4) ? 1 : 0;   // fp32 floats
        flags[1] = (odd_nonzero == 0) ? 1 : 0;  // int64 ints
    }
}

// ---------------- canonicalize float inputs to fp32 ----------------
struct CvtArgs {
    const void* src[32];
    int len[32];
    int dst_off[32];
    int blk_base[33];
};

__global__ void cvt_float_kernel(CvtArgs a, float* __restrict__ dst,
                                 const int* __restrict__ flags) {
    int b = blockIdx.x;
    int ai = 0;
    while (b >= a.blk_base[ai + 1]) ai++;
    int base = (b - a.blk_base[ai]) * 1024 + threadIdx.x;
    bool fp32 = flags[0] != 0;
    const float* sf = (const float*)a.src[ai];
    const bf16* sh = (const bf16*)a.src[ai];
    float* d = dst + a.dst_off[ai];
    int len = a.len[ai];
    #pragma unroll
    for (int u = 0; u < 4; u++) {
        int i = base + u * 256;
        if (i < len) d[i] = fp32 ? sf[i] : b2f(sh[i]);
    }
}

__global__ void cvt_int_kernel(const void* __restrict__ src, int* __restrict__ dst,
                               int n, const int* __restrict__ flags) {
    int i = blockIdx.x * 256 + threadIdx.x;
    if (i >= n) return;
    dst[i] = flags[1] ? (int)((const long long*)src)[i] : ((const int*)src)[i];
}

// ---------------- W^T bf16 prep: wt[n][k] = bf16(W[k][n]), W is [K][128] ----------------
__global__ void wt_kernel(const float* __restrict__ W, short* __restrict__ wt, int K) {
    int idx = blockIdx.x * 256 + threadIdx.x;    // over 128*K
    if (idx >= 128 * K) return;
    int nch = idx / K, k = idx % K;
    wt[idx] = f2b(W[k * 128 + nch]);
}

// ---------------- encoders + combiner -> x0 hi/lo bf16 [NNP][64] ----------------
__global__ void encode_kernel(const float* __restrict__ meta, const float* __restrict__ wavef,
                              const float* __restrict__ meta_w, const float* __restrict__ meta_b,
                              const float* __restrict__ wave_w, const float* __restrict__ wave_b,
                              const float* __restrict__ comb_w, const float* __restrict__ comb_b,
                              short* __restrict__ xhi, short* __restrict__ xlo, int n) {
    int w = threadIdx.x >> 6;
    int lane = threadIdx.x & 63;
    int node = blockIdx.x * 4 + w;
    __shared__ float xs[4][64];

    if (node < n) {
        float acc;
        if (lane < 32) {
            acc = meta_b[lane];
            #pragma unroll
            for (int k = 0; k < 4; k++)
                acc += meta[node * 4 + k] * meta_w[k * 32 + lane];
        } else {
            int c = lane - 32;
            acc = wave_b[c];
            for (int k = 0; k < 64; k++)
                acc += wavef[node * 64 + k] * wave_w[k * 32 + c];
        }
        xs[w][lane] = fmaxf(acc, 0.f);
    }
    __syncthreads();
    if (node < n) {
        float acc2 = comb_b[lane];
        for (int k = 0; k < 64; k++)
            acc2 += xs[w][k] * comb_w[k * 64 + lane];
        float v = fmaxf(acc2, 0.f);
        short h = f2b(v);
        xhi[node * 64 + lane] = h;
        xlo[node * 64 + lane] = f2b(v - __uint_as_float(((unsigned)(unsigned short)h) << 16));
    }
}

// ---------------- CSR build ----------------
__global__ void count_kernel(const int* __restrict__ ei, int* __restrict__ cnt) {
    int i = blockIdx.x * blockDim.x + threadIdx.x;
    if (i >= ET) return;
    int dst = (i < NE) ? ei[NE + i] : (i - NE);
    atomicAdd(&cnt[dst], 1);
}

__global__ void scan1_kernel(const int* __restrict__ cnt, int* __restrict__ excl,
                             int* __restrict__ bsum, int n) {
    __shared__ int buf[256];
    int gid = blockIdx.x * 256 + threadIdx.x;
    int v = (gid < n) ? cnt[gid] : 0;
    buf[threadIdx.x] = v;
    __syncthreads();
    for (int o = 1; o < 256; o <<= 1) {
        int t = (threadIdx.x >= o) ? buf[threadIdx.x - o] : 0;
        __syncthreads();
        buf[threadIdx.x] += t;
        __syncthreads();
    }
    if (gid < n) excl[gid] = buf[threadIdx.x] - v;
    if (threadIdx.x == 255) bsum[blockIdx.x] = buf[255];
}

__global__ void scan2_kernel(int* __restrict__ bsum, int nb) {
    __shared__ int buf[256];
    int tid = threadIdx.x;
    int v = (tid < nb) ? bsum[tid] : 0;
    buf[tid] = v;
    __syncthreads();
    for (int o = 1; o < 256; o <<= 1) {
        int t = (tid >= o) ? buf[tid - o] : 0;
        __syncthreads();
        buf[tid] += t;
        __syncthreads();
    }
    if (tid < nb) bsum[tid] = buf[tid] - v;   // exclusive
}

__global__ void scan3_kernel(const int* __restrict__ excl, const int* __restrict__ bsum,
                             int* __restrict__ off, int* __restrict__ cur, int n) {
    int gid = blockIdx.x * 256 + threadIdx.x;
    if (gid < n) {
        int e = excl[gid] + bsum[blockIdx.x];
        off[gid] = e;
        cur[gid] = e;
    }
    if (gid == 0) off[n] = ET;
}

__global__ void fill_kernel(const int* __restrict__ ei, int* __restrict__ cur,
                            int* __restrict__ csr) {
    int i = blockIdx.x * blockDim.x + threadIdx.x;
    if (i >= ET) return;
    int src, dst;
    if (i < NE) { src = ei[i]; dst = ei[NE + i]; }
    else        { src = i - NE; dst = i - NE; }
    int pos = atomicAdd(&cur[dst], 1);
    csr[pos] = src;
}

// ---------------- MFMA GEMM: h[NN][128] bf16 = (xhi+xlo)[NN][K] @ W[K][128] ----------------
__global__ __launch_bounds__(256) void gemm_mfma_kernel(
        const short* __restrict__ xhi, const short* __restrict__ xlo,
        const short* __restrict__ wt,   // [128][K] bf16 (W^T)
        short* __restrict__ h, int K, int n) {
    int wave = threadIdx.x >> 6;
    int lane = threadIdx.x & 63;
    int row0 = (blockIdx.x * 4 + wave) * 16;
    int m16 = lane & 15;
    int kq = (lane >> 4) * 8;

    const short* pa_hi = xhi + (size_t)(row0 + m16) * K + kq;
    const short* pa_lo = xlo + (size_t)(row0 + m16) * K + kq;

    floatx4 acc[8];
    #pragma unroll
    for (int c = 0; c < 8; c++) acc[c] = (floatx4)(0.f);

    for (int ks = 0; ks < K; ks += 32) {
        short8 ah = *(const short8*)(pa_hi + ks);
        short8 al = *(const short8*)(pa_lo + ks);
        #pragma unroll
        for (int c = 0; c < 8; c++) {
            short8 b = *(const short8*)(wt + (size_t)(c * 16 + m16) * K + ks + kq);
            acc[c] = __builtin_amdgcn_mfma_f32_16x16x32_bf16(ah, b, acc[c], 0, 0, 0);
            acc[c] = __builtin_amdgcn_mfma_f32_16x16x32_bf16(al, b, acc[c], 0, 0, 0);
        }
    }
    int rbase = (lane >> 4) * 4;
    #pragma unroll
    for (int c = 0; c < 8; c++) {
        #pragma unroll
        for (int r = 0; r < 4; r++) {
            int node = row0 + rbase + r;
            if (node < n) h[(size_t)node * 128 + c * 16 + m16] = f2b(acc[c][r]);
        }
    }
}

// ---------------- attention logits s,d from h (bf16 pairs) ----------------
__global__ void sd_kernel(const unsigned* __restrict__ hp,
                          const float* __restrict__ a_s, const float* __restrict__ a_d,
                          float* __restrict__ s, float* __restrict__ d, int n) {
    int node = blockIdx.x * 4 + (threadIdx.x >> 6);
    int lane = threadIdx.x & 63;
    if (node >= n) return;
    unsigned u = hp[(size_t)node * 64 + lane];
    float f0 = blo(u), f1 = bhi(u);
    int c0 = 2 * lane;
    float ps = f0 * a_s[c0] + f1 * a_s[c0 + 1];
    float pd = f0 * a_d[c0] + f1 * a_d[c0 + 1];
    #pragma unroll
    for (int o = 1; o < 32; o <<= 1) {
        ps += __shfl_xor(ps, o, 64);
        pd += __shfl_xor(pd, o, 64);
    }
    if ((lane & 31) == 0) {
        int head = lane >> 5;
        s[node * 2 + head] = ps;
        d[node * 2 + head] = pd;
    }
}

// ---------------- edge softmax + aggregation + bias + BN + res + relu ----------------
__global__ __launch_bounds__(256) void gat_aggregate_kernel(
        const unsigned* __restrict__ hp, const float* __restrict__ sv,
        const float* __restrict__ dv, const int* __restrict__ off,
        const int* __restrict__ csr, const float* __restrict__ bias,
        const float* __restrict__ bn_g, const float* __restrict__ bn_b,
        const float* __restrict__ bn_m, const float* __restrict__ bn_v,
        const unsigned* __restrict__ res_hi, const unsigned* __restrict__ res_lo,
        unsigned* __restrict__ out_hi, unsigned* __restrict__ out_lo, int n) {
    __shared__ float exs[4][CAP][2];
    __shared__ int scs[4][CAP];
    int w = threadIdx.x >> 6;
    int lane = threadIdx.x & 63;
    int node = blockIdx.x * 4 + w;
    bool ok = node < n;
    int begin = 0, end = 0, deg = 0;
    float d0 = 0.f, d1 = 0.f;
    if (ok) {
        begin = off[node]; end = off[node + 1]; deg = end - begin;
        d0 = dv[node * 2 + 0]; d1 = dv[node * 2 + 1];
    }
    bool fits = deg <= CAP;
    float inv0 = 0.f, inv1 = 0.f, m0 = 0.f, m1 = 0.f;

    if (ok && fits) {
        int i0 = begin + lane, i1 = begin + 64 + lane;
        int sa = (i0 < end) ? csr[i0] : -1;
        int sb = (i1 < end) ? csr[i1] : -1;
        float e0a = -3e38f, e1a = -3e38f, e0b = -3e38f, e1b = -3e38f;
        if (sa >= 0) {
            float2 sp = *(const float2*)(sv + sa * 2);
            e0a = lrelu(sp.x + d0); e1a = lrelu(sp.y + d1);
        }
        if (sb >= 0) {
            float2 sp = *(const float2*)(sv + sb * 2);
            e0b = lrelu(sp.x + d0); e1b = lrelu(sp.y + d1);
        }
        m0 = wred_max(fmaxf(e0a, e0b));
        m1 = wred_max(fmaxf(e1a, e1b));
        float x0a = 0.f, x1a = 0.f, x0b = 0.f, x1b = 0.f;
        if (sa >= 0) {
            x0a = __expf(e0a - m0); x1a = __expf(e1a - m1);
            exs[w][lane][0] = x0a; exs[w][lane][1] = x1a; scs[w][lane] = sa;
        }
        if (sb >= 0) {
            x0b = __expf(e0b - m0); x1b = __expf(e1b - m1);
            exs[w][lane + 64][0] = x0b; exs[w][lane + 64][1] = x1b; scs[w][lane + 64] = sb;
        }
        float z0 = wred_sum(x0a + x0b);
        float z1 = wred_sum(x1a + x1b);
        inv0 = 1.f / (z0 + 1e-16f);
        inv1 = 1.f / (z1 + 1e-16f);
    }
    __syncthreads();
    if (!ok) return;

    float acc0 = 0.f, acc1 = 0.f;
    bool head0 = lane < 32;
    if (fits) {
        int i = 0;
        for (; i + 1 < deg; i += 2) {
            int sA_ = scs[w][i], sB_ = scs[w][i + 1];
            float aa = head0 ? exs[w][i][0] : exs[w][i][1];
            float bb = head0 ? exs[w][i + 1][0] : exs[w][i + 1][1];
            unsigned u0 = hp[(size_t)sA_ * 64 + lane];
            unsigned u1 = hp[(size_t)sB_ * 64 + lane];
            acc0 += aa * blo(u0) + bb * blo(u1);
            acc1 += aa * bhi(u0) + bb * bhi(u1);
        }
        if (i < deg) {
            int sA_ = scs[w][i];
            float aa = head0 ? exs[w][i][0] : exs[w][i][1];
            unsigned u0 = hp[(size_t)sA_ * 64 + lane];
            acc0 += aa * blo(u0);
            acc1 += aa * bhi(u0);
        }
        float inv = head0 ? inv0 : inv1;
        acc0 *= inv;
        acc1 *= inv;
    } else {
        // fallback (deg > CAP): 3-pass sequential recompute
        float mm0 = -3e38f, mm1 = -3e38f;
        for (int i = begin + lane; i < end; i += 64) {
            int sc = csr[i];
            float2 sp = *(const float2*)(sv + sc * 2);
            mm0 = fmaxf(mm0, lrelu(sp.x + d0));
            mm1 = fmaxf(mm1, lrelu(sp.y + d1));
        }
        mm0 = wred_max(mm0); mm1 = wred_max(mm1);
        float z0 = 0.f, z1 = 0.f;
        for (int i = begin + lane; i < end; i += 64) {
            int sc = csr[i];
            float2 sp = *(const float2*)(sv + sc * 2);
            z0 += __expf(lrelu(sp.x + d0) - mm0);
            z1 += __expf(lrelu(sp.y + d1) - mm1);
        }
        z0 = wred_sum(z0); z1 = wred_sum(z1);
        float i0_ = 1.f / (z0 + 1e-16f), i1_ = 1.f / (z1 + 1e-16f);
        for (int i = begin; i < end; i++) {
            int sc = csr[i];
            float2 sp = *(const float2*)(sv + sc * 2);
            float a0 = __expf(lrelu(sp.x + d0) - mm0) * i0_;
            float a1 = __expf(lrelu(sp.y + d1) - mm1) * i1_;
            float a = head0 ? a0 : a1;
            unsigned u0 = hp[(size_t)sc * 64 + lane];
            acc0 += a * blo(u0);
            acc1 += a * bhi(u0);
        }
    }

    // epilogue: channels c0=2*lane, c1=2*lane+1
    int c0 = 2 * lane, c1 = c0 + 1;
    float v0 = acc0 + bias[c0];
    float v1 = acc1 + bias[c1];
    v0 = (v0 - bn_m[c0]) * (bn_g[c0] * rsqrtf(bn_v[c0] + 1e-5f)) + bn_b[c0];
    v1 = (v1 - bn_m[c1]) * (bn_g[c1] * rsqrtf(bn_v[c1] + 1e-5f)) + bn_b[c1];
    if (res_hi) {
        unsigned rh = res_hi[(size_t)node * 64 + lane];
        unsigned rl = res_lo[(size_t)node * 64 + lane];
        v0 += blo(rh) + blo(rl);
        v1 += bhi(rh) + bhi(rl);
    }
    v0 = fmaxf(v0, 0.f);
    v1 = fmaxf(v1, 0.f);
    unsigned h0 = (unsigned)(unsigned short)f2b(v0);
    unsigned h1 = (unsigned)(unsigned short)f2b(v1);
    float r0 = v0 - __uint_as_float(h0 << 16);
    float r1 = v1 - __uint_as_float(h1 << 16);
    unsigned l0 = (unsigned)(unsigned short)f2b(r0);
    unsigned l1 = (unsigned)(unsigned short)f2b(r1);
    out_hi[(size_t)node * 64 + lane] = h0 | (h1 << 16);
    out_lo[(size_t)node * 64 + lane] = l0 | (l1 << 16);
}

// ---------------- graph boundaries ----------------
__global__ void bounds_kernel(const int* __restrict__ batch, int* __restrict__ starts) {
    int g = threadIdx.x;
    if (g > NG) return;
    int lo = 0, hi = NN;
    while (lo < hi) {
        int mid = (lo + hi) >> 1;
        if (batch[mid] < g) lo = mid + 1; else hi = mid;
    }
    starts[g] = lo;
}

// ---------------- global mean pool (x stored as hi/lo bf16) ----------------
__global__ void pool_kernel(const unsigned short* __restrict__ xh,
                            const unsigned short* __restrict__ xl,
                            const int* __restrict__ starts, float* __restrict__ xg) {
    int g = blockIdx.x;
    int c = threadIdx.x;
    int s0 = starts[g], e0 = starts[g + 1];
    float acc = 0.f;
    int node = s0;
    for (; node + 1 < e0; node += 2) {
        size_t i0 = (size_t)node * 128 + c, i1 = i0 + 128;
        acc += __uint_as_float(((unsigned)xh[i0]) << 16) + __uint_as_float(((unsigned)xl[i0]) << 16)
             + __uint_as_float(((unsigned)xh[i1]) << 16) + __uint_as_float(((unsigned)xl[i1]) << 16);
    }
    for (; node < e0; node++) {
        size_t i0 = (size_t)node * 128 + c;
        acc += __uint_as_float(((unsigned)xh[i0]) << 16) + __uint_as_float(((unsigned)xl[i0]) << 16);
    }
    float cf = (float)(e0 - s0);
    xg[g * 128 + c] = acc / fmaxf(cf, 1.f);
}

// ---------------- lat/lon heads ----------------
__global__ void head_kernel(const float* __restrict__ xg,
                            const float* __restrict__ w1a, const float* __restrict__ b1a,
                            const float* __restrict__ w2a, const float* __restrict__ b2a,
                            const float* __restrict__ w1o, const float* __restrict__ b1o,
                            const float* __restrict__ w2o, const float* __restrict__ b2o,
                            const int* __restrict__ flags, void* __restrict__ out) {
    int g = blockIdx.x;
    int wave = threadIdx.x >> 6;
    int lane = threadIdx.x & 63;
    const float* w1 = wave ? w1o : w1a;
    const float* b1 = wave ? b1o : b1a;
    const float* w2 = wave ? w2o : w2a;
    const float* b2 = wave ? b2o : b2a;
    float acc = b1[lane];
    for (int c = 0; c < 128; c++)
        acc += xg[g * 128 + c] * w1[c * 64 + lane];
    acc = fmaxf(acc, 0.f);
    float contrib = wred_sum(acc * w2[lane]);
    if (lane == 0) {
        float r = contrib + b2[0];
        if (flags[0]) ((float*)out)[wave * NG + g] = r;
        else          ((bf16*)out)[wave * NG + g] = __float2bfloat16(r);
    }
}

extern "C" void kernel_launch(void* const* d_in, const int* in_sizes, int n_in,
                              void* d_out, int out_size, void* d_ws, size_t ws_size,
                              hipStream_t stream) {
    static const int fidx[32] = {0,1, 4,5,6,7,8,9, 10,11,12,13, 14,15,16,17,
                                 18,19,20,21, 22,23,24,25, 26,27,28,29, 30,31,32,33};
    static const int flen[32] = {200000, 3200000, 128, 32, 2048, 32, 4096, 64,
                                 8192, 128, 128, 128, 16384, 128, 128, 128,
                                 16384, 128, 128, 128, 384, 384, 384, 384,
                                 8192, 64, 64, 1, 8192, 64, 64, 1};
    CvtArgs ca;
    int O[32];
    int tot = 0, blk = 0;
    for (int i = 0; i < 32; i++) {
        ca.src[i] = d_in[fidx[i]];
        ca.len[i] = flen[i];
        O[i] = tot;
        ca.dst_off[i] = tot;
        ca.blk_base[i] = blk;
        tot += (flen[i] + 63) & ~63;
        blk += (flen[i] + 1023) / 1024;
    }
    ca.blk_base[32] = blk;

    char* w = (char*)d_ws;
    auto alloc = [&](size_t bytes) -> char* {
        char* p = w;
        w += (bytes + 255) & ~(size_t)255;
        return p;
    };
    int*   flags  = (int*)alloc(256);
    float* cf     = (float*)alloc((size_t)tot * 4);
    int*   ei32   = (int*)alloc((size_t)2 * NE * 4);
    int*   bat32  = (int*)alloc((size_t)NN * 4);
    short* x0hi   = (short*)alloc((size_t)NNP * 64 * 2);
    short* x0lo   = (short*)alloc((size_t)NNP * 64 * 2);
    short* xAhi   = (short*)alloc((size_t)NNP * 128 * 2);
    short* xAlo   = (short*)alloc((size_t)NNP * 128 * 2);
    short* xBhi   = (short*)alloc((size_t)NNP * 128 * 2);
    short* xBlo   = (short*)alloc((size_t)NNP * 128 * 2);
    short* h      = (short*)alloc((size_t)NNP * 128 * 2);
    float* sA     = (float*)alloc((size_t)NN * 2 * 4);
    float* dA     = (float*)alloc((size_t)NN * 2 * 4);
    int*   off    = (int*)alloc((size_t)(NN + 1) * 4);
    int*   cur    = (int*)alloc((size_t)NN * 4);
    int*   excl   = (int*)alloc((size_t)NN * 4);
    int*   bsum   = (int*)alloc(256 * 4);
    int*   csr    = (int*)alloc((size_t)ET * 4);
    int*   starts = (int*)alloc((size_t)(NG + 1) * 4);
    float* xg     = (float*)alloc((size_t)NG * 128 * 4);
    short* wt0    = (short*)alloc((size_t)128 * 64 * 2);
    short* wt1    = (short*)alloc((size_t)128 * 128 * 2);
    short* wt2    = (short*)alloc((size_t)128 * 128 * 2);

    detect_kernel<<<1, 256, 0, stream>>>((const unsigned int*)d_in[0],
                                         (const unsigned int*)d_in[2], flags);
    cvt_float_kernel<<<blk, 256, 0, stream>>>(ca, cf, flags);
    cvt_int_kernel<<<(2 * NE + 255) / 256, 256, 0, stream>>>(d_in[2], ei32, 2 * NE, flags);
    cvt_int_kernel<<<(NN + 255) / 256, 256, 0, stream>>>(d_in[3], bat32, NN, flags);

    wt_kernel<<<(128 * 64 + 255) / 256, 256, 0, stream>>>(cf + O[8], wt0, 64);
    wt_kernel<<<(128 * 128 + 255) / 256, 256, 0, stream>>>(cf + O[12], wt1, 128);
    wt_kernel<<<(128 * 128 + 255) / 256, 256, 0, stream>>>(cf + O[16], wt2, 128);

    hipMemsetAsync(cur, 0, (size_t)NN * 4, stream);

    encode_kernel<<<(NN + 3) / 4, 256, 0, stream>>>(cf + O[0], cf + O[1], cf + O[2], cf + O[3],
                                                    cf + O[4], cf + O[5], cf + O[6], cf + O[7],
                                                    x0hi, x0lo, NN);
    count_kernel<<<(ET + 255) / 256, 256, 0, stream>>>(ei32, cur);
    int nb = (NN + 255) / 256;
    scan1_kernel<<<nb, 256, 0, stream>>>(cur, excl, bsum, NN);
    scan2_kernel<<<1, 256, 0, stream>>>(bsum, nb);
    scan3_kernel<<<nb, 256, 0, stream>>>(excl, bsum, off, cur, NN);
    fill_kernel<<<(ET + 255) / 256, 256, 0, stream>>>(ei32, cur, csr);

    int gblk = NNP / 64;
    // layer 0
    gemm_mfma_kernel<<<gblk, 256, 0, stream>>>(x0hi, x0lo, wt0, h, 64, NN);
    sd_kernel<<<(NN + 3) / 4, 256, 0, stream>>>((const unsigned*)h, cf + O[9], cf + O[10],
                                                sA, dA, NN);
    gat_aggregate_kernel<<<(NN + 3) / 4, 256, 0, stream>>>(
        (const unsigned*)h, sA, dA, off, csr, cf + O[11],
        cf + O[20], cf + O[21], cf + O[22], cf + O[23],
        nullptr, nullptr, (unsigned*)xAhi, (unsigned*)xAlo, NN);
    // layer 1
    gemm_mfma_kernel<<<gblk, 256, 0, stream>>>(xAhi, xAlo, wt1, h, 128, NN);
    sd_kernel<<<(NN + 3) / 4, 256, 0, stream>>>((const unsigned*)h, cf + O[13], cf + O[14],
                                                sA, dA, NN);
    gat_aggregate_kernel<<<(NN + 3) / 4, 256, 0, stream>>>(
        (const unsigned*)h, sA, dA, off, csr, cf + O[15],
        cf + O[20] + 128, cf + O[21] + 128, cf + O[22] + 128, cf + O[23] + 128,
        (const unsigned*)xAhi, (const unsigned*)xAlo, (unsigned*)xBhi, (unsigned*)xBlo, NN);
    // layer 2
    gemm_mfma_kernel<<<gblk, 256, 0, stream>>>(xBhi, xBlo, wt2, h, 128, NN);
    sd_kernel<<<(NN + 3) / 4, 256, 0, stream>>>((const unsigned*)h, cf + O[17], cf + O[18],
                                                sA, dA, NN);
    gat_aggregate_kernel<<<(NN + 3) / 4, 256, 0, stream>>>(
        (const unsigned*)h, sA, dA, off, csr, cf + O[19],
        cf + O[20] + 256, cf + O[21] + 256, cf + O[22] + 256, cf + O[23] + 256,
        (const unsigned*)xBhi, (const unsigned*)xBlo, (unsigned*)xAhi, (unsigned*)xAlo, NN);

    bounds_kernel<<<1, 512, 0, stream>>>(bat32, starts);
    pool_kernel<<<NG, 128, 0, stream>>>((const unsigned short*)xAhi, (const unsigned short*)xAlo,
                                        starts, xg);
    head_kernel<<<NG, 128, 0, stream>>>(xg,
                                        cf + O[24], cf + O[25], cf + O[26], cf + O[27],
                                        cf + O[28], cf + O[29], cf + O[30], cf + O[31],
                                        flags, d_out);
}

// Round 4
// 504.350 us; speedup vs baseline: 1.8544x; 1.1396x over previous
//
#include <hip/hip_runtime.h>
#include <hip/hip_bf16.h>
#include <stdint.h>

#define NN 50000
#define NNP 50048   // padded to 64-node gemm tiles
#define NE 800000
#define ET 850000   // NE + NN self loops
#define NG 256
#define CAP 128     // per-node edge capacity for LDS alpha cache

typedef __hip_bfloat16 bf16;
typedef __attribute__((ext_vector_type(8))) short short8;
typedef __attribute__((ext_vector_type(4))) float floatx4;

__device__ __forceinline__ float b2f(bf16 v) { return __bfloat162float(v); }
__device__ __forceinline__ float lrelu(float x) { return x > 0.f ? x : 0.2f * x; }
__device__ __forceinline__ short f2b(float f) {          // RNE bf16 round
    unsigned u = __float_as_uint(f);
    unsigned r = (u + 0x7FFFu + ((u >> 16) & 1u)) >> 16;
    return (short)r;
}
__device__ __forceinline__ float sh2f(short s) { return __uint_as_float(((unsigned)(unsigned short)s) << 16); }
__device__ __forceinline__ float blo(unsigned u) { return __uint_as_float(u << 16); }
__device__ __forceinline__ float bhi(unsigned u) { return __uint_as_float(u & 0xFFFF0000u); }

__device__ __forceinline__ float wred_sum(float v) {
    for (int o = 32; o > 0; o >>= 1) v += __shfl_xor(v, o, 64);
    return v;
}
__device__ __forceinline__ float wred_max(float v) {
    for (int o = 32; o > 0; o >>= 1) v = fmaxf(v, __shfl_xor(v, o, 64));
    return v;
}

// ---------------- dtype detection ----------------
__global__ void detect_kernel(const unsigned int* __restrict__ meta_words,
                              const unsigned int* __restrict__ ei_words,
                              int* __restrict__ flags) {
    __shared__ int insane, odd_nonzero;
    if (threadIdx.x == 0) { insane = 0; odd_nonzero = 0; }
    __syncthreads();
    int cnt = 0;
    for (int k = 0; k < 8; k++) {
        unsigned int w = meta_words[threadIdx.x * 8 + k];
        int elo = (int)(((w & 0xFFFFu) >> 7) & 0xFF);
        int ehi = (int)(((w >> 16) >> 7) & 0xFF);
        if (elo >= 0x8D) cnt++;
        if (ehi >= 0x8D) cnt++;
    }
    if (cnt) atomicAdd(&insane, cnt);
    if (ei_words[threadIdx.x * 2 + 1] != 0u) atomicAdd(&odd_nonzero, 1);
    __syncthreads();
    if (threadIdx.x == 0) {
        flags[0] = (insane >= 4) ? 1 : 0;       // fp32 floats
        flags[1] = (odd_nonzero == 0) ? 1 : 0;  // int64 ints
    }
}

// ---------------- canonicalize float inputs to fp32 ----------------
struct CvtArgs {
    const void* src[32];
    int len[32];
    int dst_off[32];
    int blk_base[33];
};

__global__ void cvt_float_kernel(CvtArgs a, float* __restrict__ dst,
                                 const int* __restrict__ flags) {
    int b = blockIdx.x;
    int ai = 0;
    while (b >= a.blk_base[ai + 1]) ai++;
    int base = (b - a.blk_base[ai]) * 1024 + threadIdx.x;
    bool fp32 = flags[0] != 0;
    const float* sf = (const float*)a.src[ai];
    const bf16* sh = (const bf16*)a.src[ai];
    float* d = dst + a.dst_off[ai];
    int len = a.len[ai];
    #pragma unroll
    for (int u = 0; u < 4; u++) {
        int i = base + u * 256;
        if (i < len) d[i] = fp32 ? sf[i] : b2f(sh[i]);
    }
}

__global__ void cvt_int_kernel(const void* __restrict__ ei_src, const void* __restrict__ bat_src,
                               int* __restrict__ ei32, int* __restrict__ bat32,
                               const int* __restrict__ flags) {
    int i = blockIdx.x * 256 + threadIdx.x;
    bool i64 = flags[1] != 0;
    if (i < 2 * NE) {
        ei32[i] = i64 ? (int)((const long long*)ei_src)[i] : ((const int*)ei_src)[i];
    } else {
        int j = i - 2 * NE;
        if (j < NN)
            bat32[j] = i64 ? (int)((const long long*)bat_src)[j] : ((const int*)bat_src)[j];
    }
}

// ---------------- all weight transposes -> bf16, one launch ----------------
// ranges: wt0[128][64], wt1[128][128], wt2[128][128], wavewT[32][64], combwT[64][64]
__global__ void wt_all_kernel(const float* __restrict__ cf, short* __restrict__ wtall,
                              short* __restrict__ wavewT, short* __restrict__ combwT,
                              int O8, int O12, int O16, int O4, int O6) {
    int idx = blockIdx.x * 256 + threadIdx.x;   // < 47104
    const float* src; short* dst; int K, N, loc;
    if (idx < 8192)        { src = cf + O8;  dst = wtall;          K = 64;  N = 128; loc = idx; }
    else if (idx < 24576)  { src = cf + O12; dst = wtall + 8192;   K = 128; N = 128; loc = idx - 8192; }
    else if (idx < 40960)  { src = cf + O16; dst = wtall + 24576;  K = 128; N = 128; loc = idx - 24576; }
    else if (idx < 43008)  { src = cf + O4;  dst = wavewT;         K = 64;  N = 32;  loc = idx - 40960; }
    else if (idx < 47104)  { src = cf + O6;  dst = combwT;         K = 64;  N = 64;  loc = idx - 43008; }
    else return;
    int nch = loc / K, k = loc % K;
    dst[loc] = f2b(src[k * N + nch]);
}

// ---------------- wavef -> bf16 hi/lo [NNP][64], zero-padded rows ----------------
__global__ void prep_wf_kernel(const void* __restrict__ src, short* __restrict__ hi,
                               short* __restrict__ lo, const int* __restrict__ flags) {
    int i = blockIdx.x * 256 + threadIdx.x;
    if (i >= NNP * 64) return;
    short h = 0, l = 0;
    if (i < NN * 64) {
        if (flags[0]) {
            float v = ((const float*)src)[i];
            h = f2b(v);
            l = f2b(v - sh2f(h));
        } else {
            h = ((const short*)src)[i];
        }
    }
    hi[i] = h;
    lo[i] = l;
}

// ---------------- MFMA encoder: me|we -> combiner -> x0 hi/lo [NNP][64] ----------------
__global__ __launch_bounds__(256) void encode_mfma_kernel(
        const float* __restrict__ meta, const float* __restrict__ meta_w,
        const float* __restrict__ meta_b,
        const short* __restrict__ wfhi, const short* __restrict__ wflo,
        const short* __restrict__ wavewT, const float* __restrict__ wave_b,
        const short* __restrict__ combwT, const float* __restrict__ comb_b,
        short* __restrict__ xhi, short* __restrict__ xlo) {
    __shared__ short xc_hi[64][72];   // +8 pad: 2-way LDS conflicts only
    __shared__ short xc_lo[64][72];
    int t = threadIdx.x;
    int wave = t >> 6, lane = t & 63;
    int m16 = lane & 15, quad = lane >> 4;
    int nblk = blockIdx.x * 64;

    // meta encoder (VALU, cooperative over block): 64 nodes x 32 ch
    #pragma unroll
    for (int u = 0; u < 8; u++) {
        int idx = u * 256 + t;
        int node_l = idx >> 5, ch = idx & 31;
        int node = nblk + node_l;
        float acc = meta_b[ch];
        if (node < NN) {
            #pragma unroll
            for (int k = 0; k < 4; k++)
                acc += meta[node * 4 + k] * meta_w[k * 32 + ch];
        }
        float v = fmaxf(acc, 0.f);
        short hh = f2b(v);
        xc_hi[node_l][ch] = hh;
        xc_lo[node_l][ch] = f2b(v - sh2f(hh));
    }

    // wave encoder (MFMA): this wave's 16-node stripe
    int row0 = nblk + wave * 16;
    const short* pah = wfhi + (size_t)(row0 + m16) * 64 + quad * 8;
    const short* pal = wflo + (size_t)(row0 + m16) * 64 + quad * 8;
    floatx4 wacc[2];
    wacc[0] = (floatx4)(0.f); wacc[1] = (floatx4)(0.f);
    #pragma unroll
    for (int ks = 0; ks < 64; ks += 32) {
        short8 ah = *(const short8*)(pah + ks);
        short8 al = *(const short8*)(pal + ks);
        #pragma unroll
        for (int c = 0; c < 2; c++) {
            short8 b = *(const short8*)(wavewT + (c * 16 + m16) * 64 + ks + quad * 8);
            wacc[c] = __builtin_amdgcn_mfma_f32_16x16x32_bf16(ah, b, wacc[c], 0, 0, 0);
            wacc[c] = __builtin_amdgcn_mfma_f32_16x16x32_bf16(al, b, wacc[c], 0, 0, 0);
        }
    }
    #pragma unroll
    for (int c = 0; c < 2; c++) {
        float bb = wave_b[c * 16 + m16];
        #pragma unroll
        for (int r = 0; r < 4; r++) {
            int node_l = wave * 16 + quad * 4 + r;
            int ch = 32 + c * 16 + m16;
            float v = fmaxf(wacc[c][r] + bb, 0.f);
            short hh = f2b(v);
            xc_hi[node_l][ch] = hh;
            xc_lo[node_l][ch] = f2b(v - sh2f(hh));
        }
    }
    __syncthreads();

    // combiner (MFMA): [16,64] @ [64,64]
    floatx4 acc2[4];
    #pragma unroll
    for (int c = 0; c < 4; c++) acc2[c] = (floatx4)(0.f);
    #pragma unroll
    for (int ks = 0; ks < 64; ks += 32) {
        short8 ah = *(const short8*)&xc_hi[wave * 16 + m16][ks + quad * 8];
        short8 al = *(const short8*)&xc_lo[wave * 16 + m16][ks + quad * 8];
        #pragma unroll
        for (int c = 0; c < 4; c++) {
            short8 b = *(const short8*)(combwT + (c * 16 + m16) * 64 + ks + quad * 8);
            acc2[c] = __builtin_amdgcn_mfma_f32_16x16x32_bf16(ah, b, acc2[c], 0, 0, 0);
            acc2[c] = __builtin_amdgcn_mfma_f32_16x16x32_bf16(al, b, acc2[c], 0, 0, 0);
        }
    }
    #pragma unroll
    for (int c = 0; c < 4; c++) {
        int ch = c * 16 + m16;
        float bb = comb_b[ch];
        #pragma unroll
        for (int r = 0; r < 4; r++) {
            int node = nblk + wave * 16 + quad * 4 + r;   // < NNP always
            float v = fmaxf(acc2[c][r] + bb, 0.f);
            short hh = f2b(v);
            xhi[(size_t)node * 64 + ch] = hh;
            xlo[(size_t)node * 64 + ch] = f2b(v - sh2f(hh));
        }
    }
}

// ---------------- CSR build ----------------
__global__ void count_kernel(const int* __restrict__ ei, int* __restrict__ cnt) {
    int i = blockIdx.x * blockDim.x + threadIdx.x;
    if (i >= ET) return;
    int dst = (i < NE) ? ei[NE + i] : (i - NE);
    atomicAdd(&cnt[dst], 1);
}

__global__ void scan1_kernel(const int* __restrict__ cnt, int* __restrict__ excl,
                             int* __restrict__ bsum, int n) {
    __shared__ int buf[256];
    int gid = blockIdx.x * 256 + threadIdx.x;
    int v = (gid < n) ? cnt[gid] : 0;
    buf[threadIdx.x] = v;
    __syncthreads();
    for (int o = 1; o < 256; o <<= 1) {
        int t = (threadIdx.x >= o) ? buf[threadIdx.x - o] : 0;
        __syncthreads();
        buf[threadIdx.x] += t;
        __syncthreads();
    }
    if (gid < n) excl[gid] = buf[threadIdx.x] - v;
    if (threadIdx.x == 255) bsum[blockIdx.x] = buf[255];
}

__global__ void scan2_kernel(int* __restrict__ bsum, int nb) {
    __shared__ int buf[256];
    int tid = threadIdx.x;
    int v = (tid < nb) ? bsum[tid] : 0;
    buf[tid] = v;
    __syncthreads();
    for (int o = 1; o < 256; o <<= 1) {
        int t = (tid >= o) ? buf[tid - o] : 0;
        __syncthreads();
        buf[tid] += t;
        __syncthreads();
    }
    if (tid < nb) bsum[tid] = buf[tid] - v;   // exclusive
}

__global__ void scan3_kernel(const int* __restrict__ excl, const int* __restrict__ bsum,
                             int* __restrict__ off, int* __restrict__ cur, int n) {
    int gid = blockIdx.x * 256 + threadIdx.x;
    if (gid < n) {
        int e = excl[gid] + bsum[blockIdx.x];
        off[gid] = e;
        cur[gid] = e;
    }
    if (gid == 0) off[n] = ET;
}

__global__ void fill_kernel(const int* __restrict__ ei, int* __restrict__ cur,
                            int* __restrict__ csr) {
    int i = blockIdx.x * blockDim.x + threadIdx.x;
    if (i >= ET) return;
    int src, dst;
    if (i < NE) { src = ei[i]; dst = ei[NE + i]; }
    else        { src = i - NE; dst = i - NE; }
    int pos = atomicAdd(&cur[dst], 1);
    csr[pos] = src;
}

// ---------------- MFMA GEMM + fused s/d logits ----------------
__global__ __launch_bounds__(256) void gemm_mfma_kernel(
        const short* __restrict__ xhi, const short* __restrict__ xlo,
        const short* __restrict__ wt,   // [128][K] bf16 (W^T)
        const float* __restrict__ a_s, const float* __restrict__ a_d,
        short* __restrict__ h, float* __restrict__ s, float* __restrict__ d,
        int K, int n) {
    int wave = threadIdx.x >> 6;
    int lane = threadIdx.x & 63;
    int row0 = (blockIdx.x * 4 + wave) * 16;
    int m16 = lane & 15;
    int quad = lane >> 4;
    int kq = quad * 8;

    const short* pa_hi = xhi + (size_t)(row0 + m16) * K + kq;
    const short* pa_lo = xlo + (size_t)(row0 + m16) * K + kq;

    floatx4 acc[8];
    #pragma unroll
    for (int c = 0; c < 8; c++) acc[c] = (floatx4)(0.f);

    for (int ks = 0; ks < K; ks += 32) {
        short8 ah = *(const short8*)(pa_hi + ks);
        short8 al = *(const short8*)(pa_lo + ks);
        #pragma unroll
        for (int c = 0; c < 8; c++) {
            short8 b = *(const short8*)(wt + (size_t)(c * 16 + m16) * K + ks + kq);
            acc[c] = __builtin_amdgcn_mfma_f32_16x16x32_bf16(ah, b, acc[c], 0, 0, 0);
            acc[c] = __builtin_amdgcn_mfma_f32_16x16x32_bf16(al, b, acc[c], 0, 0, 0);
        }
    }

    // h write (bf16)
    #pragma unroll
    for (int c = 0; c < 8; c++) {
        #pragma unroll
        for (int r = 0; r < 4; r++) {
            int node = row0 + quad * 4 + r;
            if (node < n) h[(size_t)node * 128 + c * 16 + m16] = f2b(acc[c][r]);
        }
    }

    // fused attention logits: per head (c 0..3 = head0, c 4..7 = head1)
    float sp[2][4] = {{0, 0, 0, 0}, {0, 0, 0, 0}};
    float dp[2][4] = {{0, 0, 0, 0}, {0, 0, 0, 0}};
    #pragma unroll
    for (int c = 0; c < 8; c++) {
        float as_ = a_s[c * 16 + m16];
        float ad_ = a_d[c * 16 + m16];
        int hh = c >> 2;
        #pragma unroll
        for (int r = 0; r < 4; r++) {
            sp[hh][r] += acc[c][r] * as_;
            dp[hh][r] += acc[c][r] * ad_;
        }
    }
    #pragma unroll
    for (int o = 1; o < 16; o <<= 1) {
        #pragma unroll
        for (int hh = 0; hh < 2; hh++)
            #pragma unroll
            for (int r = 0; r < 4; r++) {
                sp[hh][r] += __shfl_xor(sp[hh][r], o, 64);
                dp[hh][r] += __shfl_xor(dp[hh][r], o, 64);
            }
    }
    if (m16 == 0) {
        #pragma unroll
        for (int r = 0; r < 4; r++) {
            int node = row0 + quad * 4 + r;
            if (node < n) {
                s[node * 2 + 0] = sp[0][r];
                s[node * 2 + 1] = sp[1][r];
                d[node * 2 + 0] = dp[0][r];
                d[node * 2 + 1] = dp[1][r];
            }
        }
    }
}

// ---------------- edge softmax + aggregation + bias + BN + res + relu ----------------
__global__ __launch_bounds__(256) void gat_aggregate_kernel(
        const unsigned* __restrict__ hp, const float* __restrict__ sv,
        const float* __restrict__ dv, const int* __restrict__ off,
        const int* __restrict__ csr, const float* __restrict__ bias,
        const float* __restrict__ bn_g, const float* __restrict__ bn_b,
        const float* __restrict__ bn_m, const float* __restrict__ bn_v,
        const unsigned* __restrict__ res_hi, const unsigned* __restrict__ res_lo,
        unsigned* __restrict__ out_hi, unsigned* __restrict__ out_lo, int n) {
    __shared__ float exs[4][CAP][2];
    __shared__ int scs[4][CAP];
    int w = threadIdx.x >> 6;
    int lane = threadIdx.x & 63;
    int node = blockIdx.x * 4 + w;
    bool ok = node < n;
    int begin = 0, end = 0, deg = 0;
    float d0 = 0.f, d1 = 0.f;
    if (ok) {
        begin = off[node]; end = off[node + 1]; deg = end - begin;
        d0 = dv[node * 2 + 0]; d1 = dv[node * 2 + 1];
    }
    bool fits = deg <= CAP;
    float inv0 = 0.f, inv1 = 0.f, m0 = 0.f, m1 = 0.f;

    if (ok && fits) {
        int i0 = begin + lane, i1 = begin + 64 + lane;
        int sa = (i0 < end) ? csr[i0] : -1;
        int sb = (i1 < end) ? csr[i1] : -1;
        float e0a = -3e38f, e1a = -3e38f, e0b = -3e38f, e1b = -3e38f;
        if (sa >= 0) {
            float2 sp = *(const float2*)(sv + sa * 2);
            e0a = lrelu(sp.x + d0); e1a = lrelu(sp.y + d1);
        }
        if (sb >= 0) {
            float2 sp = *(const float2*)(sv + sb * 2);
            e0b = lrelu(sp.x + d0); e1b = lrelu(sp.y + d1);
        }
        m0 = wred_max(fmaxf(e0a, e0b));
        m1 = wred_max(fmaxf(e1a, e1b));
        float x0a = 0.f, x1a = 0.f, x0b = 0.f, x1b = 0.f;
        if (sa >= 0) {
            x0a = __expf(e0a - m0); x1a = __expf(e1a - m1);
            exs[w][lane][0] = x0a; exs[w][lane][1] = x1a; scs[w][lane] = sa;
        }
        if (sb >= 0) {
            x0b = __expf(e0b - m0); x1b = __expf(e1b - m1);
            exs[w][lane + 64][0] = x0b; exs[w][lane + 64][1] = x1b; scs[w][lane + 64] = sb;
        }
        float z0 = wred_sum(x0a + x0b);
        float z1 = wred_sum(x1a + x1b);
        inv0 = 1.f / (z0 + 1e-16f);
        inv1 = 1.f / (z1 + 1e-16f);
    }
    __syncthreads();
    if (!ok) return;

    float acc0 = 0.f, acc1 = 0.f;
    bool head0 = lane < 32;
    if (fits) {
        int i = 0;
        for (; i + 1 < deg; i += 2) {
            int sA_ = scs[w][i], sB_ = scs[w][i + 1];
            float aa = head0 ? exs[w][i][0] : exs[w][i][1];
            float bb = head0 ? exs[w][i + 1][0] : exs[w][i + 1][1];
            unsigned u0 = hp[(size_t)sA_ * 64 + lane];
            unsigned u1 = hp[(size_t)sB_ * 64 + lane];
            acc0 += aa * blo(u0) + bb * blo(u1);
            acc1 += aa * bhi(u0) + bb * bhi(u1);
        }
        if (i < deg) {
            int sA_ = scs[w][i];
            float aa = head0 ? exs[w][i][0] : exs[w][i][1];
            unsigned u0 = hp[(size_t)sA_ * 64 + lane];
            acc0 += aa * blo(u0);
            acc1 += aa * bhi(u0);
        }
        float inv = head0 ? inv0 : inv1;
        acc0 *= inv;
        acc1 *= inv;
    } else {
        float mm0 = -3e38f, mm1 = -3e38f;
        for (int i = begin + lane; i < end; i += 64) {
            int sc = csr[i];
            float2 sp = *(const float2*)(sv + sc * 2);
            mm0 = fmaxf(mm0, lrelu(sp.x + d0));
            mm1 = fmaxf(mm1, lrelu(sp.y + d1));
        }
        mm0 = wred_max(mm0); mm1 = wred_max(mm1);
        float z0 = 0.f, z1 = 0.f;
        for (int i = begin + lane; i < end; i += 64) {
            int sc = csr[i];
            float2 sp = *(const float2*)(sv + sc * 2);
            z0 += __expf(lrelu(sp.x + d0) - mm0);
            z1 += __expf(lrelu(sp.y + d1) - mm1);
        }
        z0 = wred_sum(z0); z1 = wred_sum(z1);
        float i0_ = 1.f / (z0 + 1e-16f), i1_ = 1.f / (z1 + 1e-16f);
        for (int i = begin; i < end; i++) {
            int sc = csr[i];
            float2 sp = *(const float2*)(sv + sc * 2);
            float a0 = __expf(lrelu(sp.x + d0) - mm0) * i0_;
            float a1 = __expf(lrelu(sp.y + d1) - mm1) * i1_;
            float a = head0 ? a0 : a1;
            unsigned u0 = hp[(size_t)sc * 64 + lane];
            acc0 += a * blo(u0);
            acc1 += a * bhi(u0);
        }
    }

    int c0 = 2 * lane, c1 = c0 + 1;
    float v0 = acc0 + bias[c0];
    float v1 = acc1 + bias[c1];
    v0 = (v0 - bn_m[c0]) * (bn_g[c0] * rsqrtf(bn_v[c0] + 1e-5f)) + bn_b[c0];
    v1 = (v1 - bn_m[c1]) * (bn_g[c1] * rsqrtf(bn_v[c1] + 1e-5f)) + bn_b[c1];
    if (res_hi) {
        unsigned rh = res_hi[(size_t)node * 64 + lane];
        unsigned rl = res_lo[(size_t)node * 64 + lane];
        v0 += blo(rh) + blo(rl);
        v1 += bhi(rh) + bhi(rl);
    }
    v0 = fmaxf(v0, 0.f);
    v1 = fmaxf(v1, 0.f);
    unsigned h0 = (unsigned)(unsigned short)f2b(v0);
    unsigned h1 = (unsigned)(unsigned short)f2b(v1);
    float r0 = v0 - __uint_as_float(h0 << 16);
    float r1 = v1 - __uint_as_float(h1 << 16);
    unsigned l0 = (unsigned)(unsigned short)f2b(r0);
    unsigned l1 = (unsigned)(unsigned short)f2b(r1);
    out_hi[(size_t)node * 64 + lane] = h0 | (h1 << 16);
    out_lo[(size_t)node * 64 + lane] = l0 | (l1 << 16);
}

// ---------------- graph boundaries ----------------
__global__ void bounds_kernel(const int* __restrict__ batch, int* __restrict__ starts) {
    int g = threadIdx.x;
    if (g > NG) return;
    int lo = 0, hi = NN;
    while (lo < hi) {
        int mid = (lo + hi) >> 1;
        if (batch[mid] < g) lo = mid + 1; else hi = mid;
    }
    starts[g] = lo;
}

// ---------------- global mean pool ----------------
__global__ void pool_kernel(const unsigned short* __restrict__ xh,
                            const unsigned short* __restrict__ xl,
                            const int* __restrict__ starts, float* __restrict__ xg) {
    int g = blockIdx.x;
    int c = threadIdx.x;
    int s0 = starts[g], e0 = starts[g + 1];
    float acc = 0.f;
    int node = s0;
    for (; node + 1 < e0; node += 2) {
        size_t i0 = (size_t)node * 128 + c, i1 = i0 + 128;
        acc += __uint_as_float(((unsigned)xh[i0]) << 16) + __uint_as_float(((unsigned)xl[i0]) << 16)
             + __uint_as_float(((unsigned)xh[i1]) << 16) + __uint_as_float(((unsigned)xl[i1]) << 16);
    }
    for (; node < e0; node++) {
        size_t i0 = (size_t)node * 128 + c;
        acc += __uint_as_float(((unsigned)xh[i0]) << 16) + __uint_as_float(((unsigned)xl[i0]) << 16);
    }
    float cf = (float)(e0 - s0);
    xg[g * 128 + c] = acc / fmaxf(cf, 1.f);
}

// ---------------- lat/lon heads ----------------
__global__ void head_kernel(const float* __restrict__ xg,
                            const float* __restrict__ w1a, const float* __restrict__ b1a,
                            const float* __restrict__ w2a, const float* __restrict__ b2a,
                            const float* __restrict__ w1o, const float* __restrict__ b1o,
                            const float* __restrict__ w2o, const float* __restrict__ b2o,
                            const int* __restrict__ flags, void* __restrict__ out) {
    int g = blockIdx.x;
    int wave = threadIdx.x >> 6;
    int lane = threadIdx.x & 63;
    const float* w1 = wave ? w1o : w1a;
    const float* b1 = wave ? b1o : b1a;
    const float* w2 = wave ? w2o : w2a;
    const float* b2 = wave ? b2o : b2a;
    float acc = b1[lane];
    for (int c = 0; c < 128; c++)
        acc += xg[g * 128 + c] * w1[c * 64 + lane];
    acc = fmaxf(acc, 0.f);
    float contrib = wred_sum(acc * w2[lane]);
    if (lane == 0) {
        float r = contrib + b2[0];
        if (flags[0]) ((float*)out)[wave * NG + g] = r;
        else          ((bf16*)out)[wave * NG + g] = __float2bfloat16(r);
    }
}

extern "C" void kernel_launch(void* const* d_in, const int* in_sizes, int n_in,
                              void* d_out, int out_size, void* d_ws, size_t ws_size,
                              hipStream_t stream) {
    static const int fidx[32] = {0,1, 4,5,6,7,8,9, 10,11,12,13, 14,15,16,17,
                                 18,19,20,21, 22,23,24,25, 26,27,28,29, 30,31,32,33};
    static const int flen[32] = {200000, 3200000, 128, 32, 2048, 32, 4096, 64,
                                 8192, 128, 128, 128, 16384, 128, 128, 128,
                                 16384, 128, 128, 128, 384, 384, 384, 384,
                                 8192, 64, 64, 1, 8192, 64, 64, 1};
    CvtArgs ca;
    int O[32];
    int tot = 0, blk = 0;
    for (int i = 0; i < 32; i++) {
        int cl = (i == 1) ? 0 : flen[i];        // skip wavef fp32 conversion (unused)
        ca.src[i] = d_in[fidx[i]];
        ca.len[i] = cl;
        O[i] = tot;
        ca.dst_off[i] = tot;
        ca.blk_base[i] = blk;
        tot += (flen[i] + 63) & ~63;
        blk += (cl + 1023) / 1024;
    }
    ca.blk_base[32] = blk;

    char* w = (char*)d_ws;
    auto alloc = [&](size_t bytes) -> char* {
        char* p = w;
        w += (bytes + 255) & ~(size_t)255;
        return p;
    };
    int*   flags  = (int*)alloc(256);
    float* cf     = (float*)alloc((size_t)tot * 4);
    int*   ei32   = (int*)alloc((size_t)2 * NE * 4);
    int*   bat32  = (int*)alloc((size_t)NN * 4);
    short* wfhi   = (short*)alloc((size_t)NNP * 64 * 2);
    short* wflo   = (short*)alloc((size_t)NNP * 64 * 2);
    short* x0hi   = (short*)alloc((size_t)NNP * 64 * 2);
    short* x0lo   = (short*)alloc((size_t)NNP * 64 * 2);
    short* xAhi   = (short*)alloc((size_t)NNP * 128 * 2);
    short* xAlo   = (short*)alloc((size_t)NNP * 128 * 2);
    short* xBhi   = (short*)alloc((size_t)NNP * 128 * 2);
    short* xBlo   = (short*)alloc((size_t)NNP * 128 * 2);
    short* h      = (short*)alloc((size_t)NNP * 128 * 2);
    float* sA     = (float*)alloc((size_t)NN * 2 * 4);
    float* dA     = (float*)alloc((size_t)NN * 2 * 4);
    int*   off    = (int*)alloc((size_t)(NN + 1) * 4);
    int*   cur    = (int*)alloc((size_t)NN * 4);
    int*   excl   = (int*)alloc((size_t)NN * 4);
    int*   bsum   = (int*)alloc(256 * 4);
    int*   csr    = (int*)alloc((size_t)ET * 4);
    int*   starts = (int*)alloc((size_t)(NG + 1) * 4);
    float* xg     = (float*)alloc((size_t)NG * 128 * 4);
    short* wtall  = (short*)alloc((size_t)40960 * 2);
    short* wavewT = (short*)alloc((size_t)2048 * 2);
    short* combwT = (short*)alloc((size_t)4096 * 2);
    short* wt0 = wtall, *wt1 = wtall + 8192, *wt2 = wtall + 24576;

    detect_kernel<<<1, 256, 0, stream>>>((const unsigned int*)d_in[0],
                                         (const unsigned int*)d_in[2], flags);
    cvt_float_kernel<<<blk, 256, 0, stream>>>(ca, cf, flags);
    cvt_int_kernel<<<(2 * NE + NN + 255) / 256, 256, 0, stream>>>(d_in[2], d_in[3],
                                                                  ei32, bat32, flags);
    wt_all_kernel<<<184, 256, 0, stream>>>(cf, wtall, wavewT, combwT,
                                           O[8], O[12], O[16], O[4], O[6]);
    prep_wf_kernel<<<(NNP * 64 + 255) / 256, 256, 0, stream>>>(d_in[1], wfhi, wflo, flags);

    hipMemsetAsync(cur, 0, (size_t)NN * 4, stream);

    encode_mfma_kernel<<<NNP / 64, 256, 0, stream>>>(cf + O[0], cf + O[2], cf + O[3],
                                                     wfhi, wflo, wavewT, cf + O[5],
                                                     combwT, cf + O[7], x0hi, x0lo);
    count_kernel<<<(ET + 255) / 256, 256, 0, stream>>>(ei32, cur);
    int nb = (NN + 255) / 256;
    scan1_kernel<<<nb, 256, 0, stream>>>(cur, excl, bsum, NN);
    scan2_kernel<<<1, 256, 0, stream>>>(bsum, nb);
    scan3_kernel<<<nb, 256, 0, stream>>>(excl, bsum, off, cur, NN);
    fill_kernel<<<(ET + 255) / 256, 256, 0, stream>>>(ei32, cur, csr);

    int gblk = NNP / 64;
    // layer 0
    gemm_mfma_kernel<<<gblk, 256, 0, stream>>>(x0hi, x0lo, wt0, cf + O[9], cf + O[10],
                                               h, sA, dA, 64, NN);
    gat_aggregate_kernel<<<(NN + 3) / 4, 256, 0, stream>>>(
        (const unsigned*)h, sA, dA, off, csr, cf + O[11],
        cf + O[20], cf + O[21], cf + O[22], cf + O[23],
        nullptr, nullptr, (unsigned*)xAhi, (unsigned*)xAlo, NN);
    // layer 1
    gemm_mfma_kernel<<<gblk, 256, 0, stream>>>(xAhi, xAlo, wt1, cf + O[13], cf + O[14],
                                               h, sA, dA, 128, NN);
    gat_aggregate_kernel<<<(NN + 3) / 4, 256, 0, stream>>>(
        (const unsigned*)h, sA, dA, off, csr, cf + O[15],
        cf + O[20] + 128, cf + O[21] + 128, cf + O[22] + 128, cf + O[23] + 128,
        (const unsigned*)xAhi, (const unsigned*)xAlo, (unsigned*)xBhi, (unsigned*)xBlo, NN);
    // layer 2
    gemm_mfma_kernel<<<gblk, 256, 0, stream>>>(xBhi, xBlo, wt2, cf + O[17], cf + O[18],
                                               h, sA, dA, 128, NN);
    gat_aggregate_kernel<<<(NN + 3) / 4, 256, 0, stream>>>(
        (const unsigned*)h, sA, dA, off, csr, cf + O[19],
        cf + O[20] + 256, cf + O[21] + 256, cf + O[22] + 256, cf + O[23] + 256,
        (const unsigned*)xBhi, (const unsigned*)xBlo, (unsigned*)xAhi, (unsigned*)xAlo, NN);

    bounds_kernel<<<1, 512, 0, stream>>>(bat32, starts);
    pool_kernel<<<NG, 128, 0, stream>>>((const unsigned short*)xAhi, (const unsigned short*)xAlo,
                                        starts, xg);
    head_kernel<<<NG, 128, 0, stream>>>(xg,
                                        cf + O[24], cf + O[25], cf + O[26], cf + O[27],
                                        cf + O[28], cf + O[29], cf + O[30], cf + O[31],
                                        flags, d_out);
}

// Round 5
// 450.533 us; speedup vs baseline: 2.0759x; 1.1195x over previous
//
#include <hip/hip_runtime.h>
#include <hip/hip_bf16.h>
#include <stdint.h>

#define NN 50000
#define NNP 50048   // padded to 64-node gemm tiles
#define NE 800000
#define ET 850000   // NE + NN self loops
#define NG 256
#define CAP 128     // per-node edge capacity for LDS alpha cache
#define NB 196      // buckets of 256 dst nodes (196*256 = 50176 >= NNP)
#define EB 8192     // edges per block in bucket hist/scatter
#define NEB ((ET + EB - 1) / EB)   // 104

typedef __hip_bfloat16 bf16;
typedef __attribute__((ext_vector_type(8))) short short8;
typedef __attribute__((ext_vector_type(4))) float floatx4;

__device__ __forceinline__ float b2f(bf16 v) { return __bfloat162float(v); }
__device__ __forceinline__ float lrelu(float x) { return x > 0.f ? x : 0.2f * x; }
__device__ __forceinline__ short f2b(float f) {          // RNE bf16 round
    unsigned u = __float_as_uint(f);
    unsigned r = (u + 0x7FFFu + ((u >> 16) & 1u)) >> 16;
    return (short)r;
}
__device__ __forceinline__ float sh2f(short s) { return __uint_as_float(((unsigned)(unsigned short)s) << 16); }
__device__ __forceinline__ float blo(unsigned u) { return __uint_as_float(u << 16); }
__device__ __forceinline__ float bhi(unsigned u) { return __uint_as_float(u & 0xFFFF0000u); }

__device__ __forceinline__ float wred_sum(float v) {
    for (int o = 32; o > 0; o >>= 1) v += __shfl_xor(v, o, 64);
    return v;
}
__device__ __forceinline__ float wred_max(float v) {
    for (int o = 32; o > 0; o >>= 1) v = fmaxf(v, __shfl_xor(v, o, 64));
    return v;
}

// ---------------- dtype detection ----------------
__global__ void detect_kernel(const unsigned int* __restrict__ meta_words,
                              const unsigned int* __restrict__ ei_words,
                              int* __restrict__ flags) {
    __shared__ int insane, odd_nonzero;
    if (threadIdx.x == 0) { insane = 0; odd_nonzero = 0; }
    __syncthreads();
    int cnt = 0;
    for (int k = 0; k < 8; k++) {
        unsigned int w = meta_words[threadIdx.x * 8 + k];
        int elo = (int)(((w & 0xFFFFu) >> 7) & 0xFF);
        int ehi = (int)(((w >> 16) >> 7) & 0xFF);
        if (elo >= 0x8D) cnt++;
        if (ehi >= 0x8D) cnt++;
    }
    if (cnt) atomicAdd(&insane, cnt);
    if (ei_words[threadIdx.x * 2 + 1] != 0u) atomicAdd(&odd_nonzero, 1);
    __syncthreads();
    if (threadIdx.x == 0) {
        flags[0] = (insane >= 4) ? 1 : 0;       // fp32 floats
        flags[1] = (odd_nonzero == 0) ? 1 : 0;  // int64 ints
    }
}

// ---------------- canonicalize float inputs to fp32 ----------------
struct CvtArgs {
    const void* src[32];
    int len[32];
    int dst_off[32];
    int blk_base[33];
};

__global__ void cvt_float_kernel(CvtArgs a, float* __restrict__ dst,
                                 const int* __restrict__ flags) {
    int b = blockIdx.x;
    int ai = 0;
    while (b >= a.blk_base[ai + 1]) ai++;
    int base = (b - a.blk_base[ai]) * 1024 + threadIdx.x;
    bool fp32 = flags[0] != 0;
    const float* sf = (const float*)a.src[ai];
    const bf16* sh = (const bf16*)a.src[ai];
    float* d = dst + a.dst_off[ai];
    int len = a.len[ai];
    #pragma unroll
    for (int u = 0; u < 4; u++) {
        int i = base + u * 256;
        if (i < len) d[i] = fp32 ? sf[i] : b2f(sh[i]);
    }
}

__global__ void cvt_int_kernel(const void* __restrict__ ei_src, const void* __restrict__ bat_src,
                               int* __restrict__ ei32, int* __restrict__ bat32,
                               const int* __restrict__ flags) {
    int i = blockIdx.x * 256 + threadIdx.x;
    bool i64 = flags[1] != 0;
    if (i < 2 * NE) {
        ei32[i] = i64 ? (int)((const long long*)ei_src)[i] : ((const int*)ei_src)[i];
    } else {
        int j = i - 2 * NE;
        if (j < NN)
            bat32[j] = i64 ? (int)((const long long*)bat_src)[j] : ((const int*)bat_src)[j];
    }
}

// ---------------- all weight transposes -> bf16, one launch ----------------
__global__ void wt_all_kernel(const float* __restrict__ cf, short* __restrict__ wtall,
                              short* __restrict__ wavewT, short* __restrict__ combwT,
                              int O8, int O12, int O16, int O4, int O6) {
    int idx = blockIdx.x * 256 + threadIdx.x;   // < 47104
    const float* src; short* dst; int K, N, loc;
    if (idx < 8192)        { src = cf + O8;  dst = wtall;          K = 64;  N = 128; loc = idx; }
    else if (idx < 24576)  { src = cf + O12; dst = wtall + 8192;   K = 128; N = 128; loc = idx - 8192; }
    else if (idx < 40960)  { src = cf + O16; dst = wtall + 24576;  K = 128; N = 128; loc = idx - 24576; }
    else if (idx < 43008)  { src = cf + O4;  dst = wavewT;         K = 64;  N = 32;  loc = idx - 40960; }
    else if (idx < 47104)  { src = cf + O6;  dst = combwT;         K = 64;  N = 64;  loc = idx - 43008; }
    else return;
    int nch = loc / K, k = loc % K;
    dst[loc] = f2b(src[k * N + nch]);
}

// ---------------- wavef -> bf16 hi/lo [NNP][64], zero-padded rows ----------------
__global__ void prep_wf_kernel(const void* __restrict__ src, short* __restrict__ hi,
                               short* __restrict__ lo, const int* __restrict__ flags) {
    int i = blockIdx.x * 256 + threadIdx.x;
    if (i >= NNP * 64) return;
    short h = 0, l = 0;
    if (i < NN * 64) {
        if (flags[0]) {
            float v = ((const float*)src)[i];
            h = f2b(v);
            l = f2b(v - sh2f(h));
        } else {
            h = ((const short*)src)[i];
        }
    }
    hi[i] = h;
    lo[i] = l;
}

// ---------------- MFMA encoder ----------------
__global__ __launch_bounds__(256) void encode_mfma_kernel(
        const float* __restrict__ meta, const float* __restrict__ meta_w,
        const float* __restrict__ meta_b,
        const short* __restrict__ wfhi, const short* __restrict__ wflo,
        const short* __restrict__ wavewT, const float* __restrict__ wave_b,
        const short* __restrict__ combwT, const float* __restrict__ comb_b,
        short* __restrict__ xhi, short* __restrict__ xlo) {
    __shared__ short xc_hi[64][72];
    __shared__ short xc_lo[64][72];
    int t = threadIdx.x;
    int wave = t >> 6, lane = t & 63;
    int m16 = lane & 15, quad = lane >> 4;
    int nblk = blockIdx.x * 64;

    #pragma unroll
    for (int u = 0; u < 8; u++) {
        int idx = u * 256 + t;
        int node_l = idx >> 5, ch = idx & 31;
        int node = nblk + node_l;
        float acc = meta_b[ch];
        if (node < NN) {
            #pragma unroll
            for (int k = 0; k < 4; k++)
                acc += meta[node * 4 + k] * meta_w[k * 32 + ch];
        }
        float v = fmaxf(acc, 0.f);
        short hh = f2b(v);
        xc_hi[node_l][ch] = hh;
        xc_lo[node_l][ch] = f2b(v - sh2f(hh));
    }

    int row0 = nblk + wave * 16;
    const short* pah = wfhi + (size_t)(row0 + m16) * 64 + quad * 8;
    const short* pal = wflo + (size_t)(row0 + m16) * 64 + quad * 8;
    floatx4 wacc[2];
    wacc[0] = (floatx4)(0.f); wacc[1] = (floatx4)(0.f);
    #pragma unroll
    for (int ks = 0; ks < 64; ks += 32) {
        short8 ah = *(const short8*)(pah + ks);
        short8 al = *(const short8*)(pal + ks);
        #pragma unroll
        for (int c = 0; c < 2; c++) {
            short8 b = *(const short8*)(wavewT + (c * 16 + m16) * 64 + ks + quad * 8);
            wacc[c] = __builtin_amdgcn_mfma_f32_16x16x32_bf16(ah, b, wacc[c], 0, 0, 0);
            wacc[c] = __builtin_amdgcn_mfma_f32_16x16x32_bf16(al, b, wacc[c], 0, 0, 0);
        }
    }
    #pragma unroll
    for (int c = 0; c < 2; c++) {
        float bb = wave_b[c * 16 + m16];
        #pragma unroll
        for (int r = 0; r < 4; r++) {
            int node_l = wave * 16 + quad * 4 + r;
            int ch = 32 + c * 16 + m16;
            float v = fmaxf(wacc[c][r] + bb, 0.f);
            short hh = f2b(v);
            xc_hi[node_l][ch] = hh;
            xc_lo[node_l][ch] = f2b(v - sh2f(hh));
        }
    }
    __syncthreads();

    floatx4 acc2[4];
    #pragma unroll
    for (int c = 0; c < 4; c++) acc2[c] = (floatx4)(0.f);
    #pragma unroll
    for (int ks = 0; ks < 64; ks += 32) {
        short8 ah = *(const short8*)&xc_hi[wave * 16 + m16][ks + quad * 8];
        short8 al = *(const short8*)&xc_lo[wave * 16 + m16][ks + quad * 8];
        #pragma unroll
        for (int c = 0; c < 4; c++) {
            short8 b = *(const short8*)(combwT + (c * 16 + m16) * 64 + ks + quad * 8);
            acc2[c] = __builtin_amdgcn_mfma_f32_16x16x32_bf16(ah, b, acc2[c], 0, 0, 0);
            acc2[c] = __builtin_amdgcn_mfma_f32_16x16x32_bf16(al, b, acc2[c], 0, 0, 0);
        }
    }
    #pragma unroll
    for (int c = 0; c < 4; c++) {
        int ch = c * 16 + m16;
        float bb = comb_b[ch];
        #pragma unroll
        for (int r = 0; r < 4; r++) {
            int node = nblk + wave * 16 + quad * 4 + r;
            float v = fmaxf(acc2[c][r] + bb, 0.f);
            short hh = f2b(v);
            xhi[(size_t)node * 64 + ch] = hh;
            xlo[(size_t)node * 64 + ch] = f2b(v - sh2f(hh));
        }
    }
}

// ---------------- CSR build: locality-preserving 2-level bucket sort ----------------
// bucket = dst >> 8 (256 dst nodes per bucket)
__global__ void bucket_hist_kernel(const int* __restrict__ ei, int* __restrict__ gbh) {
    __shared__ int lh[NB];
    int t = threadIdx.x;
    if (t < NB) lh[t] = 0;
    __syncthreads();
    int base = blockIdx.x * EB;
    #pragma unroll 4
    for (int u = 0; u < EB / 256; u++) {
        int i = base + u * 256 + t;
        if (i < ET) {
            int dst = (i < NE) ? ei[NE + i] : (i - NE);
            atomicAdd(&lh[dst >> 8], 1);
        }
    }
    __syncthreads();
    if (t < NB && lh[t]) atomicAdd(&gbh[t], lh[t]);
}

__global__ void bucket_scan_kernel(const int* __restrict__ gbh, int* __restrict__ gbo,
                                   int* __restrict__ bcur) {
    __shared__ int buf[256];
    int t = threadIdx.x;
    int v = (t < NB) ? gbh[t] : 0;
    buf[t] = v;
    __syncthreads();
    for (int o = 1; o < 256; o <<= 1) {
        int x = (t >= o) ? buf[t - o] : 0;
        __syncthreads();
        buf[t] += x;
        __syncthreads();
    }
    if (t < NB) {
        int e = buf[t] - v;
        gbo[t] = e;
        bcur[t] = e;
    }
    if (t == 0) gbo[NB] = ET;
}

__global__ void bucket_scatter_kernel(const int* __restrict__ ei, int* __restrict__ bcur,
                                      uint2* __restrict__ bkt) {
    __shared__ int lh[NB];
    __shared__ int lbase[NB];
    int t = threadIdx.x;
    if (t < NB) lh[t] = 0;
    __syncthreads();
    int base = blockIdx.x * EB;
    #pragma unroll 4
    for (int u = 0; u < EB / 256; u++) {
        int i = base + u * 256 + t;
        if (i < ET) {
            int dst = (i < NE) ? ei[NE + i] : (i - NE);
            atomicAdd(&lh[dst >> 8], 1);
        }
    }
    __syncthreads();
    if (t < NB) {
        int c = lh[t];
        lbase[t] = c ? atomicAdd(&bcur[t], c) : 0;
        lh[t] = 0;   // reuse as local cursor
    }
    __syncthreads();
    #pragma unroll 4
    for (int u = 0; u < EB / 256; u++) {
        int i = base + u * 256 + t;
        if (i < ET) {
            int src, dst;
            if (i < NE) { src = ei[i]; dst = ei[NE + i]; }
            else        { src = i - NE; dst = i - NE; }
            int b = dst >> 8;
            int pos = lbase[b] + atomicAdd(&lh[b], 1);
            bkt[pos] = make_uint2((unsigned)src, (unsigned)dst);
        }
    }
}

__global__ void bucket_finalize_kernel(const uint2* __restrict__ bkt,
                                       const int* __restrict__ gbo,
                                       int* __restrict__ off, int* __restrict__ csr) {
    __shared__ int hist[256];
    __shared__ int excl[256];
    int b = blockIdx.x;
    int t = threadIdx.x;
    int e0 = gbo[b], e1 = gbo[b + 1];
    hist[t] = 0;
    __syncthreads();
    for (int i = e0 + t; i < e1; i += 256) {
        uint2 e = bkt[i];
        atomicAdd(&hist[e.y & 255], 1);
    }
    __syncthreads();
    int v = hist[t];
    excl[t] = v;
    __syncthreads();
    for (int o = 1; o < 256; o <<= 1) {
        int x = (t >= o) ? excl[t - o] : 0;
        __syncthreads();
        excl[t] += x;
        __syncthreads();
    }
    int ex = excl[t] - v;   // exclusive prefix within bucket
    __syncthreads();
    int node = b * 256 + t;
    if (node <= NN) off[node] = e0 + ex;
    hist[t] = e0 + ex;      // reuse as global cursor
    __syncthreads();
    for (int i = e0 + t; i < e1; i += 256) {
        uint2 e = bkt[i];
        int pos = atomicAdd(&hist[e.y & 255], 1);
        csr[pos] = (int)e.x;
    }
}

// ---------------- MFMA GEMM + fused s/d logits ----------------
__global__ __launch_bounds__(256) void gemm_mfma_kernel(
        const short* __restrict__ xhi, const short* __restrict__ xlo,
        const short* __restrict__ wt,
        const float* __restrict__ a_s, const float* __restrict__ a_d,
        short* __restrict__ h, float* __restrict__ s, float* __restrict__ d,
        int K, int n) {
    int wave = threadIdx.x >> 6;
    int lane = threadIdx.x & 63;
    int row0 = (blockIdx.x * 4 + wave) * 16;
    int m16 = lane & 15;
    int quad = lane >> 4;
    int kq = quad * 8;

    const short* pa_hi = xhi + (size_t)(row0 + m16) * K + kq;
    const short* pa_lo = xlo + (size_t)(row0 + m16) * K + kq;

    floatx4 acc[8];
    #pragma unroll
    for (int c = 0; c < 8; c++) acc[c] = (floatx4)(0.f);

    for (int ks = 0; ks < K; ks += 32) {
        short8 ah = *(const short8*)(pa_hi + ks);
        short8 al = *(const short8*)(pa_lo + ks);
        #pragma unroll
        for (int c = 0; c < 8; c++) {
            short8 b = *(const short8*)(wt + (size_t)(c * 16 + m16) * K + ks + kq);
            acc[c] = __builtin_amdgcn_mfma_f32_16x16x32_bf16(ah, b, acc[c], 0, 0, 0);
            acc[c] = __builtin_amdgcn_mfma_f32_16x16x32_bf16(al, b, acc[c], 0, 0, 0);
        }
    }

    #pragma unroll
    for (int c = 0; c < 8; c++) {
        #pragma unroll
        for (int r = 0; r < 4; r++) {
            int node = row0 + quad * 4 + r;
            if (node < n) h[(size_t)node * 128 + c * 16 + m16] = f2b(acc[c][r]);
        }
    }

    float sp[2][4] = {{0, 0, 0, 0}, {0, 0, 0, 0}};
    float dp[2][4] = {{0, 0, 0, 0}, {0, 0, 0, 0}};
    #pragma unroll
    for (int c = 0; c < 8; c++) {
        float as_ = a_s[c * 16 + m16];
        float ad_ = a_d[c * 16 + m16];
        int hh = c >> 2;
        #pragma unroll
        for (int r = 0; r < 4; r++) {
            sp[hh][r] += acc[c][r] * as_;
            dp[hh][r] += acc[c][r] * ad_;
        }
    }
    #pragma unroll
    for (int o = 1; o < 16; o <<= 1) {
        #pragma unroll
        for (int hh = 0; hh < 2; hh++)
            #pragma unroll
            for (int r = 0; r < 4; r++) {
                sp[hh][r] += __shfl_xor(sp[hh][r], o, 64);
                dp[hh][r] += __shfl_xor(dp[hh][r], o, 64);
            }
    }
    if (m16 == 0) {
        #pragma unroll
        for (int r = 0; r < 4; r++) {
            int node = row0 + quad * 4 + r;
            if (node < n) {
                s[node * 2 + 0] = sp[0][r];
                s[node * 2 + 1] = sp[1][r];
                d[node * 2 + 0] = dp[0][r];
                d[node * 2 + 1] = dp[1][r];
            }
        }
    }
}

// ---------------- edge softmax + aggregation + bias + BN + res + relu ----------------
__global__ __launch_bounds__(256) void gat_aggregate_kernel(
        const unsigned* __restrict__ hp, const float* __restrict__ sv,
        const float* __restrict__ dv, const int* __restrict__ off,
        const int* __restrict__ csr, const float* __restrict__ bias,
        const float* __restrict__ bn_g, const float* __restrict__ bn_b,
        const float* __restrict__ bn_m, const float* __restrict__ bn_v,
        const unsigned* __restrict__ res_hi, const unsigned* __restrict__ res_lo,
        unsigned* __restrict__ out_hi, unsigned* __restrict__ out_lo, int n) {
    __shared__ float exs[4][CAP][2];
    __shared__ int scs[4][CAP];
    int w = threadIdx.x >> 6;
    int lane = threadIdx.x & 63;
    int node = blockIdx.x * 4 + w;
    bool ok = node < n;
    int begin = 0, end = 0, deg = 0;
    float d0 = 0.f, d1 = 0.f;
    if (ok) {
        begin = off[node]; end = off[node + 1]; deg = end - begin;
        d0 = dv[node * 2 + 0]; d1 = dv[node * 2 + 1];
    }
    bool fits = deg <= CAP;
    float inv0 = 0.f, inv1 = 0.f, m0 = 0.f, m1 = 0.f;

    if (ok && fits) {
        int i0 = begin + lane, i1 = begin + 64 + lane;
        int sa = (i0 < end) ? csr[i0] : -1;
        int sb = (i1 < end) ? csr[i1] : -1;
        float e0a = -3e38f, e1a = -3e38f, e0b = -3e38f, e1b = -3e38f;
        if (sa >= 0) {
            float2 sp = *(const float2*)(sv + sa * 2);
            e0a = lrelu(sp.x + d0); e1a = lrelu(sp.y + d1);
        }
        if (sb >= 0) {
            float2 sp = *(const float2*)(sv + sb * 2);
            e0b = lrelu(sp.x + d0); e1b = lrelu(sp.y + d1);
        }
        m0 = wred_max(fmaxf(e0a, e0b));
        m1 = wred_max(fmaxf(e1a, e1b));
        float x0a = 0.f, x1a = 0.f, x0b = 0.f, x1b = 0.f;
        if (sa >= 0) {
            x0a = __expf(e0a - m0); x1a = __expf(e1a - m1);
            exs[w][lane][0] = x0a; exs[w][lane][1] = x1a; scs[w][lane] = sa;
        }
        if (sb >= 0) {
            x0b = __expf(e0b - m0); x1b = __expf(e1b - m1);
            exs[w][lane + 64][0] = x0b; exs[w][lane + 64][1] = x1b; scs[w][lane + 64] = sb;
        }
        float z0 = wred_sum(x0a + x0b);
        float z1 = wred_sum(x1a + x1b);
        inv0 = 1.f / (z0 + 1e-16f);
        inv1 = 1.f / (z1 + 1e-16f);
    }
    __syncthreads();
    if (!ok) return;

    float acc0 = 0.f, acc1 = 0.f;
    bool head0 = lane < 32;
    if (fits) {
        int i = 0;
        for (; i + 3 < deg; i += 4) {
            int s0 = scs[w][i], s1 = scs[w][i + 1], s2 = scs[w][i + 2], s3 = scs[w][i + 3];
            float a0 = head0 ? exs[w][i][0] : exs[w][i][1];
            float a1 = head0 ? exs[w][i + 1][0] : exs[w][i + 1][1];
            float a2 = head0 ? exs[w][i + 2][0] : exs[w][i + 2][1];
            float a3 = head0 ? exs[w][i + 3][0] : exs[w][i + 3][1];
            unsigned u0 = hp[(size_t)s0 * 64 + lane];
            unsigned u1 = hp[(size_t)s1 * 64 + lane];
            unsigned u2 = hp[(size_t)s2 * 64 + lane];
            unsigned u3 = hp[(size_t)s3 * 64 + lane];
            acc0 += a0 * blo(u0) + a1 * blo(u1) + a2 * blo(u2) + a3 * blo(u3);
            acc1 += a0 * bhi(u0) + a1 * bhi(u1) + a2 * bhi(u2) + a3 * bhi(u3);
        }
        for (; i < deg; i++) {
            int s0 = scs[w][i];
            float a0 = head0 ? exs[w][i][0] : exs[w][i][1];
            unsigned u0 = hp[(size_t)s0 * 64 + lane];
            acc0 += a0 * blo(u0);
            acc1 += a0 * bhi(u0);
        }
        float inv = head0 ? inv0 : inv1;
        acc0 *= inv;
        acc1 *= inv;
    } else {
        float mm0 = -3e38f, mm1 = -3e38f;
        for (int i = begin + lane; i < end; i += 64) {
            int sc = csr[i];
            float2 sp = *(const float2*)(sv + sc * 2);
            mm0 = fmaxf(mm0, lrelu(sp.x + d0));
            mm1 = fmaxf(mm1, lrelu(sp.y + d1));
        }
        mm0 = wred_max(mm0); mm1 = wred_max(mm1);
        float z0 = 0.f, z1 = 0.f;
        for (int i = begin + lane; i < end; i += 64) {
            int sc = csr[i];
            float2 sp = *(const float2*)(sv + sc * 2);
            z0 += __expf(lrelu(sp.x + d0) - mm0);
            z1 += __expf(lrelu(sp.y + d1) - mm1);
        }
        z0 = wred_sum(z0); z1 = wred_sum(z1);
        float i0_ = 1.f / (z0 + 1e-16f), i1_ = 1.f / (z1 + 1e-16f);
        for (int i = begin; i < end; i++) {
            int sc = csr[i];
            float2 sp = *(const float2*)(sv + sc * 2);
            float a0 = __expf(lrelu(sp.x + d0) - mm0) * i0_;
            float a1 = __expf(lrelu(sp.y + d1) - mm1) * i1_;
            float a = head0 ? a0 : a1;
            unsigned u0 = hp[(size_t)sc * 64 + lane];
            acc0 += a * blo(u0);
            acc1 += a * bhi(u0);
        }
    }

    int c0 = 2 * lane, c1 = c0 + 1;
    float v0 = acc0 + bias[c0];
    float v1 = acc1 + bias[c1];
    v0 = (v0 - bn_m[c0]) * (bn_g[c0] * rsqrtf(bn_v[c0] + 1e-5f)) + bn_b[c0];
    v1 = (v1 - bn_m[c1]) * (bn_g[c1] * rsqrtf(bn_v[c1] + 1e-5f)) + bn_b[c1];
    if (res_hi) {
        unsigned rh = res_hi[(size_t)node * 64 + lane];
        unsigned rl = res_lo[(size_t)node * 64 + lane];
        v0 += blo(rh) + blo(rl);
        v1 += bhi(rh) + bhi(rl);
    }
    v0 = fmaxf(v0, 0.f);
    v1 = fmaxf(v1, 0.f);
    unsigned h0 = (unsigned)(unsigned short)f2b(v0);
    unsigned h1 = (unsigned)(unsigned short)f2b(v1);
    float r0 = v0 - __uint_as_float(h0 << 16);
    float r1 = v1 - __uint_as_float(h1 << 16);
    unsigned l0 = (unsigned)(unsigned short)f2b(r0);
    unsigned l1 = (unsigned)(unsigned short)f2b(r1);
    out_hi[(size_t)node * 64 + lane] = h0 | (h1 << 16);
    out_lo[(size_t)node * 64 + lane] = l0 | (l1 << 16);
}

// ---------------- graph boundaries ----------------
__global__ void bounds_kernel(const int* __restrict__ batch, int* __restrict__ starts) {
    int g = threadIdx.x;
    if (g > NG) return;
    int lo = 0, hi = NN;
    while (lo < hi) {
        int mid = (lo + hi) >> 1;
        if (batch[mid] < g) lo = mid + 1; else hi = mid;
    }
    starts[g] = lo;
}

// ---------------- global mean pool ----------------
__global__ void pool_kernel(const unsigned short* __restrict__ xh,
                            const unsigned short* __restrict__ xl,
                            const int* __restrict__ starts, float* __restrict__ xg) {
    int g = blockIdx.x;
    int c = threadIdx.x;
    int s0 = starts[g], e0 = starts[g + 1];
    float acc = 0.f;
    int node = s0;
    for (; node + 1 < e0; node += 2) {
        size_t i0 = (size_t)node * 128 + c, i1 = i0 + 128;
        acc += __uint_as_float(((unsigned)xh[i0]) << 16) + __uint_as_float(((unsigned)xl[i0]) << 16)
             + __uint_as_float(((unsigned)xh[i1]) << 16) + __uint_as_float(((unsigned)xl[i1]) << 16);
    }
    for (; node < e0; node++) {
        size_t i0 = (size_t)node * 128 + c;
        acc += __uint_as_float(((unsigned)xh[i0]) << 16) + __uint_as_float(((unsigned)xl[i0]) << 16);
    }
    float cf = (float)(e0 - s0);
    xg[g * 128 + c] = acc / fmaxf(cf, 1.f);
}

// ---------------- lat/lon heads ----------------
__global__ void head_kernel(const float* __restrict__ xg,
                            const float* __restrict__ w1a, const float* __restrict__ b1a,
                            const float* __restrict__ w2a, const float* __restrict__ b2a,
                            const float* __restrict__ w1o, const float* __restrict__ b1o,
                            const float* __restrict__ w2o, const float* __restrict__ b2o,
                            const int* __restrict__ flags, void* __restrict__ out) {
    int g = blockIdx.x;
    int wave = threadIdx.x >> 6;
    int lane = threadIdx.x & 63;
    const float* w1 = wave ? w1o : w1a;
    const float* b1 = wave ? b1o : b1a;
    const float* w2 = wave ? w2o : w2a;
    const float* b2 = wave ? b2o : b2a;
    float acc = b1[lane];
    for (int c = 0; c < 128; c++)
        acc += xg[g * 128 + c] * w1[c * 64 + lane];
    acc = fmaxf(acc, 0.f);
    float contrib = wred_sum(acc * w2[lane]);
    if (lane == 0) {
        float r = contrib + b2[0];
        if (flags[0]) ((float*)out)[wave * NG + g] = r;
        else          ((bf16*)out)[wave * NG + g] = __float2bfloat16(r);
    }
}

extern "C" void kernel_launch(void* const* d_in, const int* in_sizes, int n_in,
                              void* d_out, int out_size, void* d_ws, size_t ws_size,
                              hipStream_t stream) {
    static const int fidx[32] = {0,1, 4,5,6,7,8,9, 10,11,12,13, 14,15,16,17,
                                 18,19,20,21, 22,23,24,25, 26,27,28,29, 30,31,32,33};
    static const int flen[32] = {200000, 3200000, 128, 32, 2048, 32, 4096, 64,
                                 8192, 128, 128, 128, 16384, 128, 128, 128,
                                 16384, 128, 128, 128, 384, 384, 384, 384,
                                 8192, 64, 64, 1, 8192, 64, 64, 1};
    CvtArgs ca;
    int O[32];
    int tot = 0, blk = 0;
    for (int i = 0; i < 32; i++) {
        int cl = (i == 1) ? 0 : flen[i];        // skip wavef fp32 conversion (unused)
        ca.src[i] = d_in[fidx[i]];
        ca.len[i] = cl;
        O[i] = tot;
        ca.dst_off[i] = tot;
        ca.blk_base[i] = blk;
        tot += (flen[i] + 63) & ~63;
        blk += (cl + 1023) / 1024;
    }
    ca.blk_base[32] = blk;

    char* w = (char*)d_ws;
    auto alloc = [&](size_t bytes) -> char* {
        char* p = w;
        w += (bytes + 255) & ~(size_t)255;
        return p;
    };
    int*   flags  = (int*)alloc(256);
    float* cf     = (float*)alloc((size_t)tot * 4);
    int*   ei32   = (int*)alloc((size_t)2 * NE * 4);
    int*   bat32  = (int*)alloc((size_t)NN * 4);
    short* wfhi   = (short*)alloc((size_t)NNP * 64 * 2);
    short* wflo   = (short*)alloc((size_t)NNP * 64 * 2);
    short* x0hi   = (short*)alloc((size_t)NNP * 64 * 2);
    short* x0lo   = (short*)alloc((size_t)NNP * 64 * 2);
    short* xAhi   = (short*)alloc((size_t)NNP * 128 * 2);
    short* xAlo   = (short*)alloc((size_t)NNP * 128 * 2);
    short* xBhi   = (short*)alloc((size_t)NNP * 128 * 2);
    short* xBlo   = (short*)alloc((size_t)NNP * 128 * 2);
    short* h      = (short*)alloc((size_t)NNP * 128 * 2);
    float* sA     = (float*)alloc((size_t)NN * 2 * 4);
    float* dA     = (float*)alloc((size_t)NN * 2 * 4);
    int*   off    = (int*)alloc((size_t)(NN + 1) * 4);
    int*   csr    = (int*)alloc((size_t)ET * 4);
    int*   gbh    = (int*)alloc((size_t)NB * 4);
    int*   gbo    = (int*)alloc((size_t)(NB + 1) * 4);
    int*   bcur   = (int*)alloc((size_t)NB * 4);
    uint2* bkt    = (uint2*)alloc((size_t)ET * 8);
    int*   starts = (int*)alloc((size_t)(NG + 1) * 4);
    float* xg     = (float*)alloc((size_t)NG * 128 * 4);
    short* wtall  = (short*)alloc((size_t)40960 * 2);
    short* wavewT = (short*)alloc((size_t)2048 * 2);
    short* combwT = (short*)alloc((size_t)4096 * 2);
    short* wt0 = wtall, *wt1 = wtall + 8192, *wt2 = wtall + 24576;

    detect_kernel<<<1, 256, 0, stream>>>((const unsigned int*)d_in[0],
                                         (const unsigned int*)d_in[2], flags);
    cvt_float_kernel<<<blk, 256, 0, stream>>>(ca, cf, flags);
    cvt_int_kernel<<<(2 * NE + NN + 255) / 256, 256, 0, stream>>>(d_in[2], d_in[3],
                                                                  ei32, bat32, flags);
    wt_all_kernel<<<184, 256, 0, stream>>>(cf, wtall, wavewT, combwT,
                                           O[8], O[12], O[16], O[4], O[6]);
    prep_wf_kernel<<<(NNP * 64 + 255) / 256, 256, 0, stream>>>(d_in[1], wfhi, wflo, flags);

    hipMemsetAsync(gbh, 0, (size_t)NB * 4, stream);

    encode_mfma_kernel<<<NNP / 64, 256, 0, stream>>>(cf + O[0], cf + O[2], cf + O[3],
                                                     wfhi, wflo, wavewT, cf + O[5],
                                                     combwT, cf + O[7], x0hi, x0lo);
    // CSR via bucket sort
    bucket_hist_kernel<<<NEB, 256, 0, stream>>>(ei32, gbh);
    bucket_scan_kernel<<<1, 256, 0, stream>>>(gbh, gbo, bcur);
    bucket_scatter_kernel<<<NEB, 256, 0, stream>>>(ei32, bcur, bkt);
    bucket_finalize_kernel<<<NB, 256, 0, stream>>>(bkt, gbo, off, csr);

    int gblk = NNP / 64;
    // layer 0
    gemm_mfma_kernel<<<gblk, 256, 0, stream>>>(x0hi, x0lo, wt0, cf + O[9], cf + O[10],
                                               h, sA, dA, 64, NN);
    gat_aggregate_kernel<<<(NN + 3) / 4, 256, 0, stream>>>(
        (const unsigned*)h, sA, dA, off, csr, cf + O[11],
        cf + O[20], cf + O[21], cf + O[22], cf + O[23],
        nullptr, nullptr, (unsigned*)xAhi, (unsigned*)xAlo, NN);
    // layer 1
    gemm_mfma_kernel<<<gblk, 256, 0, stream>>>(xAhi, xAlo, wt1, cf + O[13], cf + O[14],
                                               h, sA, dA, 128, NN);
    gat_aggregate_kernel<<<(NN + 3) / 4, 256, 0, stream>>>(
        (const unsigned*)h, sA, dA, off, csr, cf + O[15],
        cf + O[20] + 128, cf + O[21] + 128, cf + O[22] + 128, cf + O[23] + 128,
        (const unsigned*)xAhi, (const unsigned*)xAlo, (unsigned*)xBhi, (unsigned*)xBlo, NN);
    // layer 2
    gemm_mfma_kernel<<<gblk, 256, 0, stream>>>(xBhi, xBlo, wt2, cf + O[17], cf + O[18],
                                               h, sA, dA, 128, NN);
    gat_aggregate_kernel<<<(NN + 3) / 4, 256, 0, stream>>>(
        (const unsigned*)h, sA, dA, off, csr, cf + O[19],
        cf + O[20] + 256, cf + O[21] + 256, cf + O[22] + 256, cf + O[23] + 256,
        (const unsigned*)xBhi, (const unsigned*)xBlo, (unsigned*)xAhi, (unsigned*)xAlo, NN);

    bounds_kernel<<<1, 512, 0, stream>>>(bat32, starts);
    pool_kernel<<<NG, 128, 0, stream>>>((const unsigned short*)xAhi, (const unsigned short*)xAlo,
                                        starts, xg);
    head_kernel<<<NG, 128, 0, stream>>>(xg,
                                        cf + O[24], cf + O[25], cf + O[26], cf + O[27],
                                        cf + O[28], cf + O[29], cf + O[30], cf + O[31],
                                        flags, d_out);
}

// Round 6
// 423.098 us; speedup vs baseline: 2.2105x; 1.0648x over previous
//
#include <hip/hip_runtime.h>
#include <hip/hip_bf16.h>
#include <stdint.h>

#define NN 50000
#define NNP 50048   // padded to 64-node gemm tiles
#define NE 800000
#define ET 850000   // NE + NN self loops
#define NG 256
#define CAP 128     // per-node edge capacity for LDS alpha cache
#define NB 392      // buckets of 128 dst nodes (392*128 = 50176 >= NNP)
#define EB 4096     // edges per block in bucket hist/scatter
#define NEB ((ET + EB - 1) / EB)   // 208

typedef __hip_bfloat16 bf16;
typedef __attribute__((ext_vector_type(8))) short short8;
typedef __attribute__((ext_vector_type(4))) float floatx4;

__device__ __forceinline__ float b2f(bf16 v) { return __bfloat162float(v); }
__device__ __forceinline__ float lrelu(float x) { return x > 0.f ? x : 0.2f * x; }
__device__ __forceinline__ short f2b(float f) {          // RNE bf16 round
    unsigned u = __float_as_uint(f);
    unsigned r = (u + 0x7FFFu + ((u >> 16) & 1u)) >> 16;
    return (short)r;
}
__device__ __forceinline__ float sh2f(short s) { return __uint_as_float(((unsigned)(unsigned short)s) << 16); }
__device__ __forceinline__ float blo(unsigned u) { return __uint_as_float(u << 16); }
__device__ __forceinline__ float bhi(unsigned u) { return __uint_as_float(u & 0xFFFF0000u); }
__device__ __forceinline__ unsigned pck(float a, float b) {
    return ((unsigned)(unsigned short)f2b(a)) | (((unsigned)(unsigned short)f2b(b)) << 16);
}

__device__ __forceinline__ float wred_sum(float v) {
    for (int o = 32; o > 0; o >>= 1) v += __shfl_xor(v, o, 64);
    return v;
}
__device__ __forceinline__ float wred_max(float v) {
    for (int o = 32; o > 0; o >>= 1) v = fmaxf(v, __shfl_xor(v, o, 64));
    return v;
}

// ---------------- dtype detection + gbh zero ----------------
__global__ void detect_kernel(const unsigned int* __restrict__ meta_words,
                              const unsigned int* __restrict__ ei_words,
                              int* __restrict__ flags, int* __restrict__ gbh) {
    __shared__ int insane, odd_nonzero;
    for (int k = threadIdx.x; k < NB; k += 256) gbh[k] = 0;
    if (threadIdx.x == 0) { insane = 0; odd_nonzero = 0; }
    __syncthreads();
    int cnt = 0;
    for (int k = 0; k < 8; k++) {
        unsigned int w = meta_words[threadIdx.x * 8 + k];
        int elo = (int)(((w & 0xFFFFu) >> 7) & 0xFF);
        int ehi = (int)(((w >> 16) >> 7) & 0xFF);
        if (elo >= 0x8D) cnt++;
        if (ehi >= 0x8D) cnt++;
    }
    if (cnt) atomicAdd(&insane, cnt);
    if (ei_words[threadIdx.x * 2 + 1] != 0u) atomicAdd(&odd_nonzero, 1);
    __syncthreads();
    if (threadIdx.x == 0) {
        flags[0] = (insane >= 4) ? 1 : 0;       // fp32 floats
        flags[1] = (odd_nonzero == 0) ? 1 : 0;  // int64 ints
    }
}

// ---------------- mega prep: cvt_float | weight-T | wavef prep | int cvt ----------------
struct PrepArgs {
    const void* src[32];
    int len[32];
    int dst_off[32];
    int blk_base[33];
    int cvtBlks, wtBlks, wfBlks, intBlks;
    const void* w0; const void* w1; const void* w2;
    const void* ww; const void* wc;
    const void* wf_src;
    const void* ei_src;
    const void* bat_src;
};

__global__ void prep_kernel(PrepArgs a, float* __restrict__ cf,
                            short* __restrict__ wtall, short* __restrict__ wavewT,
                            short* __restrict__ combwT,
                            short* __restrict__ wfhi, short* __restrict__ wflo,
                            int* __restrict__ ei32, int* __restrict__ bat32,
                            const int* __restrict__ flags) {
    int b = blockIdx.x;
    bool fp32f = flags[0] != 0;
    if (b < a.cvtBlks) {
        int ai = 0;
        while (b >= a.blk_base[ai + 1]) ai++;
        int base = (b - a.blk_base[ai]) * 1024 + threadIdx.x;
        const float* sf = (const float*)a.src[ai];
        const bf16* sh = (const bf16*)a.src[ai];
        float* d = cf + a.dst_off[ai];
        int len = a.len[ai];
        #pragma unroll
        for (int u = 0; u < 4; u++) {
            int i = base + u * 256;
            if (i < len) d[i] = fp32f ? sf[i] : b2f(sh[i]);
        }
        return;
    }
    b -= a.cvtBlks;
    if (b < a.wtBlks) {
        int idx = b * 256 + threadIdx.x;
        const void* src; short* dst; int K, N, loc;
        if (idx < 8192)        { src = a.w0; dst = wtall;          K = 64;  N = 128; loc = idx; }
        else if (idx < 24576)  { src = a.w1; dst = wtall + 8192;   K = 128; N = 128; loc = idx - 8192; }
        else if (idx < 40960)  { src = a.w2; dst = wtall + 24576;  K = 128; N = 128; loc = idx - 24576; }
        else if (idx < 43008)  { src = a.ww; dst = wavewT;         K = 64;  N = 32;  loc = idx - 40960; }
        else if (idx < 47104)  { src = a.wc; dst = combwT;         K = 64;  N = 64;  loc = idx - 43008; }
        else return;
        int nch = loc / K, k = loc % K;
        int si = k * N + nch;
        dst[loc] = fp32f ? f2b(((const float*)src)[si]) : ((const short*)src)[si];
        return;
    }
    b -= a.wtBlks;
    if (b < a.wfBlks) {
        int idx = b * 256 + threadIdx.x;
        int i8 = idx * 8;
        if (i8 >= NNP * 64) return;
        short8 h = {0, 0, 0, 0, 0, 0, 0, 0};
        short8 l = {0, 0, 0, 0, 0, 0, 0, 0};
        if (i8 < NN * 64) {
            if (fp32f) {
                const float* sf = (const float*)a.wf_src + i8;
                #pragma unroll
                for (int k = 0; k < 8; k++) {
                    float v = sf[k];
                    short hh = f2b(v);
                    h[k] = hh;
                    l[k] = f2b(v - sh2f(hh));
                }
            } else {
                h = *(const short8*)((const short*)a.wf_src + i8);
            }
        }
        *(short8*)(wfhi + i8) = h;
        *(short8*)(wflo + i8) = l;
        return;
    }
    b -= a.wfBlks;
    int idx = b * 256 + threadIdx.x;
    if (idx >= 825000) return;
    bool i64f = flags[1] != 0;
    if (idx < 800000) {
        int2 o;
        if (i64f) { int4 v = ((const int4*)a.ei_src)[idx]; o.x = v.x; o.y = v.z; }
        else      { o = ((const int2*)a.ei_src)[idx]; }
        *(int2*)(ei32 + idx * 2) = o;
    } else {
        int k = idx - 800000;
        int2 o;
        if (i64f) { int4 v = ((const int4*)a.bat_src)[k]; o.x = v.x; o.y = v.z; }
        else      { o = ((const int2*)a.bat_src)[k]; }
        *(int2*)(bat32 + k * 2) = o;
    }
}

// ---------------- MFMA encoder -> x0 bf16 [NNP][64] ----------------
__global__ __launch_bounds__(256) void encode_mfma_kernel(
        const float* __restrict__ meta, const float* __restrict__ meta_w,
        const float* __restrict__ meta_b,
        const short* __restrict__ wfhi, const short* __restrict__ wflo,
        const short* __restrict__ wavewT, const float* __restrict__ wave_b,
        const short* __restrict__ combwT, const float* __restrict__ comb_b,
        short* __restrict__ xout, const int* __restrict__ flags) {
    __shared__ short xc_hi[64][72];
    __shared__ short xc_lo[64][72];
    int t = threadIdx.x;
    int wave = t >> 6, lane = t & 63;
    int m16 = lane & 15, quad = lane >> 4;
    int nblk = blockIdx.x * 64;
    bool fp32f = flags[0] != 0;

    #pragma unroll
    for (int u = 0; u < 8; u++) {
        int idx = u * 256 + t;
        int node_l = idx >> 5, ch = idx & 31;
        int node = nblk + node_l;
        float acc = meta_b[ch];
        if (node < NN) {
            #pragma unroll
            for (int k = 0; k < 4; k++)
                acc += meta[node * 4 + k] * meta_w[k * 32 + ch];
        }
        float v = fmaxf(acc, 0.f);
        short hh = f2b(v);
        xc_hi[node_l][ch] = hh;
        xc_lo[node_l][ch] = f2b(v - sh2f(hh));
    }

    int row0 = nblk + wave * 16;
    const short* pah = wfhi + (size_t)(row0 + m16) * 64 + quad * 8;
    const short* pal = wflo + (size_t)(row0 + m16) * 64 + quad * 8;
    floatx4 wacc[2];
    wacc[0] = (floatx4)(0.f); wacc[1] = (floatx4)(0.f);
    #pragma unroll
    for (int ks = 0; ks < 64; ks += 32) {
        short8 ah = *(const short8*)(pah + ks);
        #pragma unroll
        for (int c = 0; c < 2; c++) {
            short8 b = *(const short8*)(wavewT + (c * 16 + m16) * 64 + ks + quad * 8);
            wacc[c] = __builtin_amdgcn_mfma_f32_16x16x32_bf16(ah, b, wacc[c], 0, 0, 0);
        }
        if (fp32f) {
            short8 al = *(const short8*)(pal + ks);
            #pragma unroll
            for (int c = 0; c < 2; c++) {
                short8 b = *(const short8*)(wavewT + (c * 16 + m16) * 64 + ks + quad * 8);
                wacc[c] = __builtin_amdgcn_mfma_f32_16x16x32_bf16(al, b, wacc[c], 0, 0, 0);
            }
        }
    }
    #pragma unroll
    for (int c = 0; c < 2; c++) {
        float bb = wave_b[c * 16 + m16];
        #pragma unroll
        for (int r = 0; r < 4; r++) {
            int node_l = wave * 16 + quad * 4 + r;
            int ch = 32 + c * 16 + m16;
            float v = fmaxf(wacc[c][r] + bb, 0.f);
            short hh = f2b(v);
            xc_hi[node_l][ch] = hh;
            xc_lo[node_l][ch] = f2b(v - sh2f(hh));
        }
    }
    __syncthreads();

    floatx4 acc2[4];
    #pragma unroll
    for (int c = 0; c < 4; c++) acc2[c] = (floatx4)(0.f);
    #pragma unroll
    for (int ks = 0; ks < 64; ks += 32) {
        short8 ah = *(const short8*)&xc_hi[wave * 16 + m16][ks + quad * 8];
        short8 al = *(const short8*)&xc_lo[wave * 16 + m16][ks + quad * 8];
        #pragma unroll
        for (int c = 0; c < 4; c++) {
            short8 b = *(const short8*)(combwT + (c * 16 + m16) * 64 + ks + quad * 8);
            acc2[c] = __builtin_amdgcn_mfma_f32_16x16x32_bf16(ah, b, acc2[c], 0, 0, 0);
            acc2[c] = __builtin_amdgcn_mfma_f32_16x16x32_bf16(al, b, acc2[c], 0, 0, 0);
        }
    }
    #pragma unroll
    for (int c = 0; c < 4; c++) {
        int ch = c * 16 + m16;
        float bb = comb_b[ch];
        #pragma unroll
        for (int r = 0; r < 4; r++) {
            int node = nblk + wave * 16 + quad * 4 + r;
            float v = fmaxf(acc2[c][r] + bb, 0.f);
            xout[(size_t)node * 64 + ch] = f2b(v);
        }
    }
}

// ---------------- CSR build: 2-level bucket sort (bucket = dst >> 7) ----------------
__global__ void bucket_hist_kernel(const int* __restrict__ ei, int* __restrict__ gbh) {
    __shared__ int lh[NB];
    int t = threadIdx.x;
    for (int k = t; k < NB; k += 256) lh[k] = 0;
    __syncthreads();
    int base = blockIdx.x * EB;
    #pragma unroll 4
    for (int u = 0; u < EB / 256; u++) {
        int i = base + u * 256 + t;
        if (i < ET) {
            int dst = (i < NE) ? ei[NE + i] : (i - NE);
            atomicAdd(&lh[dst >> 7], 1);
        }
    }
    __syncthreads();
    for (int k = t; k < NB; k += 256)
        if (lh[k]) atomicAdd(&gbh[k], lh[k]);
}

__global__ void scan_bounds_kernel(const int* __restrict__ gbh, int* __restrict__ gbo,
                                   int* __restrict__ bcur,
                                   const int* __restrict__ batch, int* __restrict__ starts) {
    if (blockIdx.x == 0) {
        __shared__ int buf[512];
        int t = threadIdx.x;
        int v = (t < NB) ? gbh[t] : 0;
        buf[t] = v;
        __syncthreads();
        for (int o = 1; o < 512; o <<= 1) {
            int x = (t >= o) ? buf[t - o] : 0;
            __syncthreads();
            buf[t] += x;
            __syncthreads();
        }
        if (t < NB) { int e = buf[t] - v; gbo[t] = e; bcur[t] = e; }
        if (t == 0) gbo[NB] = ET;
    } else {
        int g = threadIdx.x;
        if (g <= NG) {
            int lo = 0, hi = NN;
            while (lo < hi) {
                int mid = (lo + hi) >> 1;
                if (batch[mid] < g) lo = mid + 1; else hi = mid;
            }
            starts[g] = lo;
        }
    }
}

__global__ void bucket_scatter_kernel(const int* __restrict__ ei, int* __restrict__ bcur,
                                      uint2* __restrict__ bkt) {
    __shared__ int lh[NB];
    __shared__ int lbase[NB];
    int t = threadIdx.x;
    for (int k = t; k < NB; k += 256) lh[k] = 0;
    __syncthreads();
    int base = blockIdx.x * EB;
    #pragma unroll 4
    for (int u = 0; u < EB / 256; u++) {
        int i = base + u * 256 + t;
        if (i < ET) {
            int dst = (i < NE) ? ei[NE + i] : (i - NE);
            atomicAdd(&lh[dst >> 7], 1);
        }
    }
    __syncthreads();
    for (int k = t; k < NB; k += 256) {
        int c = lh[k];
        lbase[k] = c ? atomicAdd(&bcur[k], c) : 0;
        lh[k] = 0;
    }
    __syncthreads();
    #pragma unroll 4
    for (int u = 0; u < EB / 256; u++) {
        int i = base + u * 256 + t;
        if (i < ET) {
            int src, dst;
            if (i < NE) { src = ei[i]; dst = ei[NE + i]; }
            else        { src = i - NE; dst = i - NE; }
            int b = dst >> 7;
            int pos = lbase[b] + atomicAdd(&lh[b], 1);
            bkt[pos] = make_uint2((unsigned)src, (unsigned)dst);
        }
    }
}

__global__ void bucket_finalize_kernel(const uint2* __restrict__ bkt,
                                       const int* __restrict__ gbo,
                                       int* __restrict__ off, int* __restrict__ csr) {
    __shared__ int hist[128];
    __shared__ int cur[128];
    int b = blockIdx.x;
    int t = threadIdx.x;
    int e0 = gbo[b], e1 = gbo[b + 1];
    if (t < 128) hist[t] = 0;
    __syncthreads();
    for (int i = e0 + t; i < e1; i += 256)
        atomicAdd(&hist[bkt[i].y & 127], 1);
    __syncthreads();
    int v = (t < 128) ? hist[t] : 0;
    if (t < 128) cur[t] = v;
    __syncthreads();
    for (int o = 1; o < 128; o <<= 1) {
        int x = (t < 128 && t >= o) ? cur[t - o] : 0;
        __syncthreads();
        if (t < 128) cur[t] += x;
        __syncthreads();
    }
    if (t < 128) {
        int ex = e0 + cur[t] - v;
        int node = b * 128 + t;
        if (node <= NN) off[node] = ex;
        cur[t] = ex;
    }
    __syncthreads();
    for (int i = e0 + t; i < e1; i += 256) {
        uint2 e = bkt[i];
        int pos = atomicAdd(&cur[e.y & 127], 1);
        csr[pos] = (int)e.x;
    }
}

// ---------------- MFMA GEMM + fused s/d logits (bf16 x) ----------------
__global__ __launch_bounds__(256) void gemm_mfma_kernel(
        const short* __restrict__ x, const short* __restrict__ wt,
        const float* __restrict__ a_s, const float* __restrict__ a_d,
        short* __restrict__ h, float* __restrict__ s, float* __restrict__ d,
        int K, int n) {
    int wave = threadIdx.x >> 6;
    int lane = threadIdx.x & 63;
    int row0 = (blockIdx.x * 4 + wave) * 16;
    int m16 = lane & 15;
    int quad = lane >> 4;
    int kq = quad * 8;

    const short* pa = x + (size_t)(row0 + m16) * K + kq;

    floatx4 acc[8];
    #pragma unroll
    for (int c = 0; c < 8; c++) acc[c] = (floatx4)(0.f);

    for (int ks = 0; ks < K; ks += 32) {
        short8 av = *(const short8*)(pa + ks);
        #pragma unroll
        for (int c = 0; c < 8; c++) {
            short8 b = *(const short8*)(wt + (size_t)(c * 16 + m16) * K + ks + kq);
            acc[c] = __builtin_amdgcn_mfma_f32_16x16x32_bf16(av, b, acc[c], 0, 0, 0);
        }
    }

    #pragma unroll
    for (int c = 0; c < 8; c++) {
        #pragma unroll
        for (int r = 0; r < 4; r++) {
            int node = row0 + quad * 4 + r;
            if (node < n) h[(size_t)node * 128 + c * 16 + m16] = f2b(acc[c][r]);
        }
    }

    float sp[2][4] = {{0, 0, 0, 0}, {0, 0, 0, 0}};
    float dp[2][4] = {{0, 0, 0, 0}, {0, 0, 0, 0}};
    #pragma unroll
    for (int c = 0; c < 8; c++) {
        float as_ = a_s[c * 16 + m16];
        float ad_ = a_d[c * 16 + m16];
        int hh = c >> 2;
        #pragma unroll
        for (int r = 0; r < 4; r++) {
            sp[hh][r] += acc[c][r] * as_;
            dp[hh][r] += acc[c][r] * ad_;
        }
    }
    #pragma unroll
    for (int o = 1; o < 16; o <<= 1) {
        #pragma unroll
        for (int hh = 0; hh < 2; hh++)
            #pragma unroll
            for (int r = 0; r < 4; r++) {
                sp[hh][r] += __shfl_xor(sp[hh][r], o, 64);
                dp[hh][r] += __shfl_xor(dp[hh][r], o, 64);
            }
    }
    if (m16 == 0) {
        #pragma unroll
        for (int r = 0; r < 4; r++) {
            int node = row0 + quad * 4 + r;
            if (node < n) {
                s[node * 2 + 0] = sp[0][r];
                s[node * 2 + 1] = sp[1][r];
                d[node * 2 + 0] = dp[0][r];
                d[node * 2 + 1] = dp[1][r];
            }
        }
    }
}

// ---------------- edge softmax + aggregation + bias + BN + res + relu ----------------
__global__ __launch_bounds__(256) void gat_aggregate_kernel(
        const unsigned* __restrict__ hp, const float* __restrict__ sv,
        const float* __restrict__ dv, const int* __restrict__ off,
        const int* __restrict__ csr, const float* __restrict__ bias,
        const float* __restrict__ bn_g, const float* __restrict__ bn_b,
        const float* __restrict__ bn_m, const float* __restrict__ bn_v,
        const unsigned* __restrict__ res, unsigned* __restrict__ out, int n) {
    __shared__ float exs[4][CAP][2];
    __shared__ int scs[4][CAP];
    int w = threadIdx.x >> 6;
    int lane = threadIdx.x & 63;
    int node = blockIdx.x * 4 + w;
    bool ok = node < n;
    int begin = 0, end = 0, deg = 0;
    float d0 = 0.f, d1 = 0.f;
    if (ok) {
        begin = off[node]; end = off[node + 1]; deg = end - begin;
        d0 = dv[node * 2 + 0]; d1 = dv[node * 2 + 1];
    }
    bool fits = deg <= CAP;
    float inv0 = 0.f, inv1 = 0.f;

    if (ok && fits) {
        int i0 = begin + lane, i1 = begin + 64 + lane;
        int sa = (i0 < end) ? csr[i0] : -1;
        int sb = (i1 < end) ? csr[i1] : -1;
        float e0a = -3e38f, e1a = -3e38f, e0b = -3e38f, e1b = -3e38f;
        if (sa >= 0) {
            float2 sp = *(const float2*)(sv + sa * 2);
            e0a = lrelu(sp.x + d0); e1a = lrelu(sp.y + d1);
        }
        if (sb >= 0) {
            float2 sp = *(const float2*)(sv + sb * 2);
            e0b = lrelu(sp.x + d0); e1b = lrelu(sp.y + d1);
        }
        float m0 = wred_max(fmaxf(e0a, e0b));
        float m1 = wred_max(fmaxf(e1a, e1b));
        float x0a = 0.f, x1a = 0.f, x0b = 0.f, x1b = 0.f;
        if (sa >= 0) {
            x0a = __expf(e0a - m0); x1a = __expf(e1a - m1);
            exs[w][lane][0] = x0a; exs[w][lane][1] = x1a; scs[w][lane] = sa;
        }
        if (sb >= 0) {
            x0b = __expf(e0b - m0); x1b = __expf(e1b - m1);
            exs[w][lane + 64][0] = x0b; exs[w][lane + 64][1] = x1b; scs[w][lane + 64] = sb;
        }
        float z0 = wred_sum(x0a + x0b);
        float z1 = wred_sum(x1a + x1b);
        inv0 = 1.f / (z0 + 1e-16f);
        inv1 = 1.f / (z1 + 1e-16f);
    }
    __syncthreads();
    if (!ok) return;

    if (fits) {
        int ll = lane & 15;        // channel group: ch 8*ll .. 8*ll+7
        int grp = lane >> 4;       // edge slot 0..3
        int hsel = (ll >= 8) ? 1 : 0;
        const uint4* hp4 = (const uint4*)hp;
        float a0 = 0, a1 = 0, a2 = 0, a3 = 0, a4 = 0, a5 = 0, a6 = 0, a7 = 0;
        for (int i = 0; i < deg; i += 4) {
            int e = i + grp;
            if (e < deg) {
                int src = scs[w][e];
                float a = exs[w][e][hsel];
                uint4 u = hp4[(size_t)src * 16 + ll];
                a0 += a * blo(u.x); a1 += a * bhi(u.x);
                a2 += a * blo(u.y); a3 += a * bhi(u.y);
                a4 += a * blo(u.z); a5 += a * bhi(u.z);
                a6 += a * blo(u.w); a7 += a * bhi(u.w);
            }
        }
        a0 += __shfl_xor(a0, 16, 64); a0 += __shfl_xor(a0, 32, 64);
        a1 += __shfl_xor(a1, 16, 64); a1 += __shfl_xor(a1, 32, 64);
        a2 += __shfl_xor(a2, 16, 64); a2 += __shfl_xor(a2, 32, 64);
        a3 += __shfl_xor(a3, 16, 64); a3 += __shfl_xor(a3, 32, 64);
        a4 += __shfl_xor(a4, 16, 64); a4 += __shfl_xor(a4, 32, 64);
        a5 += __shfl_xor(a5, 16, 64); a5 += __shfl_xor(a5, 32, 64);
        a6 += __shfl_xor(a6, 16, 64); a6 += __shfl_xor(a6, 32, 64);
        a7 += __shfl_xor(a7, 16, 64); a7 += __shfl_xor(a7, 32, 64);
        float inv = hsel ? inv1 : inv0;
        a0 *= inv; a1 *= inv; a2 *= inv; a3 *= inv;
        a4 *= inv; a5 *= inv; a6 *= inv; a7 *= inv;

        float4 bi0 = ((const float4*)bias)[2 * ll],  bi1 = ((const float4*)bias)[2 * ll + 1];
        float4 g0  = ((const float4*)bn_g)[2 * ll],  g1  = ((const float4*)bn_g)[2 * ll + 1];
        float4 be0 = ((const float4*)bn_b)[2 * ll],  be1 = ((const float4*)bn_b)[2 * ll + 1];
        float4 mu0 = ((const float4*)bn_m)[2 * ll],  mu1 = ((const float4*)bn_m)[2 * ll + 1];
        float4 va0 = ((const float4*)bn_v)[2 * ll],  va1 = ((const float4*)bn_v)[2 * ll + 1];
        float v0 = (a0 + bi0.x - mu0.x) * (g0.x * rsqrtf(va0.x + 1e-5f)) + be0.x;
        float v1 = (a1 + bi0.y - mu0.y) * (g0.y * rsqrtf(va0.y + 1e-5f)) + be0.y;
        float v2 = (a2 + bi0.z - mu0.z) * (g0.z * rsqrtf(va0.z + 1e-5f)) + be0.z;
        float v3 = (a3 + bi0.w - mu0.w) * (g0.w * rsqrtf(va0.w + 1e-5f)) + be0.w;
        float v4 = (a4 + bi1.x - mu1.x) * (g1.x * rsqrtf(va1.x + 1e-5f)) + be1.x;
        float v5 = (a5 + bi1.y - mu1.y) * (g1.y * rsqrtf(va1.y + 1e-5f)) + be1.y;
        float v6 = (a6 + bi1.z - mu1.z) * (g1.z * rsqrtf(va1.z + 1e-5f)) + be1.z;
        float v7 = (a7 + bi1.w - mu1.w) * (g1.w * rsqrtf(va1.w + 1e-5f)) + be1.w;
        if (res) {
            uint4 r = ((const uint4*)res)[(size_t)node * 16 + ll];
            v0 += blo(r.x); v1 += bhi(r.x); v2 += blo(r.y); v3 += bhi(r.y);
            v4 += blo(r.z); v5 += bhi(r.z); v6 += blo(r.w); v7 += bhi(r.w);
        }
        v0 = fmaxf(v0, 0.f); v1 = fmaxf(v1, 0.f); v2 = fmaxf(v2, 0.f); v3 = fmaxf(v3, 0.f);
        v4 = fmaxf(v4, 0.f); v5 = fmaxf(v5, 0.f); v6 = fmaxf(v6, 0.f); v7 = fmaxf(v7, 0.f);
        if (lane < 16) {
            ((uint4*)out)[(size_t)node * 16 + ll] =
                make_uint4(pck(v0, v1), pck(v2, v3), pck(v4, v5), pck(v6, v7));
        }
    } else {
        // fallback (deg > CAP): 3-pass, 2 channels/lane
        float mm0 = -3e38f, mm1 = -3e38f;
        for (int i = begin + lane; i < end; i += 64) {
            int sc = csr[i];
            float2 sp = *(const float2*)(sv + sc * 2);
            mm0 = fmaxf(mm0, lrelu(sp.x + d0));
            mm1 = fmaxf(mm1, lrelu(sp.y + d1));
        }
        mm0 = wred_max(mm0); mm1 = wred_max(mm1);
        float z0 = 0.f, z1 = 0.f;
        for (int i = begin + lane; i < end; i += 64) {
            int sc = csr[i];
            float2 sp = *(const float2*)(sv + sc * 2);
            z0 += __expf(lrelu(sp.x + d0) - mm0);
            z1 += __expf(lrelu(sp.y + d1) - mm1);
        }
        z0 = wred_sum(z0); z1 = wred_sum(z1);
        float i0_ = 1.f / (z0 + 1e-16f), i1_ = 1.f / (z1 + 1e-16f);
        bool head0 = lane < 32;
        float acc0 = 0.f, acc1 = 0.f;
        for (int i = begin; i < end; i++) {
            int sc = csr[i];
            float2 sp = *(const float2*)(sv + sc * 2);
            float a = head0 ? __expf(lrelu(sp.x + d0) - mm0) * i0_
                            : __expf(lrelu(sp.y + d1) - mm1) * i1_;
            unsigned u = hp[(size_t)sc * 64 + lane];
            acc0 += a * blo(u);
            acc1 += a * bhi(u);
        }
        int c0 = 2 * lane, c1 = c0 + 1;
        float v0 = acc0 + bias[c0];
        float v1 = acc1 + bias[c1];
        v0 = (v0 - bn_m[c0]) * (bn_g[c0] * rsqrtf(bn_v[c0] + 1e-5f)) + bn_b[c0];
        v1 = (v1 - bn_m[c1]) * (bn_g[c1] * rsqrtf(bn_v[c1] + 1e-5f)) + bn_b[c1];
        if (res) {
            unsigned r = res[(size_t)node * 64 + lane];
            v0 += blo(r);
            v1 += bhi(r);
        }
        v0 = fmaxf(v0, 0.f);
        v1 = fmaxf(v1, 0.f);
        out[(size_t)node * 64 + lane] = pck(v0, v1);
    }
}

// ---------------- global mean pool (x bf16 packed) ----------------
__global__ void pool_kernel(const unsigned* __restrict__ x,
                            const int* __restrict__ starts, float* __restrict__ xg) {
    __shared__ float part[4][128];
    int g = blockIdx.x;
    int wv = threadIdx.x >> 6, lane = threadIdx.x & 63;
    int s0 = starts[g], e0 = starts[g + 1];
    float a0 = 0.f, a1 = 0.f;
    for (int node = s0 + wv; node < e0; node += 4) {
        unsigned u = x[(size_t)node * 64 + lane];
        a0 += blo(u);
        a1 += bhi(u);
    }
    part[wv][lane * 2] = a0;
    part[wv][lane * 2 + 1] = a1;
    __syncthreads();
    if (wv == 0) {
        float t0 = part[0][lane * 2] + part[1][lane * 2] + part[2][lane * 2] + part[3][lane * 2];
        float t1 = part[0][lane * 2 + 1] + part[1][lane * 2 + 1] + part[2][lane * 2 + 1] + part[3][lane * 2 + 1];
        float icf = 1.f / fmaxf((float)(e0 - s0), 1.f);
        xg[g * 128 + 2 * lane] = t0 * icf;
        xg[g * 128 + 2 * lane + 1] = t1 * icf;
    }
}

// ---------------- lat/lon heads ----------------
__global__ void head_kernel(const float* __restrict__ xg,
                            const float* __restrict__ w1a, const float* __restrict__ b1a,
                            const float* __restrict__ w2a, const float* __restrict__ b2a,
                            const float* __restrict__ w1o, const float* __restrict__ b1o,
                            const float* __restrict__ w2o, const float* __restrict__ b2o,
                            const int* __restrict__ flags, void* __restrict__ out) {
    int g = blockIdx.x;
    int wave = threadIdx.x >> 6;
    int lane = threadIdx.x & 63;
    const float* w1 = wave ? w1o : w1a;
    const float* b1 = wave ? b1o : b1a;
    const float* w2 = wave ? w2o : w2a;
    const float* b2 = wave ? b2o : b2a;
    float acc = b1[lane];
    for (int c = 0; c < 128; c++)
        acc += xg[g * 128 + c] * w1[c * 64 + lane];
    acc = fmaxf(acc, 0.f);
    float contrib = wred_sum(acc * w2[lane]);
    if (lane == 0) {
        float r = contrib + b2[0];
        if (flags[0]) ((float*)out)[wave * NG + g] = r;
        else          ((bf16*)out)[wave * NG + g] = __float2bfloat16(r);
    }
}

extern "C" void kernel_launch(void* const* d_in, const int* in_sizes, int n_in,
                              void* d_out, int out_size, void* d_ws, size_t ws_size,
                              hipStream_t stream) {
    static const int fidx[32] = {0,1, 4,5,6,7,8,9, 10,11,12,13, 14,15,16,17,
                                 18,19,20,21, 22,23,24,25, 26,27,28,29, 30,31,32,33};
    static const int flen[32] = {200000, 3200000, 128, 32, 2048, 32, 4096, 64,
                                 8192, 128, 128, 128, 16384, 128, 128, 128,
                                 16384, 128, 128, 128, 384, 384, 384, 384,
                                 8192, 64, 64, 1, 8192, 64, 64, 1};
    PrepArgs pa;
    int O[32];
    int tot = 0, blk = 0;
    for (int i = 0; i < 32; i++) {
        bool skip = (i == 1) || (i == 4) || (i == 6) || (i == 8) || (i == 12) || (i == 16);
        int cl = skip ? 0 : flen[i];
        pa.src[i] = d_in[fidx[i]];
        pa.len[i] = cl;
        O[i] = tot;
        pa.dst_off[i] = tot;
        pa.blk_base[i] = blk;
        tot += (flen[i] + 63) & ~63;
        blk += (cl + 1023) / 1024;
    }
    pa.blk_base[32] = blk;
    pa.cvtBlks = blk;
    pa.wtBlks = 184;
    pa.wfBlks = NNP * 64 / 8 / 256;          // 1564
    pa.intBlks = (825000 + 255) / 256;       // 3224
    pa.w0 = d_in[10]; pa.w1 = d_in[14]; pa.w2 = d_in[18];
    pa.ww = d_in[6];  pa.wc = d_in[8];
    pa.wf_src = d_in[1];
    pa.ei_src = d_in[2];
    pa.bat_src = d_in[3];
    int prepGrid = pa.cvtBlks + pa.wtBlks + pa.wfBlks + pa.intBlks;

    char* w = (char*)d_ws;
    auto alloc = [&](size_t bytes) -> char* {
        char* p = w;
        w += (bytes + 255) & ~(size_t)255;
        return p;
    };
    int*   flags  = (int*)alloc(256);
    float* cf     = (float*)alloc((size_t)tot * 4);
    int*   ei32   = (int*)alloc((size_t)2 * NE * 4);
    int*   bat32  = (int*)alloc((size_t)NN * 4);
    short* wfhi   = (short*)alloc((size_t)NNP * 64 * 2);
    short* wflo   = (short*)alloc((size_t)NNP * 64 * 2);
    short* x0     = (short*)alloc((size_t)NNP * 64 * 2);
    short* xA     = (short*)alloc((size_t)NNP * 128 * 2);
    short* xB     = (short*)alloc((size_t)NNP * 128 * 2);
    short* h      = (short*)alloc((size_t)NNP * 128 * 2);
    float* sA     = (float*)alloc((size_t)NN * 2 * 4);
    float* dA     = (float*)alloc((size_t)NN * 2 * 4);
    int*   off    = (int*)alloc((size_t)(NN + 1) * 4);
    int*   csr    = (int*)alloc((size_t)ET * 4);
    int*   gbh    = (int*)alloc((size_t)NB * 4);
    int*   gbo    = (int*)alloc((size_t)(NB + 1) * 4);
    int*   bcur   = (int*)alloc((size_t)NB * 4);
    uint2* bkt    = (uint2*)alloc((size_t)ET * 8);
    int*   starts = (int*)alloc((size_t)(NG + 1) * 4);
    float* xg     = (float*)alloc((size_t)NG * 128 * 4);
    short* wtall  = (short*)alloc((size_t)40960 * 2);
    short* wavewT = (short*)alloc((size_t)2048 * 2);
    short* combwT = (short*)alloc((size_t)4096 * 2);
    short* wt0 = wtall, *wt1 = wtall + 8192, *wt2 = wtall + 24576;

    detect_kernel<<<1, 256, 0, stream>>>((const unsigned int*)d_in[0],
                                         (const unsigned int*)d_in[2], flags, gbh);
    prep_kernel<<<prepGrid, 256, 0, stream>>>(pa, cf, wtall, wavewT, combwT,
                                              wfhi, wflo, ei32, bat32, flags);
    encode_mfma_kernel<<<NNP / 64, 256, 0, stream>>>(cf + O[0], cf + O[2], cf + O[3],
                                                     wfhi, wflo, wavewT, cf + O[5],
                                                     combwT, cf + O[7], x0, flags);
    bucket_hist_kernel<<<NEB, 256, 0, stream>>>(ei32, gbh);
    scan_bounds_kernel<<<2, 512, 0, stream>>>(gbh, gbo, bcur, bat32, starts);
    bucket_scatter_kernel<<<NEB, 256, 0, stream>>>(ei32, bcur, bkt);
    bucket_finalize_kernel<<<NB, 256, 0, stream>>>(bkt, gbo, off, csr);

    int gblk = NNP / 64;
    // layer 0
    gemm_mfma_kernel<<<gblk, 256, 0, stream>>>(x0, wt0, cf + O[9], cf + O[10],
                                               h, sA, dA, 64, NN);
    gat_aggregate_kernel<<<NN / 4, 256, 0, stream>>>(
        (const unsigned*)h, sA, dA, off, csr, cf + O[11],
        cf + O[20], cf + O[21], cf + O[22], cf + O[23],
        nullptr, (unsigned*)xA, NN);
    // layer 1
    gemm_mfma_kernel<<<gblk, 256, 0, stream>>>(xA, wt1, cf + O[13], cf + O[14],
                                               h, sA, dA, 128, NN);
    gat_aggregate_kernel<<<NN / 4, 256, 0, stream>>>(
        (const unsigned*)h, sA, dA, off, csr, cf + O[15],
        cf + O[20] + 128, cf + O[21] + 128, cf + O[22] + 128, cf + O[23] + 128,
        (const unsigned*)xA, (unsigned*)xB, NN);
    // layer 2
    gemm_mfma_kernel<<<gblk, 256, 0, stream>>>(xB, wt2, cf + O[17], cf + O[18],
                                               h, sA, dA, 128, NN);
    gat_aggregate_kernel<<<NN / 4, 256, 0, stream>>>(
        (const unsigned*)h, sA, dA, off, csr, cf + O[19],
        cf + O[20] + 256, cf + O[21] + 256, cf + O[22] + 256, cf + O[23] + 256,
        (const unsigned*)xB, (unsigned*)xA, NN);

    pool_kernel<<<NG, 256, 0, stream>>>((const unsigned*)xA, starts, xg);
    head_kernel<<<NG, 128, 0, stream>>>(xg,
                                        cf + O[24], cf + O[25], cf + O[26], cf + O[27],
                                        cf + O[28], cf + O[29], cf + O[30], cf + O[31],
                                        flags, d_out);
}

// Round 7
// 410.140 us; speedup vs baseline: 2.2803x; 1.0316x over previous
//
#include <hip/hip_runtime.h>
#include <hip/hip_bf16.h>
#include <stdint.h>

#define NN 50000
#define NNP 50048   // padded to 64-node gemm tiles
#define NE 800000
#define ET 850000   // NE + NN self loops
#define NG 256
#define CAP 128     // per-node edge capacity for LDS alpha cache (padded deg <= 128)
#define NB 392      // buckets of 128 dst nodes
#define EB 4096     // edges per block in bucket hist/scatter
#define NEB ((ET + EB - 1) / EB)   // 208

typedef __hip_bfloat16 bf16;
typedef __attribute__((ext_vector_type(8))) short short8;
typedef __attribute__((ext_vector_type(4))) float floatx4;

__device__ __forceinline__ float b2f(bf16 v) { return __bfloat162float(v); }
__device__ __forceinline__ float lrelu(float x) { return x > 0.f ? x : 0.2f * x; }
__device__ __forceinline__ short f2b(float f) {          // RNE bf16 round
    unsigned u = __float_as_uint(f);
    unsigned r = (u + 0x7FFFu + ((u >> 16) & 1u)) >> 16;
    return (short)r;
}
__device__ __forceinline__ float sh2f(short s) { return __uint_as_float(((unsigned)(unsigned short)s) << 16); }
__device__ __forceinline__ float blo(unsigned u) { return __uint_as_float(u << 16); }
__device__ __forceinline__ float bhi(unsigned u) { return __uint_as_float(u & 0xFFFF0000u); }
__device__ __forceinline__ unsigned pck(float a, float b) {
    return ((unsigned)(unsigned short)f2b(a)) | (((unsigned)(unsigned short)f2b(b)) << 16);
}

__device__ __forceinline__ float wred_sum(float v) {
    for (int o = 32; o > 0; o >>= 1) v += __shfl_xor(v, o, 64);
    return v;
}
__device__ __forceinline__ float wred_max(float v) {
    for (int o = 32; o > 0; o >>= 1) v = fmaxf(v, __shfl_xor(v, o, 64));
    return v;
}

// raw int load honoring dtype flag
__device__ __forceinline__ int ld_int(const void* p, int i, bool i64) {
    return i64 ? (int)((const long long*)p)[i] : ((const int*)p)[i];
}

// ---------------- dtype detection + gbh zero ----------------
__global__ void detect_kernel(const unsigned int* __restrict__ meta_words,
                              const unsigned int* __restrict__ ei_words,
                              int* __restrict__ flags, int* __restrict__ gbh) {
    __shared__ int insane, odd_nonzero;
    for (int k = threadIdx.x; k < NB; k += 256) gbh[k] = 0;
    if (threadIdx.x == 0) { insane = 0; odd_nonzero = 0; }
    __syncthreads();
    int cnt = 0;
    for (int k = 0; k < 8; k++) {
        unsigned int w = meta_words[threadIdx.x * 8 + k];
        int elo = (int)(((w & 0xFFFFu) >> 7) & 0xFF);
        int ehi = (int)(((w >> 16) >> 7) & 0xFF);
        if (elo >= 0x8D) cnt++;
        if (ehi >= 0x8D) cnt++;
    }
    if (cnt) atomicAdd(&insane, cnt);
    if (ei_words[threadIdx.x * 2 + 1] != 0u) atomicAdd(&odd_nonzero, 1);
    __syncthreads();
    if (threadIdx.x == 0) {
        flags[0] = (insane >= 4) ? 1 : 0;       // fp32 floats
        flags[1] = (odd_nonzero == 0) ? 1 : 0;  // int64 ints
    }
}

// ---------------- mega prep: cvt_float | weight-T | wavef prep ----------------
struct PrepArgs {
    const void* src[32];
    int len[32];
    int dst_off[32];
    int blk_base[33];
    int cvtBlks, wtBlks, wfBlks;
    const void* w0; const void* w1; const void* w2;
    const void* ww; const void* wc;
    const void* wf_src;
};

__global__ void prep_kernel(PrepArgs a, float* __restrict__ cf,
                            short* __restrict__ wtall, short* __restrict__ wavewT,
                            short* __restrict__ combwT,
                            short* __restrict__ wfhi, short* __restrict__ wflo,
                            const int* __restrict__ flags) {
    int b = blockIdx.x;
    bool fp32f = flags[0] != 0;
    if (b < a.cvtBlks) {
        int ai = 0;
        while (b >= a.blk_base[ai + 1]) ai++;
        int base = (b - a.blk_base[ai]) * 1024 + threadIdx.x;
        const float* sf = (const float*)a.src[ai];
        const bf16* sh = (const bf16*)a.src[ai];
        float* d = cf + a.dst_off[ai];
        int len = a.len[ai];
        #pragma unroll
        for (int u = 0; u < 4; u++) {
            int i = base + u * 256;
            if (i < len) d[i] = fp32f ? sf[i] : b2f(sh[i]);
        }
        return;
    }
    b -= a.cvtBlks;
    if (b < a.wtBlks) {
        int idx = b * 256 + threadIdx.x;
        const void* src; short* dst; int K, N, loc;
        if (idx < 8192)        { src = a.w0; dst = wtall;          K = 64;  N = 128; loc = idx; }
        else if (idx < 24576)  { src = a.w1; dst = wtall + 8192;   K = 128; N = 128; loc = idx - 8192; }
        else if (idx < 40960)  { src = a.w2; dst = wtall + 24576;  K = 128; N = 128; loc = idx - 24576; }
        else if (idx < 43008)  { src = a.ww; dst = wavewT;         K = 64;  N = 32;  loc = idx - 40960; }
        else if (idx < 47104)  { src = a.wc; dst = combwT;         K = 64;  N = 64;  loc = idx - 43008; }
        else return;
        int nch = loc / K, k = loc % K;
        int si = k * N + nch;
        dst[loc] = fp32f ? f2b(((const float*)src)[si]) : ((const short*)src)[si];
        return;
    }
    b -= a.wtBlks;
    int idx = b * 256 + threadIdx.x;
    int i8 = idx * 8;
    if (i8 >= NNP * 64) return;
    short8 h = {0, 0, 0, 0, 0, 0, 0, 0};
    if (fp32f) {
        short8 l = {0, 0, 0, 0, 0, 0, 0, 0};
        if (i8 < NN * 64) {
            const float* sf = (const float*)a.wf_src + i8;
            #pragma unroll
            for (int k = 0; k < 8; k++) {
                float v = sf[k];
                short hh = f2b(v);
                h[k] = hh;
                l[k] = f2b(v - sh2f(hh));
            }
        }
        *(short8*)(wfhi + i8) = h;
        *(short8*)(wflo + i8) = l;
    } else {
        if (i8 < NN * 64) h = *(const short8*)((const short*)a.wf_src + i8);
        *(short8*)(wfhi + i8) = h;
    }
}

// ---------------- MFMA encoder -> x0 bf16 [NNP][64] ----------------
__global__ __launch_bounds__(256) void encode_mfma_kernel(
        const float* __restrict__ meta, const float* __restrict__ meta_w,
        const float* __restrict__ meta_b,
        const short* __restrict__ wfhi, const short* __restrict__ wflo,
        const short* __restrict__ wavewT, const float* __restrict__ wave_b,
        const short* __restrict__ combwT, const float* __restrict__ comb_b,
        short* __restrict__ xout, const int* __restrict__ flags) {
    __shared__ short xc_hi[64][72];
    __shared__ short xc_lo[64][72];
    int t = threadIdx.x;
    int wave = t >> 6, lane = t & 63;
    int m16 = lane & 15, quad = lane >> 4;
    int nblk = blockIdx.x * 64;
    bool fp32f = flags[0] != 0;

    #pragma unroll
    for (int u = 0; u < 8; u++) {
        int idx = u * 256 + t;
        int node_l = idx >> 5, ch = idx & 31;
        int node = nblk + node_l;
        float acc = meta_b[ch];
        if (node < NN) {
            #pragma unroll
            for (int k = 0; k < 4; k++)
                acc += meta[node * 4 + k] * meta_w[k * 32 + ch];
        }
        float v = fmaxf(acc, 0.f);
        short hh = f2b(v);
        xc_hi[node_l][ch] = hh;
        xc_lo[node_l][ch] = f2b(v - sh2f(hh));
    }

    int row0 = nblk + wave * 16;
    const short* pah = wfhi + (size_t)(row0 + m16) * 64 + quad * 8;
    const short* pal = wflo + (size_t)(row0 + m16) * 64 + quad * 8;
    floatx4 wacc[2];
    wacc[0] = (floatx4)(0.f); wacc[1] = (floatx4)(0.f);
    #pragma unroll
    for (int ks = 0; ks < 64; ks += 32) {
        short8 ah = *(const short8*)(pah + ks);
        #pragma unroll
        for (int c = 0; c < 2; c++) {
            short8 b = *(const short8*)(wavewT + (c * 16 + m16) * 64 + ks + quad * 8);
            wacc[c] = __builtin_amdgcn_mfma_f32_16x16x32_bf16(ah, b, wacc[c], 0, 0, 0);
        }
        if (fp32f) {
            short8 al = *(const short8*)(pal + ks);
            #pragma unroll
            for (int c = 0; c < 2; c++) {
                short8 b = *(const short8*)(wavewT + (c * 16 + m16) * 64 + ks + quad * 8);
                wacc[c] = __builtin_amdgcn_mfma_f32_16x16x32_bf16(al, b, wacc[c], 0, 0, 0);
            }
        }
    }
    #pragma unroll
    for (int c = 0; c < 2; c++) {
        float bb = wave_b[c * 16 + m16];
        #pragma unroll
        for (int r = 0; r < 4; r++) {
            int node_l = wave * 16 + quad * 4 + r;
            int ch = 32 + c * 16 + m16;
            float v = fmaxf(wacc[c][r] + bb, 0.f);
            short hh = f2b(v);
            xc_hi[node_l][ch] = hh;
            xc_lo[node_l][ch] = f2b(v - sh2f(hh));
        }
    }
    __syncthreads();

    floatx4 acc2[4];
    #pragma unroll
    for (int c = 0; c < 4; c++) acc2[c] = (floatx4)(0.f);
    #pragma unroll
    for (int ks = 0; ks < 64; ks += 32) {
        short8 ah = *(const short8*)&xc_hi[wave * 16 + m16][ks + quad * 8];
        short8 al = *(const short8*)&xc_lo[wave * 16 + m16][ks + quad * 8];
        #pragma unroll
        for (int c = 0; c < 4; c++) {
            short8 b = *(const short8*)(combwT + (c * 16 + m16) * 64 + ks + quad * 8);
            acc2[c] = __builtin_amdgcn_mfma_f32_16x16x32_bf16(ah, b, acc2[c], 0, 0, 0);
            acc2[c] = __builtin_amdgcn_mfma_f32_16x16x32_bf16(al, b, acc2[c], 0, 0, 0);
        }
    }
    #pragma unroll
    for (int c = 0; c < 4; c++) {
        int ch = c * 16 + m16;
        float bb = comb_b[ch];
        #pragma unroll
        for (int r = 0; r < 4; r++) {
            int node = nblk + wave * 16 + quad * 4 + r;
            float v = fmaxf(acc2[c][r] + bb, 0.f);
            xout[(size_t)node * 64 + ch] = f2b(v);
        }
    }
}

// ---------------- CSR build: 2-level bucket sort on RAW edge_index ----------------
__global__ void bucket_hist_kernel(const void* __restrict__ ei, const int* __restrict__ flags,
                                   int* __restrict__ gbh) {
    __shared__ int lh[NB];
    int t = threadIdx.x;
    bool i64 = flags[1] != 0;
    for (int k = t; k < NB; k += 256) lh[k] = 0;
    __syncthreads();
    int base = blockIdx.x * EB;
    #pragma unroll 4
    for (int u = 0; u < EB / 256; u++) {
        int i = base + u * 256 + t;
        if (i < ET) {
            int dst = (i < NE) ? ld_int(ei, NE + i, i64) : (i - NE);
            atomicAdd(&lh[dst >> 7], 1);
        }
    }
    __syncthreads();
    for (int k = t; k < NB; k += 256)
        if (lh[k]) atomicAdd(&gbh[k], lh[k]);
}

__global__ void scan_bounds_kernel(const int* __restrict__ gbh, int* __restrict__ gbo,
                                   int* __restrict__ bcur,
                                   const void* __restrict__ batch, int* __restrict__ starts,
                                   const int* __restrict__ flags) {
    if (blockIdx.x == 0) {
        __shared__ int buf[512];
        int t = threadIdx.x;
        int v = (t < NB) ? gbh[t] : 0;
        buf[t] = v;
        __syncthreads();
        for (int o = 1; o < 512; o <<= 1) {
            int x = (t >= o) ? buf[t - o] : 0;
            __syncthreads();
            buf[t] += x;
            __syncthreads();
        }
        if (t < NB) { int e = buf[t] - v; gbo[t] = e; bcur[t] = e; }
        if (t == 0) gbo[NB] = ET;
    } else {
        int g = threadIdx.x;
        bool i64 = flags[1] != 0;
        if (g <= NG) {
            int lo = 0, hi = NN;
            while (lo < hi) {
                int mid = (lo + hi) >> 1;
                if (ld_int(batch, mid, i64) < g) lo = mid + 1; else hi = mid;
            }
            starts[g] = lo;
        }
    }
}

__global__ void bucket_scatter_kernel(const void* __restrict__ ei, const int* __restrict__ flags,
                                      int* __restrict__ bcur, uint2* __restrict__ bkt) {
    __shared__ int lh[NB];
    __shared__ int lbase[NB];
    int t = threadIdx.x;
    bool i64 = flags[1] != 0;
    for (int k = t; k < NB; k += 256) lh[k] = 0;
    __syncthreads();
    int base = blockIdx.x * EB;
    #pragma unroll 4
    for (int u = 0; u < EB / 256; u++) {
        int i = base + u * 256 + t;
        if (i < ET) {
            int dst = (i < NE) ? ld_int(ei, NE + i, i64) : (i - NE);
            atomicAdd(&lh[dst >> 7], 1);
        }
    }
    __syncthreads();
    for (int k = t; k < NB; k += 256) {
        int c = lh[k];
        lbase[k] = c ? atomicAdd(&bcur[k], c) : 0;
        lh[k] = 0;
    }
    __syncthreads();
    #pragma unroll 4
    for (int u = 0; u < EB / 256; u++) {
        int i = base + u * 256 + t;
        if (i < ET) {
            int src, dst;
            if (i < NE) { src = ld_int(ei, i, i64); dst = ld_int(ei, NE + i, i64); }
            else        { src = i - NE; dst = i - NE; }
            int b = dst >> 7;
            int pos = lbase[b] + atomicAdd(&lh[b], 1);
            bkt[pos] = make_uint2((unsigned)src, (unsigned)dst);
        }
    }
}

__global__ void bucket_finalize_kernel(const uint2* __restrict__ bkt,
                                       const int* __restrict__ gbo,
                                       int* __restrict__ off, int* __restrict__ csr) {
    __shared__ int hist[128];
    __shared__ int cur[128];
    int b = blockIdx.x;
    int t = threadIdx.x;
    int e0 = gbo[b], e1 = gbo[b + 1];
    if (t < 128) hist[t] = 0;
    __syncthreads();
    for (int i = e0 + t; i < e1; i += 256)
        atomicAdd(&hist[bkt[i].y & 127], 1);
    __syncthreads();
    int v = (t < 128) ? hist[t] : 0;
    if (t < 128) cur[t] = v;
    __syncthreads();
    for (int o = 1; o < 128; o <<= 1) {
        int x = (t < 128 && t >= o) ? cur[t - o] : 0;
        __syncthreads();
        if (t < 128) cur[t] += x;
        __syncthreads();
    }
    if (t < 128) {
        int ex = e0 + cur[t] - v;
        int node = b * 128 + t;
        if (node <= NN) off[node] = ex;
        cur[t] = ex;
    }
    __syncthreads();
    for (int i = e0 + t; i < e1; i += 256) {
        uint2 e = bkt[i];
        int pos = atomicAdd(&cur[e.y & 127], 1);
        csr[pos] = (int)e.x;
    }
}

// ---------------- MFMA GEMM + fused s/d logits (bf16 x) ----------------
__global__ __launch_bounds__(256) void gemm_mfma_kernel(
        const short* __restrict__ x, const short* __restrict__ wt,
        const float* __restrict__ a_s, const float* __restrict__ a_d,
        short* __restrict__ h, float* __restrict__ s, float* __restrict__ d,
        int K, int n) {
    int wave = threadIdx.x >> 6;
    int lane = threadIdx.x & 63;
    int row0 = (blockIdx.x * 4 + wave) * 16;
    int m16 = lane & 15;
    int quad = lane >> 4;
    int kq = quad * 8;

    const short* pa = x + (size_t)(row0 + m16) * K + kq;

    floatx4 acc[8];
    #pragma unroll
    for (int c = 0; c < 8; c++) acc[c] = (floatx4)(0.f);

    for (int ks = 0; ks < K; ks += 32) {
        short8 av = *(const short8*)(pa + ks);
        #pragma unroll
        for (int c = 0; c < 8; c++) {
            short8 b = *(const short8*)(wt + (size_t)(c * 16 + m16) * K + ks + kq);
            acc[c] = __builtin_amdgcn_mfma_f32_16x16x32_bf16(av, b, acc[c], 0, 0, 0);
        }
    }

    #pragma unroll
    for (int c = 0; c < 8; c++) {
        #pragma unroll
        for (int r = 0; r < 4; r++) {
            int node = row0 + quad * 4 + r;
            if (node < n) h[(size_t)node * 128 + c * 16 + m16] = f2b(acc[c][r]);
        }
    }

    float sp[2][4] = {{0, 0, 0, 0}, {0, 0, 0, 0}};
    float dp[2][4] = {{0, 0, 0, 0}, {0, 0, 0, 0}};
    #pragma unroll
    for (int c = 0; c < 8; c++) {
        float as_ = a_s[c * 16 + m16];
        float ad_ = a_d[c * 16 + m16];
        int hh = c >> 2;
        #pragma unroll
        for (int r = 0; r < 4; r++) {
            sp[hh][r] += acc[c][r] * as_;
            dp[hh][r] += acc[c][r] * ad_;
        }
    }
    #pragma unroll
    for (int o = 1; o < 16; o <<= 1) {
        #pragma unroll
        for (int hh = 0; hh < 2; hh++)
            #pragma unroll
            for (int r = 0; r < 4; r++) {
                sp[hh][r] += __shfl_xor(sp[hh][r], o, 64);
                dp[hh][r] += __shfl_xor(dp[hh][r], o, 64);
            }
    }
    if (m16 == 0) {
        #pragma unroll
        for (int r = 0; r < 4; r++) {
            int node = row0 + quad * 4 + r;
            if (node < n) {
                s[node * 2 + 0] = sp[0][r];
                s[node * 2 + 1] = sp[1][r];
                d[node * 2 + 0] = dp[0][r];
                d[node * 2 + 1] = dp[1][r];
            }
        }
    }
}

// ---------------- edge softmax + aggregation + bias + BN + res + relu ----------------
__global__ __launch_bounds__(256) void gat_aggregate_kernel(
        const unsigned* __restrict__ hp, const float* __restrict__ sv,
        const float* __restrict__ dv, const int* __restrict__ off,
        const int* __restrict__ csr, const float* __restrict__ bias,
        const float* __restrict__ bn_g, const float* __restrict__ bn_b,
        const float* __restrict__ bn_m, const float* __restrict__ bn_v,
        const unsigned* __restrict__ res, unsigned* __restrict__ out, int n) {
    __shared__ float4 er[4][CAP];     // (src bits, ex0, ex1, unused)
    int w = threadIdx.x >> 6;
    int lane = threadIdx.x & 63;
    int node = blockIdx.x * 4 + w;
    bool ok = node < n;
    int begin = 0, end = 0, deg = 0;
    float d0 = 0.f, d1 = 0.f;
    if (ok) {
        begin = off[node]; end = off[node + 1]; deg = end - begin;
        d0 = dv[node * 2 + 0]; d1 = dv[node * 2 + 1];
    }
    bool fits = deg <= CAP;
    int degp = (deg + 15) & ~15;      // <= 128 since deg <= 128
    float inv0 = 0.f, inv1 = 0.f;

    if (ok && fits) {
        int i0 = begin + lane, i1 = begin + 64 + lane;
        int sa = (i0 < end) ? csr[i0] : -1;
        int sb = (i1 < end) ? csr[i1] : -1;
        float e0a = -3e38f, e1a = -3e38f, e0b = -3e38f, e1b = -3e38f;
        if (sa >= 0) {
            float2 sp = *(const float2*)(sv + sa * 2);
            e0a = lrelu(sp.x + d0); e1a = lrelu(sp.y + d1);
        }
        if (sb >= 0) {
            float2 sp = *(const float2*)(sv + sb * 2);
            e0b = lrelu(sp.x + d0); e1b = lrelu(sp.y + d1);
        }
        float m0 = wred_max(fmaxf(e0a, e0b));
        float m1 = wred_max(fmaxf(e1a, e1b));
        float x0a = 0.f, x1a = 0.f, x0b = 0.f, x1b = 0.f;
        if (sa >= 0) {
            x0a = __expf(e0a - m0); x1a = __expf(e1a - m1);
            er[w][lane] = make_float4(__int_as_float(sa), x0a, x1a, 0.f);
        }
        if (sb >= 0) {
            x0b = __expf(e0b - m0); x1b = __expf(e1b - m1);
            er[w][lane + 64] = make_float4(__int_as_float(sb), x0b, x1b, 0.f);
        }
        // zero-pad to degp (src=0, alpha=0 -> no contribution)
        if (lane < degp - deg)
            er[w][deg + lane] = make_float4(__int_as_float(0), 0.f, 0.f, 0.f);
        float z0 = wred_sum(x0a + x0b);
        float z1 = wred_sum(x1a + x1b);
        inv0 = 1.f / (z0 + 1e-16f);
        inv1 = 1.f / (z1 + 1e-16f);
    }
    __syncthreads();
    if (!ok) return;

    if (fits) {
        int ll = lane & 15;        // channel group: ch 8*ll .. 8*ll+7
        int grp = lane >> 4;       // which 4-edge slice of each 16
        int hsel = (ll >= 8) ? 1 : 0;
        const uint4* hp4 = (const uint4*)hp;
        float a0 = 0, a1 = 0, a2 = 0, a3 = 0, a4 = 0, a5 = 0, a6 = 0, a7 = 0;
        for (int i = 0; i < degp; i += 16) {
            int e = i + grp * 4;
            float4 r0 = er[w][e], r1 = er[w][e + 1], r2 = er[w][e + 2], r3 = er[w][e + 3];
            uint4 u0 = hp4[(size_t)__float_as_int(r0.x) * 16 + ll];
            uint4 u1 = hp4[(size_t)__float_as_int(r1.x) * 16 + ll];
            uint4 u2 = hp4[(size_t)__float_as_int(r2.x) * 16 + ll];
            uint4 u3 = hp4[(size_t)__float_as_int(r3.x) * 16 + ll];
            float al0 = hsel ? r0.z : r0.y;
            float al1 = hsel ? r1.z : r1.y;
            float al2 = hsel ? r2.z : r2.y;
            float al3 = hsel ? r3.z : r3.y;
            a0 += al0 * blo(u0.x) + al1 * blo(u1.x) + al2 * blo(u2.x) + al3 * blo(u3.x);
            a1 += al0 * bhi(u0.x) + al1 * bhi(u1.x) + al2 * bhi(u2.x) + al3 * bhi(u3.x);
            a2 += al0 * blo(u0.y) + al1 * blo(u1.y) + al2 * blo(u2.y) + al3 * blo(u3.y);
            a3 += al0 * bhi(u0.y) + al1 * bhi(u1.y) + al2 * bhi(u2.y) + al3 * bhi(u3.y);
            a4 += al0 * blo(u0.z) + al1 * blo(u1.z) + al2 * blo(u2.z) + al3 * blo(u3.z);
            a5 += al0 * bhi(u0.z) + al1 * bhi(u1.z) + al2 * bhi(u2.z) + al3 * bhi(u3.z);
            a6 += al0 * blo(u0.w) + al1 * blo(u1.w) + al2 * blo(u2.w) + al3 * blo(u3.w);
            a7 += al0 * bhi(u0.w) + al1 * bhi(u1.w) + al2 * bhi(u2.w) + al3 * bhi(u3.w);
        }
        a0 += __shfl_xor(a0, 16, 64); a0 += __shfl_xor(a0, 32, 64);
        a1 += __shfl_xor(a1, 16, 64); a1 += __shfl_xor(a1, 32, 64);
        a2 += __shfl_xor(a2, 16, 64); a2 += __shfl_xor(a2, 32, 64);
        a3 += __shfl_xor(a3, 16, 64); a3 += __shfl_xor(a3, 32, 64);
        a4 += __shfl_xor(a4, 16, 64); a4 += __shfl_xor(a4, 32, 64);
        a5 += __shfl_xor(a5, 16, 64); a5 += __shfl_xor(a5, 32, 64);
        a6 += __shfl_xor(a6, 16, 64); a6 += __shfl_xor(a6, 32, 64);
        a7 += __shfl_xor(a7, 16, 64); a7 += __shfl_xor(a7, 32, 64);
        float inv = hsel ? inv1 : inv0;
        a0 *= inv; a1 *= inv; a2 *= inv; a3 *= inv;
        a4 *= inv; a5 *= inv; a6 *= inv; a7 *= inv;

        float4 bi0 = ((const float4*)bias)[2 * ll],  bi1 = ((const float4*)bias)[2 * ll + 1];
        float4 g0  = ((const float4*)bn_g)[2 * ll],  g1  = ((const float4*)bn_g)[2 * ll + 1];
        float4 be0 = ((const float4*)bn_b)[2 * ll],  be1 = ((const float4*)bn_b)[2 * ll + 1];
        float4 mu0 = ((const float4*)bn_m)[2 * ll],  mu1 = ((const float4*)bn_m)[2 * ll + 1];
        float4 va0 = ((const float4*)bn_v)[2 * ll],  va1 = ((const float4*)bn_v)[2 * ll + 1];
        float v0 = (a0 + bi0.x - mu0.x) * (g0.x * rsqrtf(va0.x + 1e-5f)) + be0.x;
        float v1 = (a1 + bi0.y - mu0.y) * (g0.y * rsqrtf(va0.y + 1e-5f)) + be0.y;
        float v2 = (a2 + bi0.z - mu0.z) * (g0.z * rsqrtf(va0.z + 1e-5f)) + be0.z;
        float v3 = (a3 + bi0.w - mu0.w) * (g0.w * rsqrtf(va0.w + 1e-5f)) + be0.w;
        float v4 = (a4 + bi1.x - mu1.x) * (g1.x * rsqrtf(va1.x + 1e-5f)) + be1.x;
        float v5 = (a5 + bi1.y - mu1.y) * (g1.y * rsqrtf(va1.y + 1e-5f)) + be1.y;
        float v6 = (a6 + bi1.z - mu1.z) * (g1.z * rsqrtf(va1.z + 1e-5f)) + be1.z;
        float v7 = (a7 + bi1.w - mu1.w) * (g1.w * rsqrtf(va1.w + 1e-5f)) + be1.w;
        if (res) {
            uint4 r = ((const uint4*)res)[(size_t)node * 16 + ll];
            v0 += blo(r.x); v1 += bhi(r.x); v2 += blo(r.y); v3 += bhi(r.y);
            v4 += blo(r.z); v5 += bhi(r.z); v6 += blo(r.w); v7 += bhi(r.w);
        }
        v0 = fmaxf(v0, 0.f); v1 = fmaxf(v1, 0.f); v2 = fmaxf(v2, 0.f); v3 = fmaxf(v3, 0.f);
        v4 = fmaxf(v4, 0.f); v5 = fmaxf(v5, 0.f); v6 = fmaxf(v6, 0.f); v7 = fmaxf(v7, 0.f);
        if (lane < 16) {
            ((uint4*)out)[(size_t)node * 16 + ll] =
                make_uint4(pck(v0, v1), pck(v2, v3), pck(v4, v5), pck(v6, v7));
        }
    } else {
        // fallback (deg > CAP): 3-pass, 2 channels/lane
        float mm0 = -3e38f, mm1 = -3e38f;
        for (int i = begin + lane; i < end; i += 64) {
            int sc = csr[i];
            float2 sp = *(const float2*)(sv + sc * 2);
            mm0 = fmaxf(mm0, lrelu(sp.x + d0));
            mm1 = fmaxf(mm1, lrelu(sp.y + d1));
        }
        mm0 = wred_max(mm0); mm1 = wred_max(mm1);
        float z0 = 0.f, z1 = 0.f;
        for (int i = begin + lane; i < end; i += 64) {
            int sc = csr[i];
            float2 sp = *(const float2*)(sv + sc * 2);
            z0 += __expf(lrelu(sp.x + d0) - mm0);
            z1 += __expf(lrelu(sp.y + d1) - mm1);
        }
        z0 = wred_sum(z0); z1 = wred_sum(z1);
        float i0_ = 1.f / (z0 + 1e-16f), i1_ = 1.f / (z1 + 1e-16f);
        bool head0 = lane < 32;
        float acc0 = 0.f, acc1 = 0.f;
        for (int i = begin; i < end; i++) {
            int sc = csr[i];
            float2 sp = *(const float2*)(sv + sc * 2);
            float a = head0 ? __expf(lrelu(sp.x + d0) - mm0) * i0_
                            : __expf(lrelu(sp.y + d1) - mm1) * i1_;
            unsigned u = hp[(size_t)sc * 64 + lane];
            acc0 += a * blo(u);
            acc1 += a * bhi(u);
        }
        int c0 = 2 * lane, c1 = c0 + 1;
        float v0 = acc0 + bias[c0];
        float v1 = acc1 + bias[c1];
        v0 = (v0 - bn_m[c0]) * (bn_g[c0] * rsqrtf(bn_v[c0] + 1e-5f)) + bn_b[c0];
        v1 = (v1 - bn_m[c1]) * (bn_g[c1] * rsqrtf(bn_v[c1] + 1e-5f)) + bn_b[c1];
        if (res) {
            unsigned r = res[(size_t)node * 64 + lane];
            v0 += blo(r);
            v1 += bhi(r);
        }
        v0 = fmaxf(v0, 0.f);
        v1 = fmaxf(v1, 0.f);
        out[(size_t)node * 64 + lane] = pck(v0, v1);
    }
}

// ---------------- global mean pool (x bf16 packed) ----------------
__global__ void pool_kernel(const unsigned* __restrict__ x,
                            const int* __restrict__ starts, float* __restrict__ xg) {
    __shared__ float part[4][128];
    int g = blockIdx.x;
    int wv = threadIdx.x >> 6, lane = threadIdx.x & 63;
    int s0 = starts[g], e0 = starts[g + 1];
    float a0 = 0.f, a1 = 0.f;
    for (int node = s0 + wv; node < e0; node += 4) {
        unsigned u = x[(size_t)node * 64 + lane];
        a0 += blo(u);
        a1 += bhi(u);
    }
    part[wv][lane * 2] = a0;
    part[wv][lane * 2 + 1] = a1;
    __syncthreads();
    if (wv == 0) {
        float t0 = part[0][lane * 2] + part[1][lane * 2] + part[2][lane * 2] + part[3][lane * 2];
        float t1 = part[0][lane * 2 + 1] + part[1][lane * 2 + 1] + part[2][lane * 2 + 1] + part[3][lane * 2 + 1];
        float icf = 1.f / fmaxf((float)(e0 - s0), 1.f);
        xg[g * 128 + 2 * lane] = t0 * icf;
        xg[g * 128 + 2 * lane + 1] = t1 * icf;
    }
}

// ---------------- lat/lon heads ----------------
__global__ void head_kernel(const float* __restrict__ xg,
                            const float* __restrict__ w1a, const float* __restrict__ b1a,
                            const float* __restrict__ w2a, const float* __restrict__ b2a,
                            const float* __restrict__ w1o, const float* __restrict__ b1o,
                            const float* __restrict__ w2o, const float* __restrict__ b2o,
                            const int* __restrict__ flags, void* __restrict__ out) {
    int g = blockIdx.x;
    int wave = threadIdx.x >> 6;
    int lane = threadIdx.x & 63;
    const float* w1 = wave ? w1o : w1a;
    const float* b1 = wave ? b1o : b1a;
    const float* w2 = wave ? w2o : w2a;
    const float* b2 = wave ? b2o : b2a;
    float acc = b1[lane];
    for (int c = 0; c < 128; c++)
        acc += xg[g * 128 + c] * w1[c * 64 + lane];
    acc = fmaxf(acc, 0.f);
    float contrib = wred_sum(acc * w2[lane]);
    if (lane == 0) {
        float r = contrib + b2[0];
        if (flags[0]) ((float*)out)[wave * NG + g] = r;
        else          ((bf16*)out)[wave * NG + g] = __float2bfloat16(r);
    }
}

extern "C" void kernel_launch(void* const* d_in, const int* in_sizes, int n_in,
                              void* d_out, int out_size, void* d_ws, size_t ws_size,
                              hipStream_t stream) {
    static const int fidx[32] = {0,1, 4,5,6,7,8,9, 10,11,12,13, 14,15,16,17,
                                 18,19,20,21, 22,23,24,25, 26,27,28,29, 30,31,32,33};
    static const int flen[32] = {200000, 3200000, 128, 32, 2048, 32, 4096, 64,
                                 8192, 128, 128, 128, 16384, 128, 128, 128,
                                 16384, 128, 128, 128, 384, 384, 384, 384,
                                 8192, 64, 64, 1, 8192, 64, 64, 1};
    PrepArgs pa;
    int O[32];
    int tot = 0, blk = 0;
    for (int i = 0; i < 32; i++) {
        bool skip = (i == 1) || (i == 4) || (i == 6) || (i == 8) || (i == 12) || (i == 16);
        int cl = skip ? 0 : flen[i];
        pa.src[i] = d_in[fidx[i]];
        pa.len[i] = cl;
        O[i] = tot;
        pa.dst_off[i] = tot;
        pa.blk_base[i] = blk;
        tot += (flen[i] + 63) & ~63;
        blk += (cl + 1023) / 1024;
    }
    pa.blk_base[32] = blk;
    pa.cvtBlks = blk;
    pa.wtBlks = 184;
    pa.wfBlks = NNP * 64 / 8 / 256;          // 1564
    pa.w0 = d_in[10]; pa.w1 = d_in[14]; pa.w2 = d_in[18];
    pa.ww = d_in[6];  pa.wc = d_in[8];
    pa.wf_src = d_in[1];
    int prepGrid = pa.cvtBlks + pa.wtBlks + pa.wfBlks;

    char* w = (char*)d_ws;
    auto alloc = [&](size_t bytes) -> char* {
        char* p = w;
        w += (bytes + 255) & ~(size_t)255;
        return p;
    };
    int*   flags  = (int*)alloc(256);
    float* cf     = (float*)alloc((size_t)tot * 4);
    short* wfhi   = (short*)alloc((size_t)NNP * 64 * 2);
    short* wflo   = (short*)alloc((size_t)NNP * 64 * 2);
    short* x0     = (short*)alloc((size_t)NNP * 64 * 2);
    short* xA     = (short*)alloc((size_t)NNP * 128 * 2);
    short* xB     = (short*)alloc((size_t)NNP * 128 * 2);
    short* h      = (short*)alloc((size_t)NNP * 128 * 2);
    float* sA     = (float*)alloc((size_t)NN * 2 * 4);
    float* dA     = (float*)alloc((size_t)NN * 2 * 4);
    int*   off    = (int*)alloc((size_t)(NN + 1) * 4);
    int*   csr    = (int*)alloc((size_t)ET * 4);
    int*   gbh    = (int*)alloc((size_t)NB * 4);
    int*   gbo    = (int*)alloc((size_t)(NB + 1) * 4);
    int*   bcur   = (int*)alloc((size_t)NB * 4);
    uint2* bkt    = (uint2*)alloc((size_t)ET * 8);
    int*   starts = (int*)alloc((size_t)(NG + 1) * 4);
    float* xg     = (float*)alloc((size_t)NG * 128 * 4);
    short* wtall  = (short*)alloc((size_t)40960 * 2);
    short* wavewT = (short*)alloc((size_t)2048 * 2);
    short* combwT = (short*)alloc((size_t)4096 * 2);
    short* wt0 = wtall, *wt1 = wtall + 8192, *wt2 = wtall + 24576;

    detect_kernel<<<1, 256, 0, stream>>>((const unsigned int*)d_in[0],
                                         (const unsigned int*)d_in[2], flags, gbh);
    prep_kernel<<<prepGrid, 256, 0, stream>>>(pa, cf, wtall, wavewT, combwT,
                                              wfhi, wflo, flags);
    encode_mfma_kernel<<<NNP / 64, 256, 0, stream>>>(cf + O[0], cf + O[2], cf + O[3],
                                                     wfhi, wflo, wavewT, cf + O[5],
                                                     combwT, cf + O[7], x0, flags);
    bucket_hist_kernel<<<NEB, 256, 0, stream>>>(d_in[2], flags, gbh);
    scan_bounds_kernel<<<2, 512, 0, stream>>>(gbh, gbo, bcur, d_in[3], starts, flags);
    bucket_scatter_kernel<<<NEB, 256, 0, stream>>>(d_in[2], flags, bcur, bkt);
    bucket_finalize_kernel<<<NB, 256, 0, stream>>>(bkt, gbo, off, csr);

    int gblk = NNP / 64;
    // layer 0
    gemm_mfma_kernel<<<gblk, 256, 0, stream>>>(x0, wt0, cf + O[9], cf + O[10],
                                               h, sA, dA, 64, NN);
    gat_aggregate_kernel<<<NN / 4, 256, 0, stream>>>(
        (const unsigned*)h, sA, dA, off, csr, cf + O[11],
        cf + O[20], cf + O[21], cf + O[22], cf + O[23],
        nullptr, (unsigned*)xA, NN);
    // layer 1
    gemm_mfma_kernel<<<gblk, 256, 0, stream>>>(xA, wt1, cf + O[13], cf + O[14],
                                               h, sA, dA, 128, NN);
    gat_aggregate_kernel<<<NN / 4, 256, 0, stream>>>(
        (const unsigned*)h, sA, dA, off, csr, cf + O[15],
        cf + O[20] + 128, cf + O[21] + 128, cf + O[22] + 128, cf + O[23] + 128,
        (const unsigned*)xA, (unsigned*)xB, NN);
    // layer 2
    gemm_mfma_kernel<<<gblk, 256, 0, stream>>>(xB, wt2, cf + O[17], cf + O[18],
                                               h, sA, dA, 128, NN);
    gat_aggregate_kernel<<<NN / 4, 256, 0, stream>>>(
        (const unsigned*)h, sA, dA, off, csr, cf + O[19],
        cf + O[20] + 256, cf + O[21] + 256, cf + O[22] + 256, cf + O[23] + 256,
        (const unsigned*)xB, (unsigned*)xA, NN);

    pool_kernel<<<NG, 256, 0, stream>>>((const unsigned*)xA, starts, xg);
    head_kernel<<<NG, 128, 0, stream>>>(xg,
                                        cf + O[24], cf + O[25], cf + O[26], cf + O[27],
                                        cf + O[28], cf + O[29], cf + O[30], cf + O[31],
                                        flags, d_out);
}

// Round 8
// 365.389 us; speedup vs baseline: 2.5596x; 1.1225x over previous
//
#include <hip/hip_runtime.h>
#include <hip/hip_bf16.h>
#include <stdint.h>

#define NN 50000
#define NNP 50048   // padded to 64-node gemm tiles
#define NE 800000
#define ET 850000   // NE + NN self loops
#define NG 256
#define CAP 128     // per-node edge capacity for LDS alpha cache
#define NB 392      // buckets of 128 dst nodes
#define BCAP 3072   // bucket capacity (mean 2176, sigma ~47)
#define EB 4096     // edges per block in bucket scatter
#define NEB ((ET + EB - 1) / EB)   // 208

typedef __hip_bfloat16 bf16;
typedef __attribute__((ext_vector_type(8))) short short8;
typedef __attribute__((ext_vector_type(4))) float floatx4;

__device__ __forceinline__ float b2f(bf16 v) { return __bfloat162float(v); }
__device__ __forceinline__ float lrelu(float x) { return x > 0.f ? x : 0.2f * x; }
__device__ __forceinline__ short f2b(float f) {          // RNE bf16 round
    unsigned u = __float_as_uint(f);
    unsigned r = (u + 0x7FFFu + ((u >> 16) & 1u)) >> 16;
    return (short)r;
}
__device__ __forceinline__ float sh2f(short s) { return __uint_as_float(((unsigned)(unsigned short)s) << 16); }
__device__ __forceinline__ float blo(unsigned u) { return __uint_as_float(u << 16); }
__device__ __forceinline__ float bhi(unsigned u) { return __uint_as_float(u & 0xFFFF0000u); }
__device__ __forceinline__ unsigned pck(float a, float b) {
    return ((unsigned)(unsigned short)f2b(a)) | (((unsigned)(unsigned short)f2b(b)) << 16);
}
__device__ __forceinline__ float wred_sum(float v) {
    for (int o = 32; o > 0; o >>= 1) v += __shfl_xor(v, o, 64);
    return v;
}
__device__ __forceinline__ int ld_int(const void* p, int i, bool i64) {
    return i64 ? (int)((const long long*)p)[i] : ((const int*)p)[i];
}
__device__ __forceinline__ float ldf(const void* p, int i, bool fp32) {
    return fp32 ? ((const float*)p)[i] : b2f(((const bf16*)p)[i]);
}

// ---------------- dtype detection + bcur zero ----------------
__global__ void detect_kernel(const unsigned int* __restrict__ meta_words,
                              const unsigned int* __restrict__ ei_words,
                              int* __restrict__ flags, int* __restrict__ bcur) {
    __shared__ int insane, odd_nonzero;
    for (int k = threadIdx.x; k < NB; k += 256) bcur[k] = 0;
    if (threadIdx.x == 0) { insane = 0; odd_nonzero = 0; }
    __syncthreads();
    int cnt = 0;
    for (int k = 0; k < 8; k++) {
        unsigned int w = meta_words[threadIdx.x * 8 + k];
        int elo = (int)(((w & 0xFFFFu) >> 7) & 0xFF);
        int ehi = (int)(((w >> 16) >> 7) & 0xFF);
        if (elo >= 0x8D) cnt++;
        if (ehi >= 0x8D) cnt++;
    }
    if (cnt) atomicAdd(&insane, cnt);
    if (ei_words[threadIdx.x * 2 + 1] != 0u) atomicAdd(&odd_nonzero, 1);
    __syncthreads();
    if (threadIdx.x == 0) {
        flags[0] = (insane >= 4) ? 1 : 0;       // fp32 floats
        flags[1] = (odd_nonzero == 0) ? 1 : 0;  // int64 ints
    }
}

// ---------------- mega prep: cvt_float | weight-T | wavef prep | BN fold ----------------
struct PrepArgs {
    const void* src[32];
    int len[32];
    int dst_off[32];
    int blk_base[33];
    int cvtBlks, wtBlks, wfBlks;
    const void* w0; const void* w1; const void* w2;
    const void* ww; const void* wc;
    const void* wf_src;
    const void* gb0; const void* gb1; const void* gb2;
    const void* bng; const void* bnb; const void* bnm; const void* bnv;
};

__global__ void prep_kernel(PrepArgs a, float* __restrict__ cf,
                            short* __restrict__ wtall, short* __restrict__ wavewT,
                            short* __restrict__ combwT,
                            short* __restrict__ wfhi, short* __restrict__ wflo,
                            float* __restrict__ bnscl, float* __restrict__ bnsft,
                            const int* __restrict__ flags) {
    int b = blockIdx.x;
    bool fp32f = flags[0] != 0;
    if (b < a.cvtBlks) {
        int ai = 0;
        while (b >= a.blk_base[ai + 1]) ai++;
        int base = (b - a.blk_base[ai]) * 1024 + threadIdx.x;
        const float* sf = (const float*)a.src[ai];
        const bf16* sh = (const bf16*)a.src[ai];
        float* d = cf + a.dst_off[ai];
        int len = a.len[ai];
        #pragma unroll
        for (int u = 0; u < 4; u++) {
            int i = base + u * 256;
            if (i < len) d[i] = fp32f ? sf[i] : b2f(sh[i]);
        }
        return;
    }
    b -= a.cvtBlks;
    if (b < a.wtBlks) {
        int idx = b * 256 + threadIdx.x;
        const void* src; short* dst; int K, N, loc;
        if (idx < 8192)        { src = a.w0; dst = wtall;          K = 64;  N = 128; loc = idx; }
        else if (idx < 24576)  { src = a.w1; dst = wtall + 8192;   K = 128; N = 128; loc = idx - 8192; }
        else if (idx < 40960)  { src = a.w2; dst = wtall + 24576;  K = 128; N = 128; loc = idx - 24576; }
        else if (idx < 43008)  { src = a.ww; dst = wavewT;         K = 64;  N = 32;  loc = idx - 40960; }
        else if (idx < 47104)  { src = a.wc; dst = combwT;         K = 64;  N = 64;  loc = idx - 43008; }
        else return;
        int nch = loc / K, k = loc % K;
        int si = k * N + nch;
        dst[loc] = fp32f ? f2b(((const float*)src)[si]) : ((const short*)src)[si];
        return;
    }
    b -= a.wtBlks;
    if (b < a.wfBlks) {
        int idx = b * 256 + threadIdx.x;
        int i8 = idx * 8;
        if (i8 >= NNP * 64) return;
        short8 h = {0, 0, 0, 0, 0, 0, 0, 0};
        if (fp32f) {
            short8 l = {0, 0, 0, 0, 0, 0, 0, 0};
            if (i8 < NN * 64) {
                const float* sf = (const float*)a.wf_src + i8;
                #pragma unroll
                for (int k = 0; k < 8; k++) {
                    float v = sf[k];
                    short hh = f2b(v);
                    h[k] = hh;
                    l[k] = f2b(v - sh2f(hh));
                }
            }
            *(short8*)(wfhi + i8) = h;
            *(short8*)(wflo + i8) = l;
        } else {
            if (i8 < NN * 64) h = *(const short8*)((const short*)a.wf_src + i8);
            *(short8*)(wfhi + i8) = h;
        }
        return;
    }
    // BN fold: scale = g*rsqrt(v+eps); shift = (bias-mean)*scale + beta
    b -= a.wfBlks;
    int idx = b * 256 + threadIdx.x;
    if (idx >= 384) return;
    int l = idx >> 7, c = idx & 127;
    const void* biasp = (l == 0) ? a.gb0 : (l == 1) ? a.gb1 : a.gb2;
    float bias = ldf(biasp, c, fp32f);
    float g  = ldf(a.bng, l * 128 + c, fp32f);
    float be = ldf(a.bnb, l * 128 + c, fp32f);
    float mu = ldf(a.bnm, l * 128 + c, fp32f);
    float va = ldf(a.bnv, l * 128 + c, fp32f);
    float sc = g * rsqrtf(va + 1e-5f);
    bnscl[l * 128 + c] = sc;
    bnsft[l * 128 + c] = (bias - mu) * sc + be;
}

// ---------------- MFMA encoder -> x0 bf16 [NNP][64] ----------------
__global__ __launch_bounds__(256) void encode_mfma_kernel(
        const float* __restrict__ meta, const float* __restrict__ meta_w,
        const float* __restrict__ meta_b,
        const short* __restrict__ wfhi, const short* __restrict__ wflo,
        const short* __restrict__ wavewT, const float* __restrict__ wave_b,
        const short* __restrict__ combwT, const float* __restrict__ comb_b,
        short* __restrict__ xout, const int* __restrict__ flags) {
    __shared__ short xc_hi[64][72];
    __shared__ short xc_lo[64][72];
    int t = threadIdx.x;
    int wave = t >> 6, lane = t & 63;
    int m16 = lane & 15, quad = lane >> 4;
    int nblk = blockIdx.x * 64;
    bool fp32f = flags[0] != 0;

    #pragma unroll
    for (int u = 0; u < 8; u++) {
        int idx = u * 256 + t;
        int node_l = idx >> 5, ch = idx & 31;
        int node = nblk + node_l;
        float acc = meta_b[ch];
        if (node < NN) {
            #pragma unroll
            for (int k = 0; k < 4; k++)
                acc += meta[node * 4 + k] * meta_w[k * 32 + ch];
        }
        float v = fmaxf(acc, 0.f);
        short hh = f2b(v);
        xc_hi[node_l][ch] = hh;
        xc_lo[node_l][ch] = f2b(v - sh2f(hh));
    }

    int row0 = nblk + wave * 16;
    const short* pah = wfhi + (size_t)(row0 + m16) * 64 + quad * 8;
    const short* pal = wflo + (size_t)(row0 + m16) * 64 + quad * 8;
    floatx4 wacc[2];
    wacc[0] = (floatx4)(0.f); wacc[1] = (floatx4)(0.f);
    #pragma unroll
    for (int ks = 0; ks < 64; ks += 32) {
        short8 ah = *(const short8*)(pah + ks);
        #pragma unroll
        for (int c = 0; c < 2; c++) {
            short8 b = *(const short8*)(wavewT + (c * 16 + m16) * 64 + ks + quad * 8);
            wacc[c] = __builtin_amdgcn_mfma_f32_16x16x32_bf16(ah, b, wacc[c], 0, 0, 0);
        }
        if (fp32f) {
            short8 al = *(const short8*)(pal + ks);
            #pragma unroll
            for (int c = 0; c < 2; c++) {
                short8 b = *(const short8*)(wavewT + (c * 16 + m16) * 64 + ks + quad * 8);
                wacc[c] = __builtin_amdgcn_mfma_f32_16x16x32_bf16(al, b, wacc[c], 0, 0, 0);
            }
        }
    }
    #pragma unroll
    for (int c = 0; c < 2; c++) {
        float bb = wave_b[c * 16 + m16];
        #pragma unroll
        for (int r = 0; r < 4; r++) {
            int node_l = wave * 16 + quad * 4 + r;
            int ch = 32 + c * 16 + m16;
            float v = fmaxf(wacc[c][r] + bb, 0.f);
            short hh = f2b(v);
            xc_hi[node_l][ch] = hh;
            xc_lo[node_l][ch] = f2b(v - sh2f(hh));
        }
    }
    __syncthreads();

    floatx4 acc2[4];
    #pragma unroll
    for (int c = 0; c < 4; c++) acc2[c] = (floatx4)(0.f);
    #pragma unroll
    for (int ks = 0; ks < 64; ks += 32) {
        short8 ah = *(const short8*)&xc_hi[wave * 16 + m16][ks + quad * 8];
        short8 al = *(const short8*)&xc_lo[wave * 16 + m16][ks + quad * 8];
        #pragma unroll
        for (int c = 0; c < 4; c++) {
            short8 b = *(const short8*)(combwT + (c * 16 + m16) * 64 + ks + quad * 8);
            acc2[c] = __builtin_amdgcn_mfma_f32_16x16x32_bf16(ah, b, acc2[c], 0, 0, 0);
            acc2[c] = __builtin_amdgcn_mfma_f32_16x16x32_bf16(al, b, acc2[c], 0, 0, 0);
        }
    }
    #pragma unroll
    for (int c = 0; c < 4; c++) {
        int ch = c * 16 + m16;
        float bb = comb_b[ch];
        #pragma unroll
        for (int r = 0; r < 4; r++) {
            int node = nblk + wave * 16 + quad * 4 + r;
            float v = fmaxf(acc2[c][r] + bb, 0.f);
            xout[(size_t)node * 64 + ch] = f2b(v);
        }
    }
}

// ---------------- CSR build: single-pass bucket scatter + finalize ----------------
__global__ void bucket_scatter_kernel(const void* __restrict__ ei, const int* __restrict__ flags,
                                      int* __restrict__ bcur, uint2* __restrict__ bkt) {
    __shared__ int lh[NB];
    __shared__ int lbase[NB];
    int t = threadIdx.x;
    bool i64 = flags[1] != 0;
    for (int k = t; k < NB; k += 256) lh[k] = 0;
    __syncthreads();
    int base = blockIdx.x * EB;
    #pragma unroll 4
    for (int u = 0; u < EB / 256; u++) {
        int i = base + u * 256 + t;
        if (i < ET) {
            int dst = (i < NE) ? ld_int(ei, NE + i, i64) : (i - NE);
            atomicAdd(&lh[dst >> 7], 1);
        }
    }
    __syncthreads();
    for (int k = t; k < NB; k += 256) {
        int c = lh[k];
        lbase[k] = c ? atomicAdd(&bcur[k], c) : 0;
        lh[k] = 0;
    }
    __syncthreads();
    #pragma unroll 4
    for (int u = 0; u < EB / 256; u++) {
        int i = base + u * 256 + t;
        if (i < ET) {
            int src, dst;
            if (i < NE) { src = ld_int(ei, i, i64); dst = ld_int(ei, NE + i, i64); }
            else        { src = i - NE; dst = i - NE; }
            int b = dst >> 7;
            int pos = lbase[b] + atomicAdd(&lh[b], 1);
            if (pos < BCAP) bkt[(size_t)b * BCAP + pos] = make_uint2((unsigned)src, (unsigned)dst);
        }
    }
}

__global__ void bucket_finalize_kernel(const uint2* __restrict__ bkt,
                                       const int* __restrict__ bcnt,
                                       int* __restrict__ offb, int* __restrict__ dega,
                                       int* __restrict__ csr) {
    __shared__ int hist[128];
    __shared__ int cur[128];
    int b = blockIdx.x;
    int t = threadIdx.x;
    int e0 = b * BCAP;
    int cnt = min(bcnt[b], BCAP);
    if (t < 128) hist[t] = 0;
    __syncthreads();
    for (int i = t; i < cnt; i += 256)
        atomicAdd(&hist[bkt[e0 + i].y & 127], 1);
    __syncthreads();
    int v = (t < 128) ? hist[t] : 0;
    if (t < 128) cur[t] = v;
    __syncthreads();
    for (int o = 1; o < 128; o <<= 1) {
        int x = (t < 128 && t >= o) ? cur[t - o] : 0;
        __syncthreads();
        if (t < 128) cur[t] += x;
        __syncthreads();
    }
    if (t < 128) {
        int ex = e0 + cur[t] - v;
        int node = b * 128 + t;
        if (node < NN) { offb[node] = ex; dega[node] = v; }
        cur[t] = ex;
    }
    __syncthreads();
    for (int i = t; i < cnt; i += 256) {
        uint2 e = bkt[e0 + i];
        int pos = atomicAdd(&cur[e.y & 127], 1);
        csr[pos] = (int)e.x;
    }
}

// ---------------- MFMA GEMM + fused s/d logits ----------------
__global__ __launch_bounds__(256) void gemm_mfma_kernel(
        const short* __restrict__ x, const short* __restrict__ wt,
        const float* __restrict__ a_s, const float* __restrict__ a_d,
        short* __restrict__ h, float* __restrict__ s, float* __restrict__ d,
        int K, int n) {
    int wave = threadIdx.x >> 6;
    int lane = threadIdx.x & 63;
    int row0 = (blockIdx.x * 4 + wave) * 16;
    int m16 = lane & 15;
    int quad = lane >> 4;
    int kq = quad * 8;

    const short* pa = x + (size_t)(row0 + m16) * K + kq;

    floatx4 acc[8];
    #pragma unroll
    for (int c = 0; c < 8; c++) acc[c] = (floatx4)(0.f);

    for (int ks = 0; ks < K; ks += 32) {
        short8 av = *(const short8*)(pa + ks);
        #pragma unroll
        for (int c = 0; c < 8; c++) {
            short8 b = *(const short8*)(wt + (size_t)(c * 16 + m16) * K + ks + kq);
            acc[c] = __builtin_amdgcn_mfma_f32_16x16x32_bf16(av, b, acc[c], 0, 0, 0);
        }
    }

    #pragma unroll
    for (int c = 0; c < 8; c++) {
        #pragma unroll
        for (int r = 0; r < 4; r++) {
            int node = row0 + quad * 4 + r;
            if (node < n) h[(size_t)node * 128 + c * 16 + m16] = f2b(acc[c][r]);
        }
    }

    float sp[2][4] = {{0, 0, 0, 0}, {0, 0, 0, 0}};
    float dp[2][4] = {{0, 0, 0, 0}, {0, 0, 0, 0}};
    #pragma unroll
    for (int c = 0; c < 8; c++) {
        float as_ = a_s[c * 16 + m16];
        float ad_ = a_d[c * 16 + m16];
        int hh = c >> 2;
        #pragma unroll
        for (int r = 0; r < 4; r++) {
            sp[hh][r] += acc[c][r] * as_;
            dp[hh][r] += acc[c][r] * ad_;
        }
    }
    #pragma unroll
    for (int o = 1; o < 16; o <<= 1) {
        #pragma unroll
        for (int hh = 0; hh < 2; hh++)
            #pragma unroll
            for (int r = 0; r < 4; r++) {
                sp[hh][r] += __shfl_xor(sp[hh][r], o, 64);
                dp[hh][r] += __shfl_xor(dp[hh][r], o, 64);
            }
    }
    if (m16 == 0) {
        #pragma unroll
        for (int r = 0; r < 4; r++) {
            int node = row0 + quad * 4 + r;
            if (node < n) {
                s[node * 2 + 0] = sp[0][r];
                s[node * 2 + 1] = sp[1][r];
                d[node * 2 + 0] = dp[0][r];
                d[node * 2 + 1] = dp[1][r];
            }
        }
    }
}

// ---------------- edge softmax + aggregation: 2 nodes per wave ----------------
__global__ __launch_bounds__(256) void gat_aggregate_kernel(
        const unsigned* __restrict__ hp, const float* __restrict__ sv,
        const float* __restrict__ dv, const int* __restrict__ offb,
        const int* __restrict__ dega, const int* __restrict__ csr,
        const float* __restrict__ scl, const float* __restrict__ sft,
        const unsigned* __restrict__ res, unsigned* __restrict__ out, int n) {
    __shared__ float4 er[8][CAP];     // (src bits, ex0, ex1, unused)
    int slot = threadIdx.x >> 5;      // node slot 0..7
    int lane32 = threadIdx.x & 31;
    int node = blockIdx.x * 8 + slot;
    bool ok = node < n;
    int begin = 0, deg = 0;
    float d0 = 0.f, d1 = 0.f;
    if (ok) {
        begin = offb[node]; deg = dega[node];
        d0 = dv[node * 2 + 0]; d1 = dv[node * 2 + 1];
    }
    bool fits = deg <= CAP;
    int degp = (deg + 7) & ~7;
    float inv0 = 0.f, inv1 = 0.f;

    if (ok && fits) {
        int sids[4]; float e0[4], e1[4];
        #pragma unroll
        for (int k = 0; k < 4; k++) {
            int li = k * 32 + lane32;
            sids[k] = (li < deg) ? csr[begin + li] : -1;
        }
        #pragma unroll
        for (int k = 0; k < 4; k++) {
            if (sids[k] >= 0) {
                float2 sp = *(const float2*)(sv + 2 * sids[k]);
                e0[k] = lrelu(sp.x + d0); e1[k] = lrelu(sp.y + d1);
            } else { e0[k] = -3e38f; e1[k] = -3e38f; }
        }
        float m0 = fmaxf(fmaxf(e0[0], e0[1]), fmaxf(e0[2], e0[3]));
        float m1 = fmaxf(fmaxf(e1[0], e1[1]), fmaxf(e1[2], e1[3]));
        #pragma unroll
        for (int o = 1; o < 32; o <<= 1) {
            m0 = fmaxf(m0, __shfl_xor(m0, o, 64));
            m1 = fmaxf(m1, __shfl_xor(m1, o, 64));
        }
        float z0 = 0.f, z1 = 0.f;
        #pragma unroll
        for (int k = 0; k < 4; k++) {
            if (sids[k] >= 0) {
                float x0 = __expf(e0[k] - m0), x1 = __expf(e1[k] - m1);
                z0 += x0; z1 += x1;
                er[slot][k * 32 + lane32] = make_float4(__int_as_float(sids[k]), x0, x1, 0.f);
            }
        }
        #pragma unroll
        for (int o = 1; o < 32; o <<= 1) {
            z0 += __shfl_xor(z0, o, 64);
            z1 += __shfl_xor(z1, o, 64);
        }
        if (lane32 < degp - deg)
            er[slot][deg + lane32] = make_float4(__int_as_float(0), 0.f, 0.f, 0.f);
        inv0 = 1.f / (z0 + 1e-16f);
        inv1 = 1.f / (z1 + 1e-16f);
    }
    __syncthreads();
    if (!ok) return;

    if (fits) {
        int ll = lane32 & 15;       // channel group: ch 8*ll .. 8*ll+7
        int grp = lane32 >> 4;      // edge slice 0/1
        int hsel = (ll >= 8) ? 1 : 0;
        const uint4* hp4 = (const uint4*)hp;
        float a0 = 0, a1 = 0, a2 = 0, a3 = 0, a4 = 0, a5 = 0, a6 = 0, a7 = 0;
        for (int i = 0; i < degp; i += 8) {
            int e = i + grp * 4;
            float4 r0 = er[slot][e], r1 = er[slot][e + 1], r2 = er[slot][e + 2], r3 = er[slot][e + 3];
            uint4 u0 = hp4[(size_t)__float_as_int(r0.x) * 16 + ll];
            uint4 u1 = hp4[(size_t)__float_as_int(r1.x) * 16 + ll];
            uint4 u2 = hp4[(size_t)__float_as_int(r2.x) * 16 + ll];
            uint4 u3 = hp4[(size_t)__float_as_int(r3.x) * 16 + ll];
            float al0 = hsel ? r0.z : r0.y;
            float al1 = hsel ? r1.z : r1.y;
            float al2 = hsel ? r2.z : r2.y;
            float al3 = hsel ? r3.z : r3.y;
            a0 += al0 * blo(u0.x) + al1 * blo(u1.x) + al2 * blo(u2.x) + al3 * blo(u3.x);
            a1 += al0 * bhi(u0.x) + al1 * bhi(u1.x) + al2 * bhi(u2.x) + al3 * bhi(u3.x);
            a2 += al0 * blo(u0.y) + al1 * blo(u1.y) + al2 * blo(u2.y) + al3 * blo(u3.y);
            a3 += al0 * bhi(u0.y) + al1 * bhi(u1.y) + al2 * bhi(u2.y) + al3 * bhi(u3.y);
            a4 += al0 * blo(u0.z) + al1 * blo(u1.z) + al2 * blo(u2.z) + al3 * blo(u3.z);
            a5 += al0 * bhi(u0.z) + al1 * bhi(u1.z) + al2 * bhi(u2.z) + al3 * bhi(u3.z);
            a6 += al0 * blo(u0.w) + al1 * blo(u1.w) + al2 * blo(u2.w) + al3 * blo(u3.w);
            a7 += al0 * bhi(u0.w) + al1 * bhi(u1.w) + al2 * bhi(u2.w) + al3 * bhi(u3.w);
        }
        // combine the two edge slices (xor 16 stays within each 32-lane group)
        a0 += __shfl_xor(a0, 16, 64); a1 += __shfl_xor(a1, 16, 64);
        a2 += __shfl_xor(a2, 16, 64); a3 += __shfl_xor(a3, 16, 64);
        a4 += __shfl_xor(a4, 16, 64); a5 += __shfl_xor(a5, 16, 64);
        a6 += __shfl_xor(a6, 16, 64); a7 += __shfl_xor(a7, 16, 64);
        float inv = hsel ? inv1 : inv0;
        a0 *= inv; a1 *= inv; a2 *= inv; a3 *= inv;
        a4 *= inv; a5 *= inv; a6 *= inv; a7 *= inv;

        float4 sc0 = ((const float4*)scl)[2 * ll], sc1 = ((const float4*)scl)[2 * ll + 1];
        float4 sh0 = ((const float4*)sft)[2 * ll], sh1 = ((const float4*)sft)[2 * ll + 1];
        float v0 = a0 * sc0.x + sh0.x;
        float v1 = a1 * sc0.y + sh0.y;
        float v2 = a2 * sc0.z + sh0.z;
        float v3 = a3 * sc0.w + sh0.w;
        float v4 = a4 * sc1.x + sh1.x;
        float v5 = a5 * sc1.y + sh1.y;
        float v6 = a6 * sc1.z + sh1.z;
        float v7 = a7 * sc1.w + sh1.w;
        if (res) {
            uint4 r = ((const uint4*)res)[(size_t)node * 16 + ll];
            v0 += blo(r.x); v1 += bhi(r.x); v2 += blo(r.y); v3 += bhi(r.y);
            v4 += blo(r.z); v5 += bhi(r.z); v6 += blo(r.w); v7 += bhi(r.w);
        }
        v0 = fmaxf(v0, 0.f); v1 = fmaxf(v1, 0.f); v2 = fmaxf(v2, 0.f); v3 = fmaxf(v3, 0.f);
        v4 = fmaxf(v4, 0.f); v5 = fmaxf(v5, 0.f); v6 = fmaxf(v6, 0.f); v7 = fmaxf(v7, 0.f);
        if (grp == 0) {
            ((uint4*)out)[(size_t)node * 16 + ll] =
                make_uint4(pck(v0, v1), pck(v2, v3), pck(v4, v5), pck(v6, v7));
        }
    } else {
        // fallback (deg > CAP): 3-pass, 4 channels/lane over 32 lanes
        float mm0 = -3e38f, mm1 = -3e38f;
        for (int i = lane32; i < deg; i += 32) {
            int sc = csr[begin + i];
            float2 sp = *(const float2*)(sv + 2 * sc);
            mm0 = fmaxf(mm0, lrelu(sp.x + d0));
            mm1 = fmaxf(mm1, lrelu(sp.y + d1));
        }
        #pragma unroll
        for (int o = 1; o < 32; o <<= 1) {
            mm0 = fmaxf(mm0, __shfl_xor(mm0, o, 64));
            mm1 = fmaxf(mm1, __shfl_xor(mm1, o, 64));
        }
        float z0 = 0.f, z1 = 0.f;
        for (int i = lane32; i < deg; i += 32) {
            int sc = csr[begin + i];
            float2 sp = *(const float2*)(sv + 2 * sc);
            z0 += __expf(lrelu(sp.x + d0) - mm0);
            z1 += __expf(lrelu(sp.y + d1) - mm1);
        }
        #pragma unroll
        for (int o = 1; o < 32; o <<= 1) {
            z0 += __shfl_xor(z0, o, 64);
            z1 += __shfl_xor(z1, o, 64);
        }
        float i0_ = 1.f / (z0 + 1e-16f), i1_ = 1.f / (z1 + 1e-16f);
        bool head0 = lane32 < 16;    // channels 4*lane32 .. +3
        float b0 = 0.f, b1 = 0.f, b2 = 0.f, b3 = 0.f;
        for (int i = 0; i < deg; i++) {
            int sc = csr[begin + i];
            float2 sp = *(const float2*)(sv + 2 * sc);
            float a = head0 ? __expf(lrelu(sp.x + d0) - mm0) * i0_
                            : __expf(lrelu(sp.y + d1) - mm1) * i1_;
            uint2 u = *(const uint2*)(hp + (size_t)sc * 64 + lane32 * 2);
            b0 += a * blo(u.x); b1 += a * bhi(u.x);
            b2 += a * blo(u.y); b3 += a * bhi(u.y);
        }
        float4 sc4 = ((const float4*)scl)[lane32];
        float4 sh4 = ((const float4*)sft)[lane32];
        float v0 = b0 * sc4.x + sh4.x;
        float v1 = b1 * sc4.y + sh4.y;
        float v2 = b2 * sc4.z + sh4.z;
        float v3 = b3 * sc4.w + sh4.w;
        if (res) {
            uint2 r = ((const uint2*)res)[(size_t)node * 32 + lane32];
            v0 += blo(r.x); v1 += bhi(r.x); v2 += blo(r.y); v3 += bhi(r.y);
        }
        v0 = fmaxf(v0, 0.f); v1 = fmaxf(v1, 0.f);
        v2 = fmaxf(v2, 0.f); v3 = fmaxf(v3, 0.f);
        ((uint2*)out)[(size_t)node * 32 + lane32] = make_uint2(pck(v0, v1), pck(v2, v3));
    }
}

// ---------------- fused global mean pool + lat/lon heads ----------------
__global__ void poolhead_kernel(const unsigned* __restrict__ x, const void* __restrict__ batch,
                                const float* __restrict__ w1a, const float* __restrict__ b1a,
                                const float* __restrict__ w2a, const float* __restrict__ b2a,
                                const float* __restrict__ w1o, const float* __restrict__ b1o,
                                const float* __restrict__ w2o, const float* __restrict__ b2o,
                                const int* __restrict__ flags, void* __restrict__ out) {
    __shared__ float part[4][128];
    __shared__ float xs[128];
    __shared__ int bounds[2];
    int g = blockIdx.x;
    int tid = threadIdx.x;
    bool i64 = flags[1] != 0;
    if (tid < 2) {
        int target = g + tid;
        int lo = 0, hi = NN;
        while (lo < hi) {
            int mid = (lo + hi) >> 1;
            if (ld_int(batch, mid, i64) < target) lo = mid + 1; else hi = mid;
        }
        bounds[tid] = lo;
    }
    __syncthreads();
    int s0 = bounds[0], e0 = bounds[1];
    int wv = tid >> 6, lane = tid & 63;
    float a0 = 0.f, a1 = 0.f;
    for (int node = s0 + wv; node < e0; node += 4) {
        unsigned u = x[(size_t)node * 64 + lane];
        a0 += blo(u);
        a1 += bhi(u);
    }
    part[wv][2 * lane] = a0;
    part[wv][2 * lane + 1] = a1;
    __syncthreads();
    if (tid < 128) {
        float t0 = part[0][tid] + part[1][tid] + part[2][tid] + part[3][tid];
        xs[tid] = t0 / fmaxf((float)(e0 - s0), 1.f);
    }
    __syncthreads();
    if (wv < 2) {
        const float* w1 = wv ? w1o : w1a;
        const float* b1 = wv ? b1o : b1a;
        const float* w2 = wv ? w2o : w2a;
        const float* b2 = wv ? b2o : b2a;
        float acc = b1[lane];
        for (int c = 0; c < 128; c++)
            acc += xs[c] * w1[c * 64 + lane];
        acc = fmaxf(acc, 0.f);
        float contrib = wred_sum(acc * w2[lane]);
        if (lane == 0) {
            float r = contrib + b2[0];
            if (flags[0]) ((float*)out)[wv * NG + g] = r;
            else          ((bf16*)out)[wv * NG + g] = __float2bfloat16(r);
        }
    }
}

extern "C" void kernel_launch(void* const* d_in, const int* in_sizes, int n_in,
                              void* d_out, int out_size, void* d_ws, size_t ws_size,
                              hipStream_t stream) {
    static const int fidx[32] = {0,1, 4,5,6,7,8,9, 10,11,12,13, 14,15,16,17,
                                 18,19,20,21, 22,23,24,25, 26,27,28,29, 30,31,32,33};
    static const int flen[32] = {200000, 3200000, 128, 32, 2048, 32, 4096, 64,
                                 8192, 128, 128, 128, 16384, 128, 128, 128,
                                 16384, 128, 128, 128, 384, 384, 384, 384,
                                 8192, 64, 64, 1, 8192, 64, 64, 1};
    PrepArgs pa;
    int O[32];
    int tot = 0, blk = 0;
    for (int i = 0; i < 32; i++) {
        bool skip = (i == 1) || (i == 4) || (i == 6) || (i == 8) || (i == 12) || (i == 16) ||
                    (i == 11) || (i == 15) || (i == 19) ||
                    (i == 20) || (i == 21) || (i == 22) || (i == 23);
        int cl = skip ? 0 : flen[i];
        pa.src[i] = d_in[fidx[i]];
        pa.len[i] = cl;
        O[i] = tot;
        pa.dst_off[i] = tot;
        pa.blk_base[i] = blk;
        tot += (flen[i] + 63) & ~63;
        blk += (cl + 1023) / 1024;
    }
    pa.blk_base[32] = blk;
    pa.cvtBlks = blk;
    pa.wtBlks = 184;
    pa.wfBlks = NNP * 64 / 8 / 256;          // 1564
    pa.w0 = d_in[10]; pa.w1 = d_in[14]; pa.w2 = d_in[18];
    pa.ww = d_in[6];  pa.wc = d_in[8];
    pa.wf_src = d_in[1];
    pa.gb0 = d_in[13]; pa.gb1 = d_in[17]; pa.gb2 = d_in[21];
    pa.bng = d_in[22]; pa.bnb = d_in[23]; pa.bnm = d_in[24]; pa.bnv = d_in[25];
    int prepGrid = pa.cvtBlks + pa.wtBlks + pa.wfBlks + 2;

    char* w = (char*)d_ws;
    auto alloc = [&](size_t bytes) -> char* {
        char* p = w;
        w += (bytes + 255) & ~(size_t)255;
        return p;
    };
    int*   flags  = (int*)alloc(256);
    float* cf     = (float*)alloc((size_t)tot * 4);
    short* wfhi   = (short*)alloc((size_t)NNP * 64 * 2);
    short* wflo   = (short*)alloc((size_t)NNP * 64 * 2);
    short* x0     = (short*)alloc((size_t)NNP * 64 * 2);
    short* xA     = (short*)alloc((size_t)NNP * 128 * 2);
    short* xB     = (short*)alloc((size_t)NNP * 128 * 2);
    short* h      = (short*)alloc((size_t)NNP * 128 * 2);
    float* sA     = (float*)alloc((size_t)NN * 2 * 4);
    float* dA     = (float*)alloc((size_t)NN * 2 * 4);
    int*   offb   = (int*)alloc((size_t)NN * 4);
    int*   dega   = (int*)alloc((size_t)NN * 4);
    int*   csr    = (int*)alloc((size_t)NB * BCAP * 4);
    int*   bcur   = (int*)alloc((size_t)NB * 4);
    uint2* bkt    = (uint2*)alloc((size_t)NB * BCAP * 8);
    float* bnscl  = (float*)alloc(384 * 4);
    float* bnsft  = (float*)alloc(384 * 4);
    short* wtall  = (short*)alloc((size_t)40960 * 2);
    short* wavewT = (short*)alloc((size_t)2048 * 2);
    short* combwT = (short*)alloc((size_t)4096 * 2);
    short* wt0 = wtall, *wt1 = wtall + 8192, *wt2 = wtall + 24576;

    detect_kernel<<<1, 256, 0, stream>>>((const unsigned int*)d_in[0],
                                         (const unsigned int*)d_in[2], flags, bcur);
    prep_kernel<<<prepGrid, 256, 0, stream>>>(pa, cf, wtall, wavewT, combwT,
                                              wfhi, wflo, bnscl, bnsft, flags);
    encode_mfma_kernel<<<NNP / 64, 256, 0, stream>>>(cf + O[0], cf + O[2], cf + O[3],
                                                     wfhi, wflo, wavewT, cf + O[5],
                                                     combwT, cf + O[7], x0, flags);
    bucket_scatter_kernel<<<NEB, 256, 0, stream>>>(d_in[2], flags, bcur, bkt);
    bucket_finalize_kernel<<<NB, 256, 0, stream>>>(bkt, bcur, offb, dega, csr);

    int gblk = NNP / 64;
    // layer 0
    gemm_mfma_kernel<<<gblk, 256, 0, stream>>>(x0, wt0, cf + O[9], cf + O[10],
                                               h, sA, dA, 64, NN);
    gat_aggregate_kernel<<<(NN + 7) / 8, 256, 0, stream>>>(
        (const unsigned*)h, sA, dA, offb, dega, csr,
        bnscl, bnsft, nullptr, (unsigned*)xA, NN);
    // layer 1
    gemm_mfma_kernel<<<gblk, 256, 0, stream>>>(xA, wt1, cf + O[13], cf + O[14],
                                               h, sA, dA, 128, NN);
    gat_aggregate_kernel<<<(NN + 7) / 8, 256, 0, stream>>>(
        (const unsigned*)h, sA, dA, offb, dega, csr,
        bnscl + 128, bnsft + 128, (const unsigned*)xA, (unsigned*)xB, NN);
    // layer 2
    gemm_mfma_kernel<<<gblk, 256, 0, stream>>>(xB, wt2, cf + O[17], cf + O[18],
                                               h, sA, dA, 128, NN);
    gat_aggregate_kernel<<<(NN + 7) / 8, 256, 0, stream>>>(
        (const unsigned*)h, sA, dA, offb, dega, csr,
        bnscl + 256, bnsft + 256, (const unsigned*)xB, (unsigned*)xA, NN);

    poolhead_kernel<<<NG, 256, 0, stream>>>((const unsigned*)xA, d_in[3],
                                            cf + O[24], cf + O[25], cf + O[26], cf + O[27],
                                            cf + O[28], cf + O[29], cf + O[30], cf + O[31],
                                            flags, d_out);
}